// Round 1
// baseline (440.299 us; speedup 1.0000x reference)
//
#include <hip/hip_runtime.h>

typedef __bf16 bf16;
typedef __bf16 bf16x4 __attribute__((ext_vector_type(4)));
typedef __bf16 bf16x8 __attribute__((ext_vector_type(8)));
typedef float f32x4 __attribute__((ext_vector_type(4)));

#define N_TOK 2048
#define M_TOK 2048
#define DIM 1024
#define CDIM 768
#define DFF 4096

// async global->LDS, 16B per lane; LDS dest = wave-uniform base + lane*16
static __device__ __forceinline__ void async16(const void* g, void* l) {
  __builtin_amdgcn_global_load_lds((const __attribute__((address_space(1))) void*)g,
                                   (__attribute__((address_space(3))) void*)l, 16, 0, 0);
}

// ---------- dtype detector: low-16 halves plausible as bf16? ----------
__global__ __launch_bounds__(256) void detect_kernel(const void* x, int* flag) {
  __shared__ int cnt;
  if (threadIdx.x == 0) cnt = 0;
  __syncthreads();
  const unsigned* w = (const unsigned*)x;
  int ok = 0;
  for (int i = threadIdx.x; i < 512; i += 256) {
    unsigned lo = w[i] & 0xFFFFu;
    float f = __uint_as_float(lo << 16);
    if (lo == 0u || (fabsf(f) > 1e-3f && fabsf(f) < 1e3f)) ok++;
  }
  atomicAdd(&cnt, ok);
  __syncthreads();
  if (threadIdx.x == 0) *flag = (cnt >= 256) ? 1 : 0;
}

// ---------- batched small-vector conversion ----------
struct ConvArgs {
  const void* src[12];
  bf16* dst[12];
  int n[12];
};
__global__ __launch_bounds__(256) void conv_small_kernel(ConvArgs a, const int* flag) {
  const bool isbf = (*flag != 0);
  const int b = blockIdx.x;
  const void* in = a.src[b];
  bf16* out = a.dst[b];
  const int n = a.n[b];
  for (int i = threadIdx.x; i < n; i += 256)
    out[i] = isbf ? ((const bf16*)in)[i] : (bf16)((const float*)in)[i];
}

// ---------- batched transpose+convert (up to 4 slices via blockIdx.z) ----------
struct TmArgs {
  const void* src[4];
  bf16* dst[4];
  int r0[4], Rcnt[4], c0[4], Cfull[4], gx[4], gy[4];
  int force_bf;
};
__global__ __launch_bounds__(256) void tmulti_kernel(TmArgs a, const int* flag) {
  const int z = blockIdx.z;
  if ((int)blockIdx.x >= a.gx[z] || (int)blockIdx.y >= a.gy[z]) return;
  __shared__ bf16 t[32][33];
  const bool isbf = a.force_bf || (*flag != 0);
  const void* in = a.src[z];
  bf16* out = a.dst[z];
  const int Rcnt = a.Rcnt[z], Cfull = a.Cfull[z];
  const int cb = blockIdx.x * 32, rb = blockIdx.y * 32;
  const int tx = threadIdx.x & 31, ty = threadIdx.x >> 5;
#pragma unroll
  for (int i = 0; i < 4; i++) {
    const size_t r = (size_t)(a.r0[z] + rb + ty + i * 8);
    const size_t c = (size_t)(a.c0[z] + cb + tx);
    float v = isbf ? (float)((const bf16*)in)[r * Cfull + c]
                   : ((const float*)in)[r * Cfull + c];
    t[ty + i * 8][tx] = (bf16)v;
  }
  __syncthreads();
#pragma unroll
  for (int i = 0; i < 4; i++)
    out[(size_t)(cb + ty + i * 8) * Rcnt + rb + tx] = t[tx][ty + i * 8];
}

// ---------------- Fused first-layer LayerNorm pair: y=0 x, y=1 ctx --------------
__global__ __launch_bounds__(256) void ln_pair_kernel(
    const void* __restrict__ x0, const bf16* w0, const bf16* b0, bf16* o0,
    const void* __restrict__ x1, const bf16* w1, const bf16* b1, bf16* o1,
    const int* flag) {
  const bool isbf = (*flag != 0);
  const int cols = (blockIdx.y == 0) ? DIM : CDIM;
  const void* x = (blockIdx.y == 0) ? x0 : x1;
  const bf16* w = (blockIdx.y == 0) ? w0 : w1;
  const bf16* b = (blockIdx.y == 0) ? b0 : b1;
  bf16* outp = (blockIdx.y == 0) ? o0 : o1;
  const int row = blockIdx.x;
  const bf16* xr_b = (const bf16*)x + (size_t)row * cols;
  const float* xr_f = (const float*)x + (size_t)row * cols;
  bf16* orow = outp + (size_t)row * cols;
  float s = 0.f, ss = 0.f;
  for (int c = threadIdx.x; c < cols; c += 256) {
    float v = isbf ? (float)xr_b[c] : xr_f[c];
    s += v; ss += v * v;
  }
  for (int d = 1; d < 64; d <<= 1) { s += __shfl_xor(s, d, 64); ss += __shfl_xor(ss, d, 64); }
  __shared__ float sh[8];
  const int wv = threadIdx.x >> 6, lane = threadIdx.x & 63;
  if (lane == 0) { sh[wv] = s; sh[4 + wv] = ss; }
  __syncthreads();
  s = sh[0] + sh[1] + sh[2] + sh[3];
  ss = sh[4] + sh[5] + sh[6] + sh[7];
  const float mean = s / cols;
  float var = ss / cols - mean * mean;
  var = fmaxf(var, 0.f);
  const float r = rsqrtf(var + 1e-12f);
  for (int c = threadIdx.x; c < cols; c += 256) {
    float v = isbf ? (float)xr_b[c] : xr_f[c];
    orow[c] = (bf16)((v - mean) * r * (float)w[c] + (float)b[c]);
  }
}

// ---------------- LayerNorm (bf16 in, bf16 out) ----------------
__global__ __launch_bounds__(256) void ln_kernel(
    const bf16* __restrict__ x, const bf16* __restrict__ w, const bf16* __restrict__ b,
    bf16* __restrict__ out, int cols) {
  const int row = blockIdx.x;
  const bf16* xr = x + (size_t)row * cols;
  bf16* orow = out + (size_t)row * cols;
  float s = 0.f, ss = 0.f;
  for (int c = threadIdx.x; c < cols; c += 256) {
    float v = (float)xr[c];
    s += v; ss += v * v;
  }
  for (int d = 1; d < 64; d <<= 1) { s += __shfl_xor(s, d, 64); ss += __shfl_xor(ss, d, 64); }
  __shared__ float sh[8];
  const int wv = threadIdx.x >> 6, lane = threadIdx.x & 63;
  if (lane == 0) { sh[wv] = s; sh[4 + wv] = ss; }
  __syncthreads();
  s = sh[0] + sh[1] + sh[2] + sh[3];
  ss = sh[4] + sh[5] + sh[6] + sh[7];
  const float mean = s / cols;
  float var = ss / cols - mean * mean;
  var = fmaxf(var, 0.f);
  const float r = rsqrtf(var + 1e-12f);
  for (int c = threadIdx.x; c < cols; c += 256) {
    float v = (float)xr[c];
    orow[c] = (bf16)((v - mean) * r * (float)w[c] + (float)b[c]);
  }
}

__device__ __forceinline__ float gelu_f(float x) {
  float u = 0.7978845608028654f * (x + 0.044715f * x * x * x);
  return 0.5f * x * (1.f + tanhf(u));
}

// -------- gemm128: 128x128 tile, BK=64, 4 waves (2x2 of 64x64), 32 KB LDS -----
// m97 structure + both-sides XOR swizzle: LDS dest stays LINEAR (required by
// global_load_lds), the per-lane GLOBAL source column is pre-swizzled by
// (lane&7)^(lane>>3), and fragment reads XOR the same (lm&7)<<3 into the
// column. Every ds_read_b128 then covers all 32 banks (8 slots x 8 lanes).
// EPI: 1 bias + raw-dtype resid -> bf16 out
//      2 bias + gelu -> bf16 out
//      4 bias + bf16 resid -> raw-dtype out
//      5 accumulate from raw out -> raw out (no bias)
template <int EPI>
__global__ __launch_bounds__(256) void gemm128(
    const bf16* __restrict__ A, const bf16* __restrict__ Bt,
    const bf16* __restrict__ bias, const void* __restrict__ resid,
    void* __restrict__ Cout, int K, int ldc, const int* flag) {
  __shared__ __align__(16) bf16 As[128 * 64];
  __shared__ __align__(16) bf16 Bs[128 * 64];
  const int tid = threadIdx.x;
  const int lane = tid & 63, wv = tid >> 6;
  const int lq = lane >> 4, lm = lane & 15;
  const int row0 = blockIdx.y * 128, col0 = blockIdx.x * 128;
  const int wr = (wv >> 1) * 64, wc = (wv & 1) * 64;

  const int sr = lane >> 3;              // staging row within 8-row group
  const int sc = ((lane & 7) ^ sr) * 8;  // pre-swizzled source col (elems)
  const int swz = (lm & 7) << 3;         // read-side XOR (elems)

  f32x4 acc[4][4] = {};

  const bf16* Abase = A + (size_t)(row0 + wv * 32 + sr) * K + sc;
  const bf16* Bbase = Bt + (size_t)(col0 + wv * 32 + sr) * K + sc;

  for (int k0 = 0; k0 < K; k0 += 64) {
    __syncthreads();
#pragma unroll
    for (int b = 0; b < 4; b++) {
      async16(Abase + (size_t)(b * 8) * K + k0, As + wv * 2048 + b * 512);
      async16(Bbase + (size_t)(b * 8) * K + k0, Bs + wv * 2048 + b * 512);
    }
    __syncthreads();
#pragma unroll
    for (int kh = 0; kh < 2; kh++) {
      const int cofs = (kh * 32 + lq * 8) ^ swz;
      bf16x8 af[4], bfv[4];
#pragma unroll
      for (int t = 0; t < 4; t++)
        af[t] = *(const bf16x8*)&As[(wr + t * 16 + lm) * 64 + cofs];
#pragma unroll
      for (int t = 0; t < 4; t++)
        bfv[t] = *(const bf16x8*)&Bs[(wc + t * 16 + lm) * 64 + cofs];
#pragma unroll
      for (int i = 0; i < 4; i++)
#pragma unroll
        for (int j = 0; j < 4; j++)
          acc[i][j] = __builtin_amdgcn_mfma_f32_16x16x32_bf16(af[i], bfv[j], acc[i][j], 0, 0, 0);
    }
  }

  const bool isbf = (*flag != 0);
#pragma unroll
  for (int i = 0; i < 4; i++) {
    const int rb = row0 + wr + i * 16 + lq * 4;
#pragma unroll
    for (int j = 0; j < 4; j++) {
      const int c = col0 + wc + j * 16 + lm;
      const float bv = (EPI != 5) ? (float)bias[c] : 0.f;
#pragma unroll
      for (int rg = 0; rg < 4; rg++) {
        const size_t idx = (size_t)(rb + rg) * ldc + c;
        float v = acc[i][j][rg] + bv;
        if (EPI == 1)
          v += isbf ? (float)((const bf16*)resid)[idx] : ((const float*)resid)[idx];
        if (EPI == 2) v = gelu_f(v);
        if (EPI == 4) v += (float)((const bf16*)resid)[idx];
        if (EPI == 5)
          v += isbf ? (float)((bf16*)Cout)[idx] : ((float*)Cout)[idx];
        if (EPI == 4 || EPI == 5) {
          if (isbf) ((bf16*)Cout)[idx] = (bf16)v;
          else      ((float*)Cout)[idx] = v;
        } else {
          ((bf16*)Cout)[idx] = (bf16)v;
        }
      }
    }
  }
}

// ------- fused q/k/v projection, z=2 computes V^T directly (bias per row) ------
struct QkvArgs {
  const bf16* A[3];
  const bf16* Bt[3];
  const bf16* bias[3];
  bf16* C[3];
  int K[3], ldc[3], gx[3], gy[3], brow[3];
};
__global__ __launch_bounds__(256) void gemm128_qkv(QkvArgs a) {
  const int z = blockIdx.z;
  if ((int)blockIdx.x >= a.gx[z] || (int)blockIdx.y >= a.gy[z]) return;
  const bf16* A = a.A[z];
  const bf16* Bt = a.Bt[z];
  const int K = a.K[z];
  __shared__ __align__(16) bf16 As[128 * 64];
  __shared__ __align__(16) bf16 Bs[128 * 64];
  const int tid = threadIdx.x;
  const int lane = tid & 63, wv = tid >> 6;
  const int lq = lane >> 4, lm = lane & 15;
  const int row0 = blockIdx.y * 128, col0 = blockIdx.x * 128;
  const int wr = (wv >> 1) * 64, wc = (wv & 1) * 64;

  const int sr = lane >> 3;
  const int sc = ((lane & 7) ^ sr) * 8;
  const int swz = (lm & 7) << 3;

  f32x4 acc[4][4] = {};

  const bf16* Abase = A + (size_t)(row0 + wv * 32 + sr) * K + sc;
  const bf16* Bbase = Bt + (size_t)(col0 + wv * 32 + sr) * K + sc;

  for (int k0 = 0; k0 < K; k0 += 64) {
    __syncthreads();
#pragma unroll
    for (int b = 0; b < 4; b++) {
      async16(Abase + (size_t)(b * 8) * K + k0, As + wv * 2048 + b * 512);
      async16(Bbase + (size_t)(b * 8) * K + k0, Bs + wv * 2048 + b * 512);
    }
    __syncthreads();
#pragma unroll
    for (int kh = 0; kh < 2; kh++) {
      const int cofs = (kh * 32 + lq * 8) ^ swz;
      bf16x8 af[4], bfv[4];
#pragma unroll
      for (int t = 0; t < 4; t++)
        af[t] = *(const bf16x8*)&As[(wr + t * 16 + lm) * 64 + cofs];
#pragma unroll
      for (int t = 0; t < 4; t++)
        bfv[t] = *(const bf16x8*)&Bs[(wc + t * 16 + lm) * 64 + cofs];
#pragma unroll
      for (int i = 0; i < 4; i++)
#pragma unroll
        for (int j = 0; j < 4; j++)
          acc[i][j] = __builtin_amdgcn_mfma_f32_16x16x32_bf16(af[i], bfv[j], acc[i][j], 0, 0, 0);
    }
  }

  const bf16* bias = a.bias[z];
  bf16* C = a.C[z];
  const int ldc = a.ldc[z];
  const bool brow = a.brow[z] != 0;
#pragma unroll
  for (int i = 0; i < 4; i++) {
    const int rb = row0 + wr + i * 16 + lq * 4;
#pragma unroll
    for (int j = 0; j < 4; j++) {
      const int c = col0 + wc + j * 16 + lm;
      const float bcol = brow ? 0.f : (float)bias[c];
#pragma unroll
      for (int rg = 0; rg < 4; rg++) {
        const float bv = brow ? (float)bias[rb + rg] : bcol;
        C[(size_t)(rb + rg) * ldc + c] = (bf16)(acc[i][j][rg] + bv);
      }
    }
  }
}

// ---------------- Flash attention v7: split-M over grid.z (2 halves) ----------
// Each block does 64 q-rows x 1 head x M/2 context, writing UNNORMALIZED partial
// O^T (bf16) + partial row-sums (fp32). Combine kernel merges. 1024 blocks ->
// 4 blocks/CU (was grid-limited at 2). Bounded scores -> no running max.
#define KS_STR 72
#define VS_STR 136
__global__ __launch_bounds__(256) void attn_kernel(
    const bf16* __restrict__ q, const bf16* __restrict__ k,
    const bf16* __restrict__ vT, bf16* __restrict__ pO0, bf16* __restrict__ pO1,
    float* __restrict__ l0, float* __restrict__ l1) {
  __shared__ __align__(16) bf16 KPs[128 * KS_STR];  // Ks [128][64]+pad, then P^T
  __shared__ __align__(16) bf16 Vs[64 * VS_STR];    // [d 64][m 128]+pad
  const int tid = threadIdx.x, lane = tid & 63, wv = tid >> 6;
  const int lq = lane >> 4, lm = lane & 15;
  const int h = blockIdx.y;
  const int n0 = blockIdx.x * 64;
  const int half = blockIdx.z;
  const int mbeg = half * (M_TOK / 2), mend = mbeg + M_TOK / 2;
  bf16* pO = half ? pO1 : pO0;
  float* lb = half ? l1 : l0;

  bf16x8 qf[2];
#pragma unroll
  for (int f = 0; f < 2; f++)
    qf[f] = *(const bf16x8*)&q[(size_t)(n0 + wv * 16 + lm) * DIM + h * 64 + f * 32 + lq * 8];

  f32x4 oacc[4] = {};  // O^T tiles: rows d, cols n
  float lsum = 0.f;
  const float sc = 0.125f * 1.4426950408889634f;  // (1/sqrt(64)) * log2(e)

  for (int m0 = mbeg; m0 < mend; m0 += 128) {
    __syncthreads();
#pragma unroll
    for (int it = 0; it < 4; it++) {  // Ks [128][64] stride 72
      const int e = tid * 8 + it * 2048;
      const int r = e >> 6, c = e & 63;
      *(bf16x8*)&KPs[r * KS_STR + c] =
          *(const bf16x8*)&k[(size_t)(m0 + r) * DIM + h * 64 + c];
    }
#pragma unroll
    for (int it = 0; it < 4; it++) {  // Vs [64][128] stride 136
      const int e = tid * 8 + it * 2048;
      const int r = e >> 7, c = e & 127;
      *(bf16x8*)&Vs[r * VS_STR + c] =
          *(const bf16x8*)&vT[(size_t)(h * 64 + r) * M_TOK + m0 + c];
    }
    __syncthreads();

    // S^T into regs: tile j rows m = j*16+lq*4+rg, col n = wv*16 + (lane&15)
    f32x4 s[8];
#pragma unroll
    for (int j = 0; j < 8; j++) {
      bf16x8 kf0 = *(const bf16x8*)&KPs[(j * 16 + lm) * KS_STR + lq * 8];
      bf16x8 kf1 = *(const bf16x8*)&KPs[(j * 16 + lm) * KS_STR + 32 + lq * 8];
      f32x4 z = {};
      z = __builtin_amdgcn_mfma_f32_16x16x32_bf16(kf0, qf[0], z, 0, 0, 0);
      s[j] = __builtin_amdgcn_mfma_f32_16x16x32_bf16(kf1, qf[1], z, 0, 0, 0);
    }
    __syncthreads();  // every wave done reading Ks; region becomes P^T

#pragma unroll
    for (int j = 0; j < 8; j++) {
      bf16x4 pw;
#pragma unroll
      for (int rg = 0; rg < 4; rg++) {
        const float pv = exp2f(s[j][rg] * sc);
        lsum += pv;
        pw[rg] = (bf16)pv;
      }
      *(bf16x4*)&KPs[(wv * 16 + lm) * VS_STR + j * 16 + lq * 4] = pw;
    }

    // O^T += V^T P^T (pf rows are this wave's own -> same-wave RAW, lgkmcnt)
#pragma unroll
    for (int kk = 0; kk < 4; kk++) {
      bf16x8 pf = *(const bf16x8*)&KPs[(wv * 16 + lm) * VS_STR + kk * 32 + lq * 8];
#pragma unroll
      for (int dt = 0; dt < 4; dt++) {
        bf16x8 vf = *(const bf16x8*)&Vs[(dt * 16 + lm) * VS_STR + kk * 32 + lq * 8];
        oacc[dt] = __builtin_amdgcn_mfma_f32_16x16x32_bf16(vf, pf, oacc[dt], 0, 0, 0);
      }
    }
  }

  // partial row-sum: reduce over the 4 lanes sharing this n (lane bits 4..5)
  lsum += __shfl_xor(lsum, 16, 64);
  lsum += __shfl_xor(lsum, 32, 64);
  if (lane < 16) lb[h * N_TOK + n0 + wv * 16 + lane] = lsum;

  const int rn = n0 + wv * 16 + lm;
#pragma unroll
  for (int dt = 0; dt < 4; dt++) {
    bf16x4 ow;
#pragma unroll
    for (int rg = 0; rg < 4; rg++) ow[rg] = (bf16)oacc[dt][rg];
    *(bf16x4*)&pO[(size_t)rn * DIM + h * 64 + dt * 16 + lq * 4] = ow;
  }
}

// ---------------- combine: om = (pO0 + pO1) / (l0 + l1) ----------------
__global__ __launch_bounds__(256) void attn_combine(
    const bf16* __restrict__ pO0, const bf16* __restrict__ pO1,
    const float* __restrict__ l0, const float* __restrict__ l1,
    bf16* __restrict__ om) {
  const int i4 = (blockIdx.x * 256 + threadIdx.x) * 4;  // over N*DIM = 2M elems
  const int n = i4 >> 10;
  const int h = (i4 & 1023) >> 6;
  const float rinv = 1.f / (l0[h * N_TOK + n] + l1[h * N_TOK + n]);
  bf16x4 a = *(const bf16x4*)&pO0[i4];
  bf16x4 b = *(const bf16x4*)&pO1[i4];
  bf16x4 o;
#pragma unroll
  for (int r = 0; r < 4; r++) o[r] = (bf16)(((float)a[r] + (float)b[r]) * rinv);
  *(bf16x4*)&om[i4] = o;
}

extern "C" void kernel_launch(void* const* d_in, const int* in_sizes, int n_in,
                              void* d_out, int out_size, void* d_ws, size_t ws_size,
                              hipStream_t stream) {
  const void* x_r     = d_in[0];
  const void* ctx_r   = d_in[1];
  const void* wq_r    = d_in[2];
  const void* bq_r    = d_in[3];
  const void* wk_r    = d_in[4];
  const void* bk_r    = d_in[5];
  const void* wv_r    = d_in[6];
  const void* bv_r    = d_in[7];
  const void* wo_r    = d_in[8];
  const void* bo_r    = d_in[9];
  const void* w1_r    = d_in[10];
  const void* b1_r    = d_in[11];
  const void* w2_r    = d_in[12];
  const void* b2_r    = d_in[13];
  const void* qnw_r   = d_in[14];
  const void* qnb_r   = d_in[15];
  const void* kvnw_r  = d_in[16];
  const void* kvnb_r  = d_in[17];
  const void* pnw_r   = d_in[18];
  const void* pnb_r   = d_in[19];

  // ---- workspace carve: 14M bf16 elems + smalls (~28.0 MB, known-good) ----
  // [0,2M) qm->hln | [2M,4M) km->xat | [4M,8M) weights (wqT/wkT/wvT/woT, then
  //   w1Th/w2Th; l0/l1 park in dead wqT after qkv) | [8M,10M) xq->pO0->om |
  // [10M,12M) vTb | [12M,14M) kvn->pO1 ; h1h spans [10M,14M) in MLP phase
  bf16* p = (bf16*)d_ws;
  const size_t MEG = 1024 * 1024;
  bf16* qm  = p;             bf16* hln = qm;
  bf16* km  = p + 2 * MEG;   bf16* xat = km;
  bf16* wC  = p + 4 * MEG;
  bf16* xq  = p + 8 * MEG;   bf16* pO0 = xq;   bf16* om = xq;
  bf16* vTb = p + 10 * MEG;
  bf16* kvn = p + 12 * MEG;  bf16* pO1 = kvn;
  bf16* h1h = p + 10 * MEG;  // MLP h1 half spans [10M,14M)
  bf16* SM  = p + 14 * MEG;
  int* flag = (int*)(p + 14 * MEG + 16384);

  bf16* wqT = wC;
  bf16* wkT = wC + 1 * MEG;
  bf16* wvT = wC + 1 * MEG + 786432;
  bf16* woT = wC + 2 * MEG + 524288;
  bf16* w1Th = wC;
  bf16* w2Th = wC + 2 * MEG;
  float* l0 = (float*)wC;        // parks in dead wqT region after qkv (128 KB)
  float* l1 = l0 + N_TOK * 16;   // 32768 floats each

  bf16* bqc = SM, *bkc = SM + 1024, *bvc = SM + 2048, *boc = SM + 3072;
  bf16* b1c = SM + 4096, *b2c = SM + 8192;
  bf16* qnw = SM + 9216, *qnb = SM + 10240;
  bf16* kvnw = SM + 11264, *kvnb = SM + 12032;
  bf16* pnw = SM + 12800, *pnb = SM + 13824;

  // 0) dtype detection + batched small-vector conversion
  detect_kernel<<<1, 256, 0, stream>>>(x_r, flag);
  ConvArgs ca;
  ca.src[0] = bq_r;   ca.dst[0] = bqc;  ca.n[0] = DIM;
  ca.src[1] = bk_r;   ca.dst[1] = bkc;  ca.n[1] = DIM;
  ca.src[2] = bv_r;   ca.dst[2] = bvc;  ca.n[2] = DIM;
  ca.src[3] = bo_r;   ca.dst[3] = boc;  ca.n[3] = DIM;
  ca.src[4] = b1_r;   ca.dst[4] = b1c;  ca.n[4] = DFF;
  ca.src[5] = b2_r;   ca.dst[5] = b2c;  ca.n[5] = DIM;
  ca.src[6] = qnw_r;  ca.dst[6] = qnw;  ca.n[6] = DIM;
  ca.src[7] = qnb_r;  ca.dst[7] = qnb;  ca.n[7] = DIM;
  ca.src[8] = kvnw_r; ca.dst[8] = kvnw; ca.n[8] = CDIM;
  ca.src[9] = kvnb_r; ca.dst[9] = kvnb; ca.n[9] = CDIM;
  ca.src[10] = pnw_r; ca.dst[10] = pnw; ca.n[10] = DIM;
  ca.src[11] = pnb_r; ca.dst[11] = pnb; ca.n[11] = DIM;
  conv_small_kernel<<<12, 256, 0, stream>>>(ca, flag);

  // 1) both input layernorms in one launch
  ln_pair_kernel<<<dim3(2048, 2), 256, 0, stream>>>(x_r, qnw, qnb, xq,
                                                    ctx_r, kvnw, kvnb, kvn, flag);

  // 2) all four attention weight transposes in one launch
  {
    TmArgs ta;
    ta.force_bf = 0;
    ta.src[0] = wq_r; ta.dst[0] = wqT; ta.r0[0] = 0; ta.Rcnt[0] = DIM;
    ta.c0[0] = 0; ta.Cfull[0] = DIM; ta.gx[0] = 32; ta.gy[0] = 32;
    ta.src[1] = wk_r; ta.dst[1] = wkT; ta.r0[1] = 0; ta.Rcnt[1] = CDIM;
    ta.c0[1] = 0; ta.Cfull[1] = DIM; ta.gx[1] = 32; ta.gy[1] = 24;
    ta.src[2] = wv_r; ta.dst[2] = wvT; ta.r0[2] = 0; ta.Rcnt[2] = CDIM;
    ta.c0[2] = 0; ta.Cfull[2] = DIM; ta.gx[2] = 32; ta.gy[2] = 24;
    ta.src[3] = wo_r; ta.dst[3] = woT; ta.r0[3] = 0; ta.Rcnt[3] = DIM;
    ta.c0[3] = 0; ta.Cfull[3] = DIM; ta.gx[3] = 32; ta.gy[3] = 32;
    tmulti_kernel<<<dim3(32, 32, 4), 256, 0, stream>>>(ta, flag);
  }

  // 3) fused q/k/v; z=2 emits V^T directly (A=wvT rows d, Bt=kvn rows m)
  {
    QkvArgs qa;
    qa.A[0] = xq;  qa.Bt[0] = wqT; qa.bias[0] = bqc; qa.C[0] = qm;
    qa.K[0] = DIM;  qa.ldc[0] = DIM;   qa.gx[0] = 8;  qa.gy[0] = 16; qa.brow[0] = 0;
    qa.A[1] = kvn; qa.Bt[1] = wkT; qa.bias[1] = bkc; qa.C[1] = km;
    qa.K[1] = CDIM; qa.ldc[1] = DIM;   qa.gx[1] = 8;  qa.gy[1] = 16; qa.brow[1] = 0;
    qa.A[2] = wvT; qa.Bt[2] = kvn; qa.bias[2] = bvc; qa.C[2] = vTb;
    qa.K[2] = CDIM; qa.ldc[2] = M_TOK; qa.gx[2] = 16; qa.gy[2] = 8;  qa.brow[2] = 1;
    gemm128_qkv<<<dim3(16, 16, 3), 256, 0, stream>>>(qa);
  }

  // 4) attention split-M (1024 blocks) + combine
  attn_kernel<<<dim3(32, 16, 2), 256, 0, stream>>>(qm, km, vTb, pO0, pO1, l0, l1);
  attn_combine<<<2048, 256, 0, stream>>>(pO0, pO1, l0, l1, om);

  // 5) o-projection + raw-dtype residual(x)
  gemm128<1><<<dim3(8, 16), 256, 0, stream>>>(om, woT, boc, x_r, xat, DIM, DIM, flag);

  // 6) post-norm
  ln_kernel<<<N_TOK, 256, 0, stream>>>(xat, pnw, pnb, hln, DIM);

  // 7) MLP split over DFF halves; final writes d_out in raw dtype
  for (int hh = 0; hh < 2; hh++) {
    TmArgs ta;
    ta.force_bf = 0;
    ta.src[0] = w1_r; ta.dst[0] = w1Th; ta.r0[0] = 0; ta.Rcnt[0] = DIM;
    ta.c0[0] = hh * 2048; ta.Cfull[0] = DFF; ta.gx[0] = 64; ta.gy[0] = 32;
    ta.src[1] = w2_r; ta.dst[1] = w2Th; ta.r0[1] = hh * 2048; ta.Rcnt[1] = 2048;
    ta.c0[1] = 0; ta.Cfull[1] = DIM; ta.gx[1] = 32; ta.gy[1] = 64;
    ta.src[2] = ta.src[0]; ta.dst[2] = ta.dst[0]; ta.r0[2] = 0; ta.Rcnt[2] = 32;
    ta.c0[2] = 0; ta.Cfull[2] = DIM; ta.gx[2] = 0; ta.gy[2] = 0;
    ta.src[3] = ta.src[0]; ta.dst[3] = ta.dst[0]; ta.r0[3] = 0; ta.Rcnt[3] = 32;
    ta.c0[3] = 0; ta.Cfull[3] = DIM; ta.gx[3] = 0; ta.gy[3] = 0;
    tmulti_kernel<<<dim3(64, 64, 2), 256, 0, stream>>>(ta, flag);

    // MLP1 half: [2048]x[2048], 256 blocks of 128x128
    gemm128<2><<<dim3(16, 16), 256, 0, stream>>>(hln, w1Th, b1c + hh * 2048, nullptr,
                                                 h1h, DIM, 2048, flag);
    // MLP2 half: [2048]x[1024], 128 blocks of 128x128
    if (hh == 0)
      gemm128<4><<<dim3(8, 16), 256, 0, stream>>>(h1h, w2Th, b2c, xat, d_out,
                                                  2048, DIM, flag);
    else
      gemm128<5><<<dim3(8, 16), 256, 0, stream>>>(h1h, w2Th, b2c, nullptr, d_out,
                                                  2048, DIM, flag);
  }
}

// Round 3
// 396.077 us; speedup vs baseline: 1.1117x; 1.1117x over previous
//
#include <hip/hip_runtime.h>

typedef __bf16 bf16;
typedef __bf16 bf16x4 __attribute__((ext_vector_type(4)));
typedef __bf16 bf16x8 __attribute__((ext_vector_type(8)));
typedef float f32x4 __attribute__((ext_vector_type(4)));

#define N_TOK 2048
#define M_TOK 2048
#define DIM 1024
#define CDIM 768
#define DFF 4096

// async global->LDS, 16B per lane; LDS dest = wave-uniform base + lane*16
static __device__ __forceinline__ void async16(const void* g, void* l) {
  __builtin_amdgcn_global_load_lds((const __attribute__((address_space(1))) void*)g,
                                   (__attribute__((address_space(3))) void*)l, 16, 0, 0);
}

// ---------- dtype detector: low-16 halves plausible as bf16? ----------
__global__ __launch_bounds__(256) void detect_kernel(const void* x, int* flag) {
  __shared__ int cnt;
  if (threadIdx.x == 0) cnt = 0;
  __syncthreads();
  const unsigned* w = (const unsigned*)x;
  int ok = 0;
  for (int i = threadIdx.x; i < 512; i += 256) {
    unsigned lo = w[i] & 0xFFFFu;
    float f = __uint_as_float(lo << 16);
    if (lo == 0u || (fabsf(f) > 1e-3f && fabsf(f) < 1e3f)) ok++;
  }
  atomicAdd(&cnt, ok);
  __syncthreads();
  if (threadIdx.x == 0) *flag = (cnt >= 256) ? 1 : 0;
}

// ---------- batched small-vector conversion ----------
struct ConvArgs {
  const void* src[12];
  bf16* dst[12];
  int n[12];
};
__global__ __launch_bounds__(256) void conv_small_kernel(ConvArgs a, const int* flag) {
  const bool isbf = (*flag != 0);
  const int b = blockIdx.x;
  const void* in = a.src[b];
  bf16* out = a.dst[b];
  const int n = a.n[b];
  for (int i = threadIdx.x; i < n; i += 256)
    out[i] = isbf ? ((const bf16*)in)[i] : (bf16)((const float*)in)[i];
}

// ---------- batched transpose+convert (up to 4 slices via blockIdx.z) ----------
struct TmArgs {
  const void* src[4];
  bf16* dst[4];
  int r0[4], Rcnt[4], c0[4], Cfull[4], gx[4], gy[4];
  int force_bf;
};
__global__ __launch_bounds__(256) void tmulti_kernel(TmArgs a, const int* flag) {
  const int z = blockIdx.z;
  if ((int)blockIdx.x >= a.gx[z] || (int)blockIdx.y >= a.gy[z]) return;
  __shared__ bf16 t[32][33];
  const bool isbf = a.force_bf || (*flag != 0);
  const void* in = a.src[z];
  bf16* out = a.dst[z];
  const int Rcnt = a.Rcnt[z], Cfull = a.Cfull[z];
  const int cb = blockIdx.x * 32, rb = blockIdx.y * 32;
  const int tx = threadIdx.x & 31, ty = threadIdx.x >> 5;
#pragma unroll
  for (int i = 0; i < 4; i++) {
    const size_t r = (size_t)(a.r0[z] + rb + ty + i * 8);
    const size_t c = (size_t)(a.c0[z] + cb + tx);
    float v = isbf ? (float)((const bf16*)in)[r * Cfull + c]
                   : ((const float*)in)[r * Cfull + c];
    t[ty + i * 8][tx] = (bf16)v;
  }
  __syncthreads();
#pragma unroll
  for (int i = 0; i < 4; i++)
    out[(size_t)(cb + ty + i * 8) * Rcnt + rb + tx] = t[tx][ty + i * 8];
}

// ---------------- Fused first-layer LayerNorm pair: y=0 x, y=1 ctx --------------
__global__ __launch_bounds__(256) void ln_pair_kernel(
    const void* __restrict__ x0, const bf16* w0, const bf16* b0, bf16* o0,
    const void* __restrict__ x1, const bf16* w1, const bf16* b1, bf16* o1,
    const int* flag) {
  const bool isbf = (*flag != 0);
  const int cols = (blockIdx.y == 0) ? DIM : CDIM;
  const void* x = (blockIdx.y == 0) ? x0 : x1;
  const bf16* w = (blockIdx.y == 0) ? w0 : w1;
  const bf16* b = (blockIdx.y == 0) ? b0 : b1;
  bf16* outp = (blockIdx.y == 0) ? o0 : o1;
  const int row = blockIdx.x;
  const bf16* xr_b = (const bf16*)x + (size_t)row * cols;
  const float* xr_f = (const float*)x + (size_t)row * cols;
  bf16* orow = outp + (size_t)row * cols;
  float s = 0.f, ss = 0.f;
  for (int c = threadIdx.x; c < cols; c += 256) {
    float v = isbf ? (float)xr_b[c] : xr_f[c];
    s += v; ss += v * v;
  }
  for (int d = 1; d < 64; d <<= 1) { s += __shfl_xor(s, d, 64); ss += __shfl_xor(ss, d, 64); }
  __shared__ float sh[8];
  const int wv = threadIdx.x >> 6, lane = threadIdx.x & 63;
  if (lane == 0) { sh[wv] = s; sh[4 + wv] = ss; }
  __syncthreads();
  s = sh[0] + sh[1] + sh[2] + sh[3];
  ss = sh[4] + sh[5] + sh[6] + sh[7];
  const float mean = s / cols;
  float var = ss / cols - mean * mean;
  var = fmaxf(var, 0.f);
  const float r = rsqrtf(var + 1e-12f);
  for (int c = threadIdx.x; c < cols; c += 256) {
    float v = isbf ? (float)xr_b[c] : xr_f[c];
    orow[c] = (bf16)((v - mean) * r * (float)w[c] + (float)b[c]);
  }
}

// ---------------- LayerNorm (bf16 in, bf16 out) ----------------
__global__ __launch_bounds__(256) void ln_kernel(
    const bf16* __restrict__ x, const bf16* __restrict__ w, const bf16* __restrict__ b,
    bf16* __restrict__ out, int cols) {
  const int row = blockIdx.x;
  const bf16* xr = x + (size_t)row * cols;
  bf16* orow = out + (size_t)row * cols;
  float s = 0.f, ss = 0.f;
  for (int c = threadIdx.x; c < cols; c += 256) {
    float v = (float)xr[c];
    s += v; ss += v * v;
  }
  for (int d = 1; d < 64; d <<= 1) { s += __shfl_xor(s, d, 64); ss += __shfl_xor(ss, d, 64); }
  __shared__ float sh[8];
  const int wv = threadIdx.x >> 6, lane = threadIdx.x & 63;
  if (lane == 0) { sh[wv] = s; sh[4 + wv] = ss; }
  __syncthreads();
  s = sh[0] + sh[1] + sh[2] + sh[3];
  ss = sh[4] + sh[5] + sh[6] + sh[7];
  const float mean = s / cols;
  float var = ss / cols - mean * mean;
  var = fmaxf(var, 0.f);
  const float r = rsqrtf(var + 1e-12f);
  for (int c = threadIdx.x; c < cols; c += 256) {
    float v = (float)xr[c];
    orow[c] = (bf16)((v - mean) * r * (float)w[c] + (float)b[c]);
  }
}

__device__ __forceinline__ float gelu_f(float x) {
  float u = 0.7978845608028654f * (x + 0.044715f * x * x * x);
  return 0.5f * x * (1.f + tanhf(u));
}

// -------- gemm128db: 128x128 tile, BK=64, 512 thr (8 waves 2x4, 64x32/wave) ----
// Double-buffered LDS (64 KB), T3-minimum 2-phase: next tile's global_load_lds
// issued BEFORE current tile's ds_read+MFMA; ONE __syncthreads per K-tile
// (drains both vmcnt of next stage and lgkm of current reads). Both-sides XOR
// swizzle as round-1 (conflict-free, harness-verified): LDS linear,
// global source col pre-swizzled by (lane&7)^(lane>>3), read col XOR (lm&7)<<3.
// EPI: 1 bias + raw-dtype resid -> bf16 out
//      2 bias + gelu -> bf16 out
//      4 bias + bf16 resid -> raw-dtype out
//      5 accumulate from raw out -> raw out (no bias)
template <int EPI>
__global__ __launch_bounds__(512) void gemm128db(
    const bf16* __restrict__ A, const bf16* __restrict__ Bt,
    const bf16* __restrict__ bias, const void* __restrict__ resid,
    void* __restrict__ Cout, int K, int ldc, const int* flag) {
  __shared__ __align__(16) bf16 As[2][128 * 64];
  __shared__ __align__(16) bf16 Bs[2][128 * 64];
  const int tid = threadIdx.x;
  const int lane = tid & 63, wv = tid >> 6;
  const int lq = lane >> 4, lm = lane & 15;
  const int row0 = blockIdx.y * 128, col0 = blockIdx.x * 128;
  const int wm = (wv >> 2) * 64, wn = (wv & 3) * 32;

  const int sr = lane >> 3;              // staging row within 8-row group
  const int sc = ((lane & 7) ^ sr) * 8;  // pre-swizzled source col (elems)
  const int swz = (lm & 7) << 3;         // read-side XOR (elems)

  f32x4 acc[4][2] = {};

  // wave wv stages tile rows [wv*16, wv*16+16), 2 async16 per operand
  const bf16* Abase = A + (size_t)(row0 + wv * 16 + sr) * K + sc;
  const bf16* Bbase = Bt + (size_t)(col0 + wv * 16 + sr) * K + sc;

  const int nt = K >> 6;
  // prologue: stage tile 0 into buffer 0
#pragma unroll
  for (int b = 0; b < 2; b++) {
    async16(Abase + (size_t)(b * 8) * K, &As[0][wv * 1024 + b * 512]);
    async16(Bbase + (size_t)(b * 8) * K, &Bs[0][wv * 1024 + b * 512]);
  }
  __syncthreads();

  int cur = 0;
  for (int t = 0; t < nt; ++t) {
    if (t + 1 < nt) {  // issue next tile's loads BEFORE compute (they fly under MFMA)
      const int k1 = (t + 1) << 6;
#pragma unroll
      for (int b = 0; b < 2; b++) {
        async16(Abase + (size_t)(b * 8) * K + k1, &As[cur ^ 1][wv * 1024 + b * 512]);
        async16(Bbase + (size_t)(b * 8) * K + k1, &Bs[cur ^ 1][wv * 1024 + b * 512]);
      }
    }
#pragma unroll
    for (int kh = 0; kh < 2; kh++) {
      const int cofs = (kh * 32 + lq * 8) ^ swz;
      bf16x8 af[4], bfv[2];
#pragma unroll
      for (int i = 0; i < 4; i++)
        af[i] = *(const bf16x8*)&As[cur][(wm + i * 16 + lm) * 64 + cofs];
#pragma unroll
      for (int j = 0; j < 2; j++)
        bfv[j] = *(const bf16x8*)&Bs[cur][(wn + j * 16 + lm) * 64 + cofs];
#pragma unroll
      for (int i = 0; i < 4; i++)
#pragma unroll
        for (int j = 0; j < 2; j++)
          acc[i][j] = __builtin_amdgcn_mfma_f32_16x16x32_bf16(af[i], bfv[j], acc[i][j], 0, 0, 0);
    }
    __syncthreads();  // drains next-stage vmcnt + this tile's lgkm reads
    cur ^= 1;
  }

  const bool isbf = (*flag != 0);
#pragma unroll
  for (int i = 0; i < 4; i++) {
    const int rb = row0 + wm + i * 16 + lq * 4;
#pragma unroll
    for (int j = 0; j < 2; j++) {
      const int c = col0 + wn + j * 16 + lm;
      const float bv = (EPI != 5) ? (float)bias[c] : 0.f;
#pragma unroll
      for (int rg = 0; rg < 4; rg++) {
        const size_t idx = (size_t)(rb + rg) * ldc + c;
        float v = acc[i][j][rg] + bv;
        if (EPI == 1)
          v += isbf ? (float)((const bf16*)resid)[idx] : ((const float*)resid)[idx];
        if (EPI == 2) v = gelu_f(v);
        if (EPI == 4) v += (float)((const bf16*)resid)[idx];
        if (EPI == 5)
          v += isbf ? (float)((bf16*)Cout)[idx] : ((float*)Cout)[idx];
        if (EPI == 4 || EPI == 5) {
          if (isbf) ((bf16*)Cout)[idx] = (bf16)v;
          else      ((float*)Cout)[idx] = v;
        } else {
          ((bf16*)Cout)[idx] = (bf16)v;
        }
      }
    }
  }
}

// ------- fused q/k/v projection, z=2 computes V^T directly (bias per row) ------
struct QkvArgs {
  const bf16* A[3];
  const bf16* Bt[3];
  const bf16* bias[3];
  bf16* C[3];
  int K[3], ldc[3], gx[3], gy[3], brow[3];
};
__global__ __launch_bounds__(512) void gemm128db_qkv(QkvArgs a) {
  const int z = blockIdx.z;
  if ((int)blockIdx.x >= a.gx[z] || (int)blockIdx.y >= a.gy[z]) return;
  const bf16* A = a.A[z];
  const bf16* Bt = a.Bt[z];
  const int K = a.K[z];
  __shared__ __align__(16) bf16 As[2][128 * 64];
  __shared__ __align__(16) bf16 Bs[2][128 * 64];
  const int tid = threadIdx.x;
  const int lane = tid & 63, wv = tid >> 6;
  const int lq = lane >> 4, lm = lane & 15;
  const int row0 = blockIdx.y * 128, col0 = blockIdx.x * 128;
  const int wm = (wv >> 2) * 64, wn = (wv & 3) * 32;

  const int sr = lane >> 3;
  const int sc = ((lane & 7) ^ sr) * 8;
  const int swz = (lm & 7) << 3;

  f32x4 acc[4][2] = {};

  const bf16* Abase = A + (size_t)(row0 + wv * 16 + sr) * K + sc;
  const bf16* Bbase = Bt + (size_t)(col0 + wv * 16 + sr) * K + sc;

  const int nt = K >> 6;
#pragma unroll
  for (int b = 0; b < 2; b++) {
    async16(Abase + (size_t)(b * 8) * K, &As[0][wv * 1024 + b * 512]);
    async16(Bbase + (size_t)(b * 8) * K, &Bs[0][wv * 1024 + b * 512]);
  }
  __syncthreads();

  int cur = 0;
  for (int t = 0; t < nt; ++t) {
    if (t + 1 < nt) {
      const int k1 = (t + 1) << 6;
#pragma unroll
      for (int b = 0; b < 2; b++) {
        async16(Abase + (size_t)(b * 8) * K + k1, &As[cur ^ 1][wv * 1024 + b * 512]);
        async16(Bbase + (size_t)(b * 8) * K + k1, &Bs[cur ^ 1][wv * 1024 + b * 512]);
      }
    }
#pragma unroll
    for (int kh = 0; kh < 2; kh++) {
      const int cofs = (kh * 32 + lq * 8) ^ swz;
      bf16x8 af[4], bfv[2];
#pragma unroll
      for (int i = 0; i < 4; i++)
        af[i] = *(const bf16x8*)&As[cur][(wm + i * 16 + lm) * 64 + cofs];
#pragma unroll
      for (int j = 0; j < 2; j++)
        bfv[j] = *(const bf16x8*)&Bs[cur][(wn + j * 16 + lm) * 64 + cofs];
#pragma unroll
      for (int i = 0; i < 4; i++)
#pragma unroll
        for (int j = 0; j < 2; j++)
          acc[i][j] = __builtin_amdgcn_mfma_f32_16x16x32_bf16(af[i], bfv[j], acc[i][j], 0, 0, 0);
    }
    __syncthreads();
    cur ^= 1;
  }

  const bf16* bias = a.bias[z];
  bf16* C = a.C[z];
  const int ldc = a.ldc[z];
  const bool brow = a.brow[z] != 0;
#pragma unroll
  for (int i = 0; i < 4; i++) {
    const int rb = row0 + wm + i * 16 + lq * 4;
#pragma unroll
    for (int j = 0; j < 2; j++) {
      const int c = col0 + wn + j * 16 + lm;
      const float bcol = brow ? 0.f : (float)bias[c];
#pragma unroll
      for (int rg = 0; rg < 4; rg++) {
        const float bv = brow ? (float)bias[rb + rg] : bcol;
        C[(size_t)(rb + rg) * ldc + c] = (bf16)(acc[i][j][rg] + bv);
      }
    }
  }
}

// ---------------- Flash attention v7: split-M over grid.z (2 halves) ----------
// Each block does 64 q-rows x 1 head x M/2 context, writing UNNORMALIZED partial
// O^T (bf16) + partial row-sums (fp32). Combine kernel merges. 1024 blocks ->
// 4 blocks/CU (was grid-limited at 2). Bounded scores -> no running max.
#define KS_STR 72
#define VS_STR 136
__global__ __launch_bounds__(256) void attn_kernel(
    const bf16* __restrict__ q, const bf16* __restrict__ k,
    const bf16* __restrict__ vT, bf16* __restrict__ pO0, bf16* __restrict__ pO1,
    float* __restrict__ l0, float* __restrict__ l1) {
  __shared__ __align__(16) bf16 KPs[128 * KS_STR];  // Ks [128][64]+pad, then P^T
  __shared__ __align__(16) bf16 Vs[64 * VS_STR];    // [d 64][m 128]+pad
  const int tid = threadIdx.x, lane = tid & 63, wv = tid >> 6;
  const int lq = lane >> 4, lm = lane & 15;
  const int h = blockIdx.y;
  const int n0 = blockIdx.x * 64;
  const int half = blockIdx.z;
  const int mbeg = half * (M_TOK / 2), mend = mbeg + M_TOK / 2;
  bf16* pO = half ? pO1 : pO0;
  float* lb = half ? l1 : l0;

  bf16x8 qf[2];
#pragma unroll
  for (int f = 0; f < 2; f++)
    qf[f] = *(const bf16x8*)&q[(size_t)(n0 + wv * 16 + lm) * DIM + h * 64 + f * 32 + lq * 8];

  f32x4 oacc[4] = {};  // O^T tiles: rows d, cols n
  float lsum = 0.f;
  const float sc = 0.125f * 1.4426950408889634f;  // (1/sqrt(64)) * log2(e)

  for (int m0 = mbeg; m0 < mend; m0 += 128) {
    __syncthreads();
#pragma unroll
    for (int it = 0; it < 4; it++) {  // Ks [128][64] stride 72
      const int e = tid * 8 + it * 2048;
      const int r = e >> 6, c = e & 63;
      *(bf16x8*)&KPs[r * KS_STR + c] =
          *(const bf16x8*)&k[(size_t)(m0 + r) * DIM + h * 64 + c];
    }
#pragma unroll
    for (int it = 0; it < 4; it++) {  // Vs [64][128] stride 136
      const int e = tid * 8 + it * 2048;
      const int r = e >> 7, c = e & 127;
      *(bf16x8*)&Vs[r * VS_STR + c] =
          *(const bf16x8*)&vT[(size_t)(h * 64 + r) * M_TOK + m0 + c];
    }
    __syncthreads();

    // S^T into regs: tile j rows m = j*16+lq*4+rg, col n = wv*16 + (lane&15)
    f32x4 s[8];
#pragma unroll
    for (int j = 0; j < 8; j++) {
      bf16x8 kf0 = *(const bf16x8*)&KPs[(j * 16 + lm) * KS_STR + lq * 8];
      bf16x8 kf1 = *(const bf16x8*)&KPs[(j * 16 + lm) * KS_STR + 32 + lq * 8];
      f32x4 z = {};
      z = __builtin_amdgcn_mfma_f32_16x16x32_bf16(kf0, qf[0], z, 0, 0, 0);
      s[j] = __builtin_amdgcn_mfma_f32_16x16x32_bf16(kf1, qf[1], z, 0, 0, 0);
    }
    __syncthreads();  // every wave done reading Ks; region becomes P^T

#pragma unroll
    for (int j = 0; j < 8; j++) {
      bf16x4 pw;
#pragma unroll
      for (int rg = 0; rg < 4; rg++) {
        const float pv = exp2f(s[j][rg] * sc);
        lsum += pv;
        pw[rg] = (bf16)pv;
      }
      *(bf16x4*)&KPs[(wv * 16 + lm) * VS_STR + j * 16 + lq * 4] = pw;
    }

    // O^T += V^T P^T (pf rows are this wave's own -> same-wave RAW, lgkmcnt)
#pragma unroll
    for (int kk = 0; kk < 4; kk++) {
      bf16x8 pf = *(const bf16x8*)&KPs[(wv * 16 + lm) * VS_STR + kk * 32 + lq * 8];
#pragma unroll
      for (int dt = 0; dt < 4; dt++) {
        bf16x8 vf = *(const bf16x8*)&Vs[(dt * 16 + lm) * VS_STR + kk * 32 + lq * 8];
        oacc[dt] = __builtin_amdgcn_mfma_f32_16x16x32_bf16(vf, pf, oacc[dt], 0, 0, 0);
      }
    }
  }

  // partial row-sum: reduce over the 4 lanes sharing this n (lane bits 4..5)
  lsum += __shfl_xor(lsum, 16, 64);
  lsum += __shfl_xor(lsum, 32, 64);
  if (lane < 16) lb[h * N_TOK + n0 + wv * 16 + lane] = lsum;

  const int rn = n0 + wv * 16 + lm;
#pragma unroll
  for (int dt = 0; dt < 4; dt++) {
    bf16x4 ow;
#pragma unroll
    for (int rg = 0; rg < 4; rg++) ow[rg] = (bf16)oacc[dt][rg];
    *(bf16x4*)&pO[(size_t)rn * DIM + h * 64 + dt * 16 + lq * 4] = ow;
  }
}

// ---------------- combine: om = (pO0 + pO1) / (l0 + l1) ----------------
__global__ __launch_bounds__(256) void attn_combine(
    const bf16* __restrict__ pO0, const bf16* __restrict__ pO1,
    const float* __restrict__ l0, const float* __restrict__ l1,
    bf16* __restrict__ om) {
  const int i4 = (blockIdx.x * 256 + threadIdx.x) * 4;  // over N*DIM = 2M elems
  const int n = i4 >> 10;
  const int h = (i4 & 1023) >> 6;
  const float rinv = 1.f / (l0[h * N_TOK + n] + l1[h * N_TOK + n]);
  bf16x4 a = *(const bf16x4*)&pO0[i4];
  bf16x4 b = *(const bf16x4*)&pO1[i4];
  bf16x4 o;
#pragma unroll
  for (int r = 0; r < 4; r++) o[r] = (bf16)(((float)a[r] + (float)b[r]) * rinv);
  *(bf16x4*)&om[i4] = o;
}

extern "C" void kernel_launch(void* const* d_in, const int* in_sizes, int n_in,
                              void* d_out, int out_size, void* d_ws, size_t ws_size,
                              hipStream_t stream) {
  const void* x_r     = d_in[0];
  const void* ctx_r   = d_in[1];
  const void* wq_r    = d_in[2];
  const void* bq_r    = d_in[3];
  const void* wk_r    = d_in[4];
  const void* bk_r    = d_in[5];
  const void* wv_r    = d_in[6];
  const void* bv_r    = d_in[7];
  const void* wo_r    = d_in[8];
  const void* bo_r    = d_in[9];
  const void* w1_r    = d_in[10];
  const void* b1_r    = d_in[11];
  const void* w2_r    = d_in[12];
  const void* b2_r    = d_in[13];
  const void* qnw_r   = d_in[14];
  const void* qnb_r   = d_in[15];
  const void* kvnw_r  = d_in[16];
  const void* kvnb_r  = d_in[17];
  const void* pnw_r   = d_in[18];
  const void* pnb_r   = d_in[19];

  // ---- workspace carve: 14M bf16 elems + smalls (~28.0 MB, known-good) ----
  // [0,2M) qm->hln | [2M,4M) km->xat | [4M,8M) weights (wqT/wkT/wvT/woT, then
  //   w1Th/w2Th; l0/l1 park in dead wqT after qkv) | [8M,10M) xq->pO0->om |
  // [10M,12M) vTb | [12M,14M) kvn->pO1 ; h1h spans [10M,14M) in MLP phase
  bf16* p = (bf16*)d_ws;
  const size_t MEG = 1024 * 1024;
  bf16* qm  = p;             bf16* hln = qm;
  bf16* km  = p + 2 * MEG;   bf16* xat = km;
  bf16* wC  = p + 4 * MEG;
  bf16* xq  = p + 8 * MEG;   bf16* pO0 = xq;   bf16* om = xq;
  bf16* vTb = p + 10 * MEG;
  bf16* kvn = p + 12 * MEG;  bf16* pO1 = kvn;
  bf16* h1h = p + 10 * MEG;  // MLP h1 half spans [10M,14M)
  bf16* SM  = p + 14 * MEG;
  int* flag = (int*)(p + 14 * MEG + 16384);

  bf16* wqT = wC;
  bf16* wkT = wC + 1 * MEG;
  bf16* wvT = wC + 1 * MEG + 786432;
  bf16* woT = wC + 2 * MEG + 524288;
  bf16* w1Th = wC;
  bf16* w2Th = wC + 2 * MEG;
  float* l0 = (float*)wC;        // parks in dead wqT region after qkv (128 KB)
  float* l1 = l0 + N_TOK * 16;   // 32768 floats each

  bf16* bqc = SM, *bkc = SM + 1024, *bvc = SM + 2048, *boc = SM + 3072;
  bf16* b1c = SM + 4096, *b2c = SM + 8192;
  bf16* qnw = SM + 9216, *qnb = SM + 10240;
  bf16* kvnw = SM + 11264, *kvnb = SM + 12032;
  bf16* pnw = SM + 12800, *pnb = SM + 13824;

  // 0) dtype detection + batched small-vector conversion
  detect_kernel<<<1, 256, 0, stream>>>(x_r, flag);
  ConvArgs ca;
  ca.src[0] = bq_r;   ca.dst[0] = bqc;  ca.n[0] = DIM;
  ca.src[1] = bk_r;   ca.dst[1] = bkc;  ca.n[1] = DIM;
  ca.src[2] = bv_r;   ca.dst[2] = bvc;  ca.n[2] = DIM;
  ca.src[3] = bo_r;   ca.dst[3] = boc;  ca.n[3] = DIM;
  ca.src[4] = b1_r;   ca.dst[4] = b1c;  ca.n[4] = DFF;
  ca.src[5] = b2_r;   ca.dst[5] = b2c;  ca.n[5] = DIM;
  ca.src[6] = qnw_r;  ca.dst[6] = qnw;  ca.n[6] = DIM;
  ca.src[7] = qnb_r;  ca.dst[7] = qnb;  ca.n[7] = DIM;
  ca.src[8] = kvnw_r; ca.dst[8] = kvnw; ca.n[8] = CDIM;
  ca.src[9] = kvnb_r; ca.dst[9] = kvnb; ca.n[9] = CDIM;
  ca.src[10] = pnw_r; ca.dst[10] = pnw; ca.n[10] = DIM;
  ca.src[11] = pnb_r; ca.dst[11] = pnb; ca.n[11] = DIM;
  conv_small_kernel<<<12, 256, 0, stream>>>(ca, flag);

  // 1) both input layernorms in one launch
  ln_pair_kernel<<<dim3(2048, 2), 256, 0, stream>>>(x_r, qnw, qnb, xq,
                                                    ctx_r, kvnw, kvnb, kvn, flag);

  // 2) all four attention weight transposes in one launch
  {
    TmArgs ta;
    ta.force_bf = 0;
    ta.src[0] = wq_r; ta.dst[0] = wqT; ta.r0[0] = 0; ta.Rcnt[0] = DIM;
    ta.c0[0] = 0; ta.Cfull[0] = DIM; ta.gx[0] = 32; ta.gy[0] = 32;
    ta.src[1] = wk_r; ta.dst[1] = wkT; ta.r0[1] = 0; ta.Rcnt[1] = CDIM;
    ta.c0[1] = 0; ta.Cfull[1] = DIM; ta.gx[1] = 32; ta.gy[1] = 24;
    ta.src[2] = wv_r; ta.dst[2] = wvT; ta.r0[2] = 0; ta.Rcnt[2] = CDIM;
    ta.c0[2] = 0; ta.Cfull[2] = DIM; ta.gx[2] = 32; ta.gy[2] = 24;
    ta.src[3] = wo_r; ta.dst[3] = woT; ta.r0[3] = 0; ta.Rcnt[3] = DIM;
    ta.c0[3] = 0; ta.Cfull[3] = DIM; ta.gx[3] = 32; ta.gy[3] = 32;
    tmulti_kernel<<<dim3(32, 32, 4), 256, 0, stream>>>(ta, flag);
  }

  // 3) fused q/k/v; z=2 emits V^T directly (A=wvT rows d, Bt=kvn rows m)
  {
    QkvArgs qa;
    qa.A[0] = xq;  qa.Bt[0] = wqT; qa.bias[0] = bqc; qa.C[0] = qm;
    qa.K[0] = DIM;  qa.ldc[0] = DIM;   qa.gx[0] = 8;  qa.gy[0] = 16; qa.brow[0] = 0;
    qa.A[1] = kvn; qa.Bt[1] = wkT; qa.bias[1] = bkc; qa.C[1] = km;
    qa.K[1] = CDIM; qa.ldc[1] = DIM;   qa.gx[1] = 8;  qa.gy[1] = 16; qa.brow[1] = 0;
    qa.A[2] = wvT; qa.Bt[2] = kvn; qa.bias[2] = bvc; qa.C[2] = vTb;
    qa.K[2] = CDIM; qa.ldc[2] = M_TOK; qa.gx[2] = 16; qa.gy[2] = 8;  qa.brow[2] = 1;
    gemm128db_qkv<<<dim3(16, 16, 3), 512, 0, stream>>>(qa);
  }

  // 4) attention split-M (1024 blocks) + combine
  attn_kernel<<<dim3(32, 16, 2), 256, 0, stream>>>(qm, km, vTb, pO0, pO1, l0, l1);
  attn_combine<<<2048, 256, 0, stream>>>(pO0, pO1, l0, l1, om);

  // 5) o-projection + raw-dtype residual(x)
  gemm128db<1><<<dim3(8, 16), 512, 0, stream>>>(om, woT, boc, x_r, xat, DIM, DIM, flag);

  // 6) post-norm
  ln_kernel<<<N_TOK, 256, 0, stream>>>(xat, pnw, pnb, hln, DIM);

  // 7) MLP split over DFF halves; final writes d_out in raw dtype
  for (int hh = 0; hh < 2; hh++) {
    TmArgs ta;
    ta.force_bf = 0;
    ta.src[0] = w1_r; ta.dst[0] = w1Th; ta.r0[0] = 0; ta.Rcnt[0] = DIM;
    ta.c0[0] = hh * 2048; ta.Cfull[0] = DFF; ta.gx[0] = 64; ta.gy[0] = 32;
    ta.src[1] = w2_r; ta.dst[1] = w2Th; ta.r0[1] = hh * 2048; ta.Rcnt[1] = 2048;
    ta.c0[1] = 0; ta.Cfull[1] = DIM; ta.gx[1] = 32; ta.gy[1] = 64;
    ta.src[2] = ta.src[0]; ta.dst[2] = ta.dst[0]; ta.r0[2] = 0; ta.Rcnt[2] = 32;
    ta.c0[2] = 0; ta.Cfull[2] = DIM; ta.gx[2] = 0; ta.gy[2] = 0;
    ta.src[3] = ta.src[0]; ta.dst[3] = ta.dst[0]; ta.r0[3] = 0; ta.Rcnt[3] = 32;
    ta.c0[3] = 0; ta.Cfull[3] = DIM; ta.gx[3] = 0; ta.gy[3] = 0;
    tmulti_kernel<<<dim3(64, 64, 2), 256, 0, stream>>>(ta, flag);

    // MLP1 half: [2048]x[2048], 256 blocks of 128x128
    gemm128db<2><<<dim3(16, 16), 512, 0, stream>>>(hln, w1Th, b1c + hh * 2048, nullptr,
                                                   h1h, DIM, 2048, flag);
    // MLP2 half: [2048]x[1024], 128 blocks of 128x128
    if (hh == 0)
      gemm128db<4><<<dim3(8, 16), 512, 0, stream>>>(h1h, w2Th, b2c, xat, d_out,
                                                    2048, DIM, flag);
    else
      gemm128db<5><<<dim3(8, 16), 512, 0, stream>>>(h1h, w2Th, b2c, nullptr, d_out,
                                                    2048, DIM, flag);
  }
}

// Round 4
// 358.063 us; speedup vs baseline: 1.2297x; 1.1062x over previous
//
#include <hip/hip_runtime.h>

typedef __bf16 bf16;
typedef __bf16 bf16x4 __attribute__((ext_vector_type(4)));
typedef __bf16 bf16x8 __attribute__((ext_vector_type(8)));
typedef float f32x4 __attribute__((ext_vector_type(4)));

#define N_TOK 2048
#define M_TOK 2048
#define DIM 1024
#define CDIM 768
#define DFF 4096

// async global->LDS, 16B per lane; LDS dest = wave-uniform base + lane*16
static __device__ __forceinline__ void async16(const void* g, void* l) {
  __builtin_amdgcn_global_load_lds((const __attribute__((address_space(1))) void*)g,
                                   (__attribute__((address_space(3))) void*)l, 16, 0, 0);
}

// ---------- dtype detector: low-16 halves plausible as bf16? ----------
__global__ __launch_bounds__(256) void detect_kernel(const void* x, int* flag) {
  __shared__ int cnt;
  if (threadIdx.x == 0) cnt = 0;
  __syncthreads();
  const unsigned* w = (const unsigned*)x;
  int ok = 0;
  for (int i = threadIdx.x; i < 512; i += 256) {
    unsigned lo = w[i] & 0xFFFFu;
    float f = __uint_as_float(lo << 16);
    if (lo == 0u || (fabsf(f) > 1e-3f && fabsf(f) < 1e3f)) ok++;
  }
  atomicAdd(&cnt, ok);
  __syncthreads();
  if (threadIdx.x == 0) *flag = (cnt >= 256) ? 1 : 0;
}

// ---------- batched small-vector conversion ----------
struct ConvArgs {
  const void* src[12];
  bf16* dst[12];
  int n[12];
};
__global__ __launch_bounds__(256) void conv_small_kernel(ConvArgs a, const int* flag) {
  const bool isbf = (*flag != 0);
  const int b = blockIdx.x;
  const void* in = a.src[b];
  bf16* out = a.dst[b];
  const int n = a.n[b];
  for (int i = threadIdx.x; i < n; i += 256)
    out[i] = isbf ? ((const bf16*)in)[i] : (bf16)((const float*)in)[i];
}

// ---------- batched transpose+convert (up to 4 slices via blockIdx.z) ----------
struct TmArgs {
  const void* src[4];
  bf16* dst[4];
  int r0[4], Rcnt[4], c0[4], Cfull[4], gx[4], gy[4];
  int force_bf;
};
__global__ __launch_bounds__(256) void tmulti_kernel(TmArgs a, const int* flag) {
  const int z = blockIdx.z;
  if ((int)blockIdx.x >= a.gx[z] || (int)blockIdx.y >= a.gy[z]) return;
  __shared__ bf16 t[32][33];
  const bool isbf = a.force_bf || (*flag != 0);
  const void* in = a.src[z];
  bf16* out = a.dst[z];
  const int Rcnt = a.Rcnt[z], Cfull = a.Cfull[z];
  const int cb = blockIdx.x * 32, rb = blockIdx.y * 32;
  const int tx = threadIdx.x & 31, ty = threadIdx.x >> 5;
#pragma unroll
  for (int i = 0; i < 4; i++) {
    const size_t r = (size_t)(a.r0[z] + rb + ty + i * 8);
    const size_t c = (size_t)(a.c0[z] + cb + tx);
    float v = isbf ? (float)((const bf16*)in)[r * Cfull + c]
                   : ((const float*)in)[r * Cfull + c];
    t[ty + i * 8][tx] = (bf16)v;
  }
  __syncthreads();
#pragma unroll
  for (int i = 0; i < 4; i++)
    out[(size_t)(cb + ty + i * 8) * Rcnt + rb + tx] = t[tx][ty + i * 8];
}

// ---------------- Fused first-layer LayerNorm pair: y=0 x, y=1 ctx --------------
__global__ __launch_bounds__(256) void ln_pair_kernel(
    const void* __restrict__ x0, const bf16* w0, const bf16* b0, bf16* o0,
    const void* __restrict__ x1, const bf16* w1, const bf16* b1, bf16* o1,
    const int* flag) {
  const bool isbf = (*flag != 0);
  const int cols = (blockIdx.y == 0) ? DIM : CDIM;
  const void* x = (blockIdx.y == 0) ? x0 : x1;
  const bf16* w = (blockIdx.y == 0) ? w0 : w1;
  const bf16* b = (blockIdx.y == 0) ? b0 : b1;
  bf16* outp = (blockIdx.y == 0) ? o0 : o1;
  const int row = blockIdx.x;
  const bf16* xr_b = (const bf16*)x + (size_t)row * cols;
  const float* xr_f = (const float*)x + (size_t)row * cols;
  bf16* orow = outp + (size_t)row * cols;
  float s = 0.f, ss = 0.f;
  for (int c = threadIdx.x; c < cols; c += 256) {
    float v = isbf ? (float)xr_b[c] : xr_f[c];
    s += v; ss += v * v;
  }
  for (int d = 1; d < 64; d <<= 1) { s += __shfl_xor(s, d, 64); ss += __shfl_xor(ss, d, 64); }
  __shared__ float sh[8];
  const int wv = threadIdx.x >> 6, lane = threadIdx.x & 63;
  if (lane == 0) { sh[wv] = s; sh[4 + wv] = ss; }
  __syncthreads();
  s = sh[0] + sh[1] + sh[2] + sh[3];
  ss = sh[4] + sh[5] + sh[6] + sh[7];
  const float mean = s / cols;
  float var = ss / cols - mean * mean;
  var = fmaxf(var, 0.f);
  const float r = rsqrtf(var + 1e-12f);
  for (int c = threadIdx.x; c < cols; c += 256) {
    float v = isbf ? (float)xr_b[c] : xr_f[c];
    orow[c] = (bf16)((v - mean) * r * (float)w[c] + (float)b[c]);
  }
}

// ---------------- LayerNorm (bf16 in, bf16 out) ----------------
__global__ __launch_bounds__(256) void ln_kernel(
    const bf16* __restrict__ x, const bf16* __restrict__ w, const bf16* __restrict__ b,
    bf16* __restrict__ out, int cols) {
  const int row = blockIdx.x;
  const bf16* xr = x + (size_t)row * cols;
  bf16* orow = out + (size_t)row * cols;
  float s = 0.f, ss = 0.f;
  for (int c = threadIdx.x; c < cols; c += 256) {
    float v = (float)xr[c];
    s += v; ss += v * v;
  }
  for (int d = 1; d < 64; d <<= 1) { s += __shfl_xor(s, d, 64); ss += __shfl_xor(ss, d, 64); }
  __shared__ float sh[8];
  const int wv = threadIdx.x >> 6, lane = threadIdx.x & 63;
  if (lane == 0) { sh[wv] = s; sh[4 + wv] = ss; }
  __syncthreads();
  s = sh[0] + sh[1] + sh[2] + sh[3];
  ss = sh[4] + sh[5] + sh[6] + sh[7];
  const float mean = s / cols;
  float var = ss / cols - mean * mean;
  var = fmaxf(var, 0.f);
  const float r = rsqrtf(var + 1e-12f);
  for (int c = threadIdx.x; c < cols; c += 256) {
    float v = (float)xr[c];
    orow[c] = (bf16)((v - mean) * r * (float)w[c] + (float)b[c]);
  }
}

__device__ __forceinline__ float gelu_f(float x) {
  float u = 0.7978845608028654f * (x + 0.044715f * x * x * x);
  return 0.5f * x * (1.f + tanhf(u));
}

// -------- gemm64db: 64x64 tile, BK=64, 256 thr (4 waves 2x2, 32x32/wave) -------
// Round-0 tile/grid (4-5 blocks/CU cross-block TLP) + round-3-verified 2-phase
// double-buffer: next K-tile's global_load_lds issued BEFORE current compute,
// ONE __syncthreads per K-tile. 32 KB LDS -> 5 blocks/CU. Both-sides XOR
// swizzle (LDS linear, source col pre-swizzled, read col XOR (lm&7)<<3).
// EPI: 1 bias + raw-dtype resid -> bf16 out
//      2 bias + gelu -> bf16 out
//      4 bias + bf16 resid -> raw-dtype out
//      5 accumulate from raw out -> raw out (no bias)
template <int EPI>
__global__ __launch_bounds__(256) void gemm64db(
    const bf16* __restrict__ A, const bf16* __restrict__ Bt,
    const bf16* __restrict__ bias, const void* __restrict__ resid,
    void* __restrict__ Cout, int K, int ldc, const int* flag) {
  __shared__ __align__(16) bf16 As[2][64 * 64];
  __shared__ __align__(16) bf16 Bs[2][64 * 64];
  const int tid = threadIdx.x;
  const int lane = tid & 63, wv = tid >> 6;
  const int lq = lane >> 4, lm = lane & 15;
  const int row0 = blockIdx.y * 64, col0 = blockIdx.x * 64;
  const int wr = (wv >> 1) * 32, wc = (wv & 1) * 32;

  const int sr = lane >> 3;              // staging row within 8-row group
  const int sc = ((lane & 7) ^ sr) * 8;  // pre-swizzled source col (elems)
  const int swz = (lm & 7) << 3;         // read-side XOR (elems)

  f32x4 acc[2][2] = {};

  // wave wv stages rows [wv*16, wv*16+16) of each operand (2 async16 each)
  const bf16* Abase = A + (size_t)(row0 + wv * 16 + sr) * K + sc;
  const bf16* Bbase = Bt + (size_t)(col0 + wv * 16 + sr) * K + sc;

  const int nt = K >> 6;
#pragma unroll
  for (int b = 0; b < 2; b++) {
    async16(Abase + (size_t)(b * 8) * K, &As[0][wv * 1024 + b * 512]);
    async16(Bbase + (size_t)(b * 8) * K, &Bs[0][wv * 1024 + b * 512]);
  }
  __syncthreads();

  int cur = 0;
  for (int t = 0; t < nt; ++t) {
    if (t + 1 < nt) {  // prefetch next tile; loads fly under the MFMA phase
      const int k1 = (t + 1) << 6;
#pragma unroll
      for (int b = 0; b < 2; b++) {
        async16(Abase + (size_t)(b * 8) * K + k1, &As[cur ^ 1][wv * 1024 + b * 512]);
        async16(Bbase + (size_t)(b * 8) * K + k1, &Bs[cur ^ 1][wv * 1024 + b * 512]);
      }
    }
#pragma unroll
    for (int kh = 0; kh < 2; kh++) {
      const int cofs = (kh * 32 + lq * 8) ^ swz;
      bf16x8 af[2], bfv[2];
#pragma unroll
      for (int i = 0; i < 2; i++)
        af[i] = *(const bf16x8*)&As[cur][(wr + i * 16 + lm) * 64 + cofs];
#pragma unroll
      for (int j = 0; j < 2; j++)
        bfv[j] = *(const bf16x8*)&Bs[cur][(wc + j * 16 + lm) * 64 + cofs];
#pragma unroll
      for (int i = 0; i < 2; i++)
#pragma unroll
        for (int j = 0; j < 2; j++)
          acc[i][j] = __builtin_amdgcn_mfma_f32_16x16x32_bf16(af[i], bfv[j], acc[i][j], 0, 0, 0);
    }
    __syncthreads();  // drains prefetch vmcnt + this tile's lgkm reads
    cur ^= 1;
  }

  const bool isbf = (*flag != 0);
#pragma unroll
  for (int i = 0; i < 2; i++) {
    const int rb = row0 + wr + i * 16 + lq * 4;
#pragma unroll
    for (int j = 0; j < 2; j++) {
      const int c = col0 + wc + j * 16 + lm;
      const float bv = (EPI != 5) ? (float)bias[c] : 0.f;
#pragma unroll
      for (int rg = 0; rg < 4; rg++) {
        const size_t idx = (size_t)(rb + rg) * ldc + c;
        float v = acc[i][j][rg] + bv;
        if (EPI == 1)
          v += isbf ? (float)((const bf16*)resid)[idx] : ((const float*)resid)[idx];
        if (EPI == 2) v = gelu_f(v);
        if (EPI == 4) v += (float)((const bf16*)resid)[idx];
        if (EPI == 5)
          v += isbf ? (float)((bf16*)Cout)[idx] : ((float*)Cout)[idx];
        if (EPI == 4 || EPI == 5) {
          if (isbf) ((bf16*)Cout)[idx] = (bf16)v;
          else      ((float*)Cout)[idx] = v;
        } else {
          ((bf16*)Cout)[idx] = (bf16)v;
        }
      }
    }
  }
}

// ------- fused q/k/v projection, z=2 computes V^T directly (bias per row) ------
struct QkvArgs {
  const bf16* A[3];
  const bf16* Bt[3];
  const bf16* bias[3];
  bf16* C[3];
  int K[3], ldc[3], gx[3], gy[3], brow[3];
};
__global__ __launch_bounds__(256) void gemm64db_qkv(QkvArgs a) {
  const int z = blockIdx.z;
  if ((int)blockIdx.x >= a.gx[z] || (int)blockIdx.y >= a.gy[z]) return;
  const bf16* A = a.A[z];
  const bf16* Bt = a.Bt[z];
  const int K = a.K[z];
  __shared__ __align__(16) bf16 As[2][64 * 64];
  __shared__ __align__(16) bf16 Bs[2][64 * 64];
  const int tid = threadIdx.x;
  const int lane = tid & 63, wv = tid >> 6;
  const int lq = lane >> 4, lm = lane & 15;
  const int row0 = blockIdx.y * 64, col0 = blockIdx.x * 64;
  const int wr = (wv >> 1) * 32, wc = (wv & 1) * 32;

  const int sr = lane >> 3;
  const int sc = ((lane & 7) ^ sr) * 8;
  const int swz = (lm & 7) << 3;

  f32x4 acc[2][2] = {};

  const bf16* Abase = A + (size_t)(row0 + wv * 16 + sr) * K + sc;
  const bf16* Bbase = Bt + (size_t)(col0 + wv * 16 + sr) * K + sc;

  const int nt = K >> 6;
#pragma unroll
  for (int b = 0; b < 2; b++) {
    async16(Abase + (size_t)(b * 8) * K, &As[0][wv * 1024 + b * 512]);
    async16(Bbase + (size_t)(b * 8) * K, &Bs[0][wv * 1024 + b * 512]);
  }
  __syncthreads();

  int cur = 0;
  for (int t = 0; t < nt; ++t) {
    if (t + 1 < nt) {
      const int k1 = (t + 1) << 6;
#pragma unroll
      for (int b = 0; b < 2; b++) {
        async16(Abase + (size_t)(b * 8) * K + k1, &As[cur ^ 1][wv * 1024 + b * 512]);
        async16(Bbase + (size_t)(b * 8) * K + k1, &Bs[cur ^ 1][wv * 1024 + b * 512]);
      }
    }
#pragma unroll
    for (int kh = 0; kh < 2; kh++) {
      const int cofs = (kh * 32 + lq * 8) ^ swz;
      bf16x8 af[2], bfv[2];
#pragma unroll
      for (int i = 0; i < 2; i++)
        af[i] = *(const bf16x8*)&As[cur][(wr + i * 16 + lm) * 64 + cofs];
#pragma unroll
      for (int j = 0; j < 2; j++)
        bfv[j] = *(const bf16x8*)&Bs[cur][(wc + j * 16 + lm) * 64 + cofs];
#pragma unroll
      for (int i = 0; i < 2; i++)
#pragma unroll
        for (int j = 0; j < 2; j++)
          acc[i][j] = __builtin_amdgcn_mfma_f32_16x16x32_bf16(af[i], bfv[j], acc[i][j], 0, 0, 0);
    }
    __syncthreads();
    cur ^= 1;
  }

  const bf16* bias = a.bias[z];
  bf16* C = a.C[z];
  const int ldc = a.ldc[z];
  const bool brow = a.brow[z] != 0;
#pragma unroll
  for (int i = 0; i < 2; i++) {
    const int rb = row0 + wr + i * 16 + lq * 4;
#pragma unroll
    for (int j = 0; j < 2; j++) {
      const int c = col0 + wc + j * 16 + lm;
      const float bcol = brow ? 0.f : (float)bias[c];
#pragma unroll
      for (int rg = 0; rg < 4; rg++) {
        const float bv = brow ? (float)bias[rb + rg] : bcol;
        C[(size_t)(rb + rg) * ldc + c] = (bf16)(acc[i][j][rg] + bv);
      }
    }
  }
}

// ---------------- Flash attention v8: split-M + XOR-swizzled LDS --------------
// Pads replaced by XOR swizzle col^=(row&7)<<3 (all stores AND loads), which
// spreads every b128 access across all 32 banks (old pads 72/136 gave stride
// ≡4 dwords mod 32 -> 8-way conflicts, 5.77M/dispatch). LDS 35840 -> 32768 B.
__global__ __launch_bounds__(256) void attn_kernel(
    const bf16* __restrict__ q, const bf16* __restrict__ k,
    const bf16* __restrict__ vT, bf16* __restrict__ pO0, bf16* __restrict__ pO1,
    float* __restrict__ l0, float* __restrict__ l1) {
  __shared__ __align__(16) bf16 KPs[128 * 64];  // Ks [128][64]; then P^T [64][128]
  __shared__ __align__(16) bf16 Vs[64 * 128];   // [d 64][m 128]
  const int tid = threadIdx.x, lane = tid & 63, wv = tid >> 6;
  const int lq = lane >> 4, lm = lane & 15;
  const int h = blockIdx.y;
  const int n0 = blockIdx.x * 64;
  const int half = blockIdx.z;
  const int mbeg = half * (M_TOK / 2), mend = mbeg + M_TOK / 2;
  bf16* pO = half ? pO1 : pO0;
  float* lb = half ? l1 : l0;

  bf16x8 qf[2];
#pragma unroll
  for (int f = 0; f < 2; f++)
    qf[f] = *(const bf16x8*)&q[(size_t)(n0 + wv * 16 + lm) * DIM + h * 64 + f * 32 + lq * 8];

  f32x4 oacc[4] = {};  // O^T tiles: rows d, cols n
  float lsum = 0.f;
  const float sc = 0.125f * 1.4426950408889634f;  // (1/sqrt(64)) * log2(e)

  for (int m0 = mbeg; m0 < mend; m0 += 128) {
    __syncthreads();
#pragma unroll
    for (int it = 0; it < 4; it++) {  // Ks [128][64], swizzled store
      const int e = tid * 8 + it * 2048;
      const int r = e >> 6, c = e & 63;
      *(bf16x8*)&KPs[r * 64 + (c ^ ((r & 7) << 3))] =
          *(const bf16x8*)&k[(size_t)(m0 + r) * DIM + h * 64 + c];
    }
#pragma unroll
    for (int it = 0; it < 4; it++) {  // Vs [64][128], swizzled store
      const int e = tid * 8 + it * 2048;
      const int r = e >> 7, c = e & 127;
      *(bf16x8*)&Vs[r * 128 + (c ^ ((r & 7) << 3))] =
          *(const bf16x8*)&vT[(size_t)(h * 64 + r) * M_TOK + m0 + c];
    }
    __syncthreads();

    // S^T into regs: tile j rows m = j*16+lq*4+rg, col n = wv*16 + (lane&15)
    f32x4 s[8];
#pragma unroll
    for (int j = 0; j < 8; j++) {
      const int kswz = (lm & 7) << 3;  // row = j*16+lm -> row&7 = lm&7
      bf16x8 kf0 = *(const bf16x8*)&KPs[(j * 16 + lm) * 64 + ((lq * 8) ^ kswz)];
      bf16x8 kf1 = *(const bf16x8*)&KPs[(j * 16 + lm) * 64 + ((32 + lq * 8) ^ kswz)];
      f32x4 z = {};
      z = __builtin_amdgcn_mfma_f32_16x16x32_bf16(kf0, qf[0], z, 0, 0, 0);
      s[j] = __builtin_amdgcn_mfma_f32_16x16x32_bf16(kf1, qf[1], z, 0, 0, 0);
    }
    __syncthreads();  // every wave done reading Ks; region becomes P^T [64][128]

#pragma unroll
    for (int j = 0; j < 8; j++) {
      bf16x4 pw;
#pragma unroll
      for (int rg = 0; rg < 4; rg++) {
        const float pv = exp2f(s[j][rg] * sc);
        lsum += pv;
        pw[rg] = (bf16)pv;
      }
      // P^T row = wv*16+lm (row&7 = lm&7), col = j*16+lq*4; swizzled b64 write
      *(bf16x4*)&KPs[(wv * 16 + lm) * 128 + ((j * 16 + lq * 4) ^ ((lm & 7) << 3))] = pw;
    }

    // O^T += V^T P^T (pf rows are this wave's own -> same-wave RAW, lgkmcnt)
#pragma unroll
    for (int kk = 0; kk < 4; kk++) {
      bf16x8 pf = *(const bf16x8*)&KPs[(wv * 16 + lm) * 128 +
                                       ((kk * 32 + lq * 8) ^ ((lm & 7) << 3))];
#pragma unroll
      for (int dt = 0; dt < 4; dt++) {
        bf16x8 vf = *(const bf16x8*)&Vs[(dt * 16 + lm) * 128 +
                                        ((kk * 32 + lq * 8) ^ ((lm & 7) << 3))];
        oacc[dt] = __builtin_amdgcn_mfma_f32_16x16x32_bf16(vf, pf, oacc[dt], 0, 0, 0);
      }
    }
  }

  // partial row-sum: reduce over the 4 lanes sharing this n (lane bits 4..5)
  lsum += __shfl_xor(lsum, 16, 64);
  lsum += __shfl_xor(lsum, 32, 64);
  if (lane < 16) lb[h * N_TOK + n0 + wv * 16 + lane] = lsum;

  const int rn = n0 + wv * 16 + lm;
#pragma unroll
  for (int dt = 0; dt < 4; dt++) {
    bf16x4 ow;
#pragma unroll
    for (int rg = 0; rg < 4; rg++) ow[rg] = (bf16)oacc[dt][rg];
    *(bf16x4*)&pO[(size_t)rn * DIM + h * 64 + dt * 16 + lq * 4] = ow;
  }
}

// ---------------- combine: om = (pO0 + pO1) / (l0 + l1) ----------------
__global__ __launch_bounds__(256) void attn_combine(
    const bf16* __restrict__ pO0, const bf16* __restrict__ pO1,
    const float* __restrict__ l0, const float* __restrict__ l1,
    bf16* __restrict__ om) {
  const int i4 = (blockIdx.x * 256 + threadIdx.x) * 4;  // over N*DIM = 2M elems
  const int n = i4 >> 10;
  const int h = (i4 & 1023) >> 6;
  const float rinv = 1.f / (l0[h * N_TOK + n] + l1[h * N_TOK + n]);
  bf16x4 a = *(const bf16x4*)&pO0[i4];
  bf16x4 b = *(const bf16x4*)&pO1[i4];
  bf16x4 o;
#pragma unroll
  for (int r = 0; r < 4; r++) o[r] = (bf16)(((float)a[r] + (float)b[r]) * rinv);
  *(bf16x4*)&om[i4] = o;
}

extern "C" void kernel_launch(void* const* d_in, const int* in_sizes, int n_in,
                              void* d_out, int out_size, void* d_ws, size_t ws_size,
                              hipStream_t stream) {
  const void* x_r     = d_in[0];
  const void* ctx_r   = d_in[1];
  const void* wq_r    = d_in[2];
  const void* bq_r    = d_in[3];
  const void* wk_r    = d_in[4];
  const void* bk_r    = d_in[5];
  const void* wv_r    = d_in[6];
  const void* bv_r    = d_in[7];
  const void* wo_r    = d_in[8];
  const void* bo_r    = d_in[9];
  const void* w1_r    = d_in[10];
  const void* b1_r    = d_in[11];
  const void* w2_r    = d_in[12];
  const void* b2_r    = d_in[13];
  const void* qnw_r   = d_in[14];
  const void* qnb_r   = d_in[15];
  const void* kvnw_r  = d_in[16];
  const void* kvnb_r  = d_in[17];
  const void* pnw_r   = d_in[18];
  const void* pnb_r   = d_in[19];

  // ---- workspace carve: 14M bf16 elems + smalls (~28.0 MB, known-good) ----
  // [0,2M) qm->hln | [2M,4M) km->xat | [4M,8M) weights (wqT/wkT/wvT/woT, then
  //   w1Th/w2Th; l0/l1 park in dead wqT after qkv) | [8M,10M) xq->pO0->om |
  // [10M,12M) vTb | [12M,14M) kvn->pO1 ; h1h spans [10M,14M) in MLP phase
  bf16* p = (bf16*)d_ws;
  const size_t MEG = 1024 * 1024;
  bf16* qm  = p;             bf16* hln = qm;
  bf16* km  = p + 2 * MEG;   bf16* xat = km;
  bf16* wC  = p + 4 * MEG;
  bf16* xq  = p + 8 * MEG;   bf16* pO0 = xq;   bf16* om = xq;
  bf16* vTb = p + 10 * MEG;
  bf16* kvn = p + 12 * MEG;  bf16* pO1 = kvn;
  bf16* h1h = p + 10 * MEG;  // MLP h1 half spans [10M,14M)
  bf16* SM  = p + 14 * MEG;
  int* flag = (int*)(p + 14 * MEG + 16384);

  bf16* wqT = wC;
  bf16* wkT = wC + 1 * MEG;
  bf16* wvT = wC + 1 * MEG + 786432;
  bf16* woT = wC + 2 * MEG + 524288;
  bf16* w1Th = wC;
  bf16* w2Th = wC + 2 * MEG;
  float* l0 = (float*)wC;        // parks in dead wqT region after qkv (128 KB)
  float* l1 = l0 + N_TOK * 16;   // 32768 floats each

  bf16* bqc = SM, *bkc = SM + 1024, *bvc = SM + 2048, *boc = SM + 3072;
  bf16* b1c = SM + 4096, *b2c = SM + 8192;
  bf16* qnw = SM + 9216, *qnb = SM + 10240;
  bf16* kvnw = SM + 11264, *kvnb = SM + 12032;
  bf16* pnw = SM + 12800, *pnb = SM + 13824;

  // 0) dtype detection + batched small-vector conversion
  detect_kernel<<<1, 256, 0, stream>>>(x_r, flag);
  ConvArgs ca;
  ca.src[0] = bq_r;   ca.dst[0] = bqc;  ca.n[0] = DIM;
  ca.src[1] = bk_r;   ca.dst[1] = bkc;  ca.n[1] = DIM;
  ca.src[2] = bv_r;   ca.dst[2] = bvc;  ca.n[2] = DIM;
  ca.src[3] = bo_r;   ca.dst[3] = boc;  ca.n[3] = DIM;
  ca.src[4] = b1_r;   ca.dst[4] = b1c;  ca.n[4] = DFF;
  ca.src[5] = b2_r;   ca.dst[5] = b2c;  ca.n[5] = DIM;
  ca.src[6] = qnw_r;  ca.dst[6] = qnw;  ca.n[6] = DIM;
  ca.src[7] = qnb_r;  ca.dst[7] = qnb;  ca.n[7] = DIM;
  ca.src[8] = kvnw_r; ca.dst[8] = kvnw; ca.n[8] = CDIM;
  ca.src[9] = kvnb_r; ca.dst[9] = kvnb; ca.n[9] = CDIM;
  ca.src[10] = pnw_r; ca.dst[10] = pnw; ca.n[10] = DIM;
  ca.src[11] = pnb_r; ca.dst[11] = pnb; ca.n[11] = DIM;
  conv_small_kernel<<<12, 256, 0, stream>>>(ca, flag);

  // 1) both input layernorms in one launch
  ln_pair_kernel<<<dim3(2048, 2), 256, 0, stream>>>(x_r, qnw, qnb, xq,
                                                    ctx_r, kvnw, kvnb, kvn, flag);

  // 2) all four attention weight transposes in one launch
  {
    TmArgs ta;
    ta.force_bf = 0;
    ta.src[0] = wq_r; ta.dst[0] = wqT; ta.r0[0] = 0; ta.Rcnt[0] = DIM;
    ta.c0[0] = 0; ta.Cfull[0] = DIM; ta.gx[0] = 32; ta.gy[0] = 32;
    ta.src[1] = wk_r; ta.dst[1] = wkT; ta.r0[1] = 0; ta.Rcnt[1] = CDIM;
    ta.c0[1] = 0; ta.Cfull[1] = DIM; ta.gx[1] = 32; ta.gy[1] = 24;
    ta.src[2] = wv_r; ta.dst[2] = wvT; ta.r0[2] = 0; ta.Rcnt[2] = CDIM;
    ta.c0[2] = 0; ta.Cfull[2] = DIM; ta.gx[2] = 32; ta.gy[2] = 24;
    ta.src[3] = wo_r; ta.dst[3] = woT; ta.r0[3] = 0; ta.Rcnt[3] = DIM;
    ta.c0[3] = 0; ta.Cfull[3] = DIM; ta.gx[3] = 32; ta.gy[3] = 32;
    tmulti_kernel<<<dim3(32, 32, 4), 256, 0, stream>>>(ta, flag);
  }

  // 3) fused q/k/v; z=2 emits V^T directly (A=wvT rows d, Bt=kvn rows m)
  {
    QkvArgs qa;
    qa.A[0] = xq;  qa.Bt[0] = wqT; qa.bias[0] = bqc; qa.C[0] = qm;
    qa.K[0] = DIM;  qa.ldc[0] = DIM;   qa.gx[0] = 16; qa.gy[0] = 32; qa.brow[0] = 0;
    qa.A[1] = kvn; qa.Bt[1] = wkT; qa.bias[1] = bkc; qa.C[1] = km;
    qa.K[1] = CDIM; qa.ldc[1] = DIM;   qa.gx[1] = 16; qa.gy[1] = 32; qa.brow[1] = 0;
    qa.A[2] = wvT; qa.Bt[2] = kvn; qa.bias[2] = bvc; qa.C[2] = vTb;
    qa.K[2] = CDIM; qa.ldc[2] = M_TOK; qa.gx[2] = 32; qa.gy[2] = 16; qa.brow[2] = 1;
    gemm64db_qkv<<<dim3(32, 32, 3), 256, 0, stream>>>(qa);
  }

  // 4) attention split-M (1024 blocks) + combine
  attn_kernel<<<dim3(32, 16, 2), 256, 0, stream>>>(qm, km, vTb, pO0, pO1, l0, l1);
  attn_combine<<<2048, 256, 0, stream>>>(pO0, pO1, l0, l1, om);

  // 5) o-projection + raw-dtype residual(x)
  gemm64db<1><<<dim3(16, 32), 256, 0, stream>>>(om, woT, boc, x_r, xat, DIM, DIM, flag);

  // 6) post-norm
  ln_kernel<<<N_TOK, 256, 0, stream>>>(xat, pnw, pnb, hln, DIM);

  // 7) MLP split over DFF halves; final writes d_out in raw dtype
  for (int hh = 0; hh < 2; hh++) {
    TmArgs ta;
    ta.force_bf = 0;
    ta.src[0] = w1_r; ta.dst[0] = w1Th; ta.r0[0] = 0; ta.Rcnt[0] = DIM;
    ta.c0[0] = hh * 2048; ta.Cfull[0] = DFF; ta.gx[0] = 64; ta.gy[0] = 32;
    ta.src[1] = w2_r; ta.dst[1] = w2Th; ta.r0[1] = hh * 2048; ta.Rcnt[1] = 2048;
    ta.c0[1] = 0; ta.Cfull[1] = DIM; ta.gx[1] = 32; ta.gy[1] = 64;
    ta.src[2] = ta.src[0]; ta.dst[2] = ta.dst[0]; ta.r0[2] = 0; ta.Rcnt[2] = 32;
    ta.c0[2] = 0; ta.Cfull[2] = DIM; ta.gx[2] = 0; ta.gy[2] = 0;
    ta.src[3] = ta.src[0]; ta.dst[3] = ta.dst[0]; ta.r0[3] = 0; ta.Rcnt[3] = 32;
    ta.c0[3] = 0; ta.Cfull[3] = DIM; ta.gx[3] = 0; ta.gy[3] = 0;
    tmulti_kernel<<<dim3(64, 64, 2), 256, 0, stream>>>(ta, flag);

    // MLP1 half: [2048]x[2048], 1024 blocks of 64x64
    gemm64db<2><<<dim3(32, 32), 256, 0, stream>>>(hln, w1Th, b1c + hh * 2048, nullptr,
                                                  h1h, DIM, 2048, flag);
    // MLP2 half: [2048]x[1024], 512 blocks of 64x64
    if (hh == 0)
      gemm64db<4><<<dim3(16, 32), 256, 0, stream>>>(h1h, w2Th, b2c, xat, d_out,
                                                    2048, DIM, flag);
    else
      gemm64db<5><<<dim3(16, 32), 256, 0, stream>>>(h1h, w2Th, b2c, nullptr, d_out,
                                                    2048, DIM, flag);
  }
}

// Round 5
// 352.740 us; speedup vs baseline: 1.2482x; 1.0151x over previous
//
#include <hip/hip_runtime.h>

typedef __bf16 bf16;
typedef __bf16 bf16x4 __attribute__((ext_vector_type(4)));
typedef __bf16 bf16x8 __attribute__((ext_vector_type(8)));
typedef float f32x4 __attribute__((ext_vector_type(4)));

#define N_TOK 2048
#define M_TOK 2048
#define DIM 1024
#define CDIM 768
#define DFF 4096

// async global->LDS, 16B per lane; LDS dest = wave-uniform base + lane*16
static __device__ __forceinline__ void async16(const void* g, void* l) {
  __builtin_amdgcn_global_load_lds((const __attribute__((address_space(1))) void*)g,
                                   (__attribute__((address_space(3))) void*)l, 16, 0, 0);
}

// ---------- batched small-vector conversion + dtype-flag publish ----------
// Each block locally detects the dtype (low-16 halves plausible as bf16?) from
// x_r's first 512 words; block 0 publishes the flag for downstream kernels.
// (Folds the old detect_kernel launch away.)
struct ConvArgs {
  const void* src[12];
  bf16* dst[12];
  int n[12];
  const void* xprobe;
};
__global__ __launch_bounds__(256) void conv_small_kernel(ConvArgs a, int* flag) {
  __shared__ int cnt;
  if (threadIdx.x == 0) cnt = 0;
  __syncthreads();
  const unsigned* w = (const unsigned*)a.xprobe;
  int ok = 0;
  for (int i = threadIdx.x; i < 512; i += 256) {
    unsigned lo = w[i] & 0xFFFFu;
    float f = __uint_as_float(lo << 16);
    if (lo == 0u || (fabsf(f) > 1e-3f && fabsf(f) < 1e3f)) ok++;
  }
  atomicAdd(&cnt, ok);
  __syncthreads();
  const bool isbf = (cnt >= 256);
  if (blockIdx.x == 0 && threadIdx.x == 0) *flag = isbf ? 1 : 0;
  const int b = blockIdx.x;
  const void* in = a.src[b];
  bf16* out = a.dst[b];
  const int n = a.n[b];
  for (int i = threadIdx.x; i < n; i += 256)
    out[i] = isbf ? ((const bf16*)in)[i] : (bf16)((const float*)in)[i];
}

// ---------- batched transpose+convert (up to 4 slices via blockIdx.z) ----------
struct TmArgs {
  const void* src[4];
  bf16* dst[4];
  int r0[4], Rcnt[4], c0[4], Cfull[4], gx[4], gy[4];
  int force_bf;
};
__global__ __launch_bounds__(256) void tmulti_kernel(TmArgs a, const int* flag) {
  const int z = blockIdx.z;
  if ((int)blockIdx.x >= a.gx[z] || (int)blockIdx.y >= a.gy[z]) return;
  __shared__ bf16 t[32][33];
  const bool isbf = a.force_bf || (*flag != 0);
  const void* in = a.src[z];
  bf16* out = a.dst[z];
  const int Rcnt = a.Rcnt[z], Cfull = a.Cfull[z];
  const int cb = blockIdx.x * 32, rb = blockIdx.y * 32;
  const int tx = threadIdx.x & 31, ty = threadIdx.x >> 5;
#pragma unroll
  for (int i = 0; i < 4; i++) {
    const size_t r = (size_t)(a.r0[z] + rb + ty + i * 8);
    const size_t c = (size_t)(a.c0[z] + cb + tx);
    float v = isbf ? (float)((const bf16*)in)[r * Cfull + c]
                   : ((const float*)in)[r * Cfull + c];
    t[ty + i * 8][tx] = (bf16)v;
  }
  __syncthreads();
#pragma unroll
  for (int i = 0; i < 4; i++)
    out[(size_t)(cb + ty + i * 8) * Rcnt + rb + tx] = t[tx][ty + i * 8];
}

// ---------------- Fused first-layer LayerNorm pair: y=0 x, y=1 ctx --------------
__global__ __launch_bounds__(256) void ln_pair_kernel(
    const void* __restrict__ x0, const bf16* w0, const bf16* b0, bf16* o0,
    const void* __restrict__ x1, const bf16* w1, const bf16* b1, bf16* o1,
    const int* flag) {
  const bool isbf = (*flag != 0);
  const int cols = (blockIdx.y == 0) ? DIM : CDIM;
  const void* x = (blockIdx.y == 0) ? x0 : x1;
  const bf16* w = (blockIdx.y == 0) ? w0 : w1;
  const bf16* b = (blockIdx.y == 0) ? b0 : b1;
  bf16* outp = (blockIdx.y == 0) ? o0 : o1;
  const int row = blockIdx.x;
  const bf16* xr_b = (const bf16*)x + (size_t)row * cols;
  const float* xr_f = (const float*)x + (size_t)row * cols;
  bf16* orow = outp + (size_t)row * cols;
  float s = 0.f, ss = 0.f;
  for (int c = threadIdx.x; c < cols; c += 256) {
    float v = isbf ? (float)xr_b[c] : xr_f[c];
    s += v; ss += v * v;
  }
  for (int d = 1; d < 64; d <<= 1) { s += __shfl_xor(s, d, 64); ss += __shfl_xor(ss, d, 64); }
  __shared__ float sh[8];
  const int wv = threadIdx.x >> 6, lane = threadIdx.x & 63;
  if (lane == 0) { sh[wv] = s; sh[4 + wv] = ss; }
  __syncthreads();
  s = sh[0] + sh[1] + sh[2] + sh[3];
  ss = sh[4] + sh[5] + sh[6] + sh[7];
  const float mean = s / cols;
  float var = ss / cols - mean * mean;
  var = fmaxf(var, 0.f);
  const float r = rsqrtf(var + 1e-12f);
  for (int c = threadIdx.x; c < cols; c += 256) {
    float v = isbf ? (float)xr_b[c] : xr_f[c];
    orow[c] = (bf16)((v - mean) * r * (float)w[c] + (float)b[c]);
  }
}

// ---------------- LayerNorm (bf16 in, bf16 out) ----------------
__global__ __launch_bounds__(256) void ln_kernel(
    const bf16* __restrict__ x, const bf16* __restrict__ w, const bf16* __restrict__ b,
    bf16* __restrict__ out, int cols) {
  const int row = blockIdx.x;
  const bf16* xr = x + (size_t)row * cols;
  bf16* orow = out + (size_t)row * cols;
  float s = 0.f, ss = 0.f;
  for (int c = threadIdx.x; c < cols; c += 256) {
    float v = (float)xr[c];
    s += v; ss += v * v;
  }
  for (int d = 1; d < 64; d <<= 1) { s += __shfl_xor(s, d, 64); ss += __shfl_xor(ss, d, 64); }
  __shared__ float sh[8];
  const int wv = threadIdx.x >> 6, lane = threadIdx.x & 63;
  if (lane == 0) { sh[wv] = s; sh[4 + wv] = ss; }
  __syncthreads();
  s = sh[0] + sh[1] + sh[2] + sh[3];
  ss = sh[4] + sh[5] + sh[6] + sh[7];
  const float mean = s / cols;
  float var = ss / cols - mean * mean;
  var = fmaxf(var, 0.f);
  const float r = rsqrtf(var + 1e-12f);
  for (int c = threadIdx.x; c < cols; c += 256) {
    float v = (float)xr[c];
    orow[c] = (bf16)((v - mean) * r * (float)w[c] + (float)b[c]);
  }
}

__device__ __forceinline__ float gelu_f(float x) {
  float u = 0.7978845608028654f * (x + 0.044715f * x * x * x);
  return 0.5f * x * (1.f + tanhf(u));
}

// -------- gemm64db: 64x64 tile, BK=64, 256 thr (4 waves 2x2, 32x32/wave) -------
// (unchanged from round 4 - harness-verified at 358 us)
template <int EPI>
__global__ __launch_bounds__(256) void gemm64db(
    const bf16* __restrict__ A, const bf16* __restrict__ Bt,
    const bf16* __restrict__ bias, const void* __restrict__ resid,
    void* __restrict__ Cout, int K, int ldc, const int* flag) {
  __shared__ __align__(16) bf16 As[2][64 * 64];
  __shared__ __align__(16) bf16 Bs[2][64 * 64];
  const int tid = threadIdx.x;
  const int lane = tid & 63, wv = tid >> 6;
  const int lq = lane >> 4, lm = lane & 15;
  const int row0 = blockIdx.y * 64, col0 = blockIdx.x * 64;
  const int wr = (wv >> 1) * 32, wc = (wv & 1) * 32;

  const int sr = lane >> 3;              // staging row within 8-row group
  const int sc = ((lane & 7) ^ sr) * 8;  // pre-swizzled source col (elems)
  const int swz = (lm & 7) << 3;         // read-side XOR (elems)

  f32x4 acc[2][2] = {};

  const bf16* Abase = A + (size_t)(row0 + wv * 16 + sr) * K + sc;
  const bf16* Bbase = Bt + (size_t)(col0 + wv * 16 + sr) * K + sc;

  const int nt = K >> 6;
#pragma unroll
  for (int b = 0; b < 2; b++) {
    async16(Abase + (size_t)(b * 8) * K, &As[0][wv * 1024 + b * 512]);
    async16(Bbase + (size_t)(b * 8) * K, &Bs[0][wv * 1024 + b * 512]);
  }
  __syncthreads();

  int cur = 0;
  for (int t = 0; t < nt; ++t) {
    if (t + 1 < nt) {  // prefetch next tile; loads fly under the MFMA phase
      const int k1 = (t + 1) << 6;
#pragma unroll
      for (int b = 0; b < 2; b++) {
        async16(Abase + (size_t)(b * 8) * K + k1, &As[cur ^ 1][wv * 1024 + b * 512]);
        async16(Bbase + (size_t)(b * 8) * K + k1, &Bs[cur ^ 1][wv * 1024 + b * 512]);
      }
    }
#pragma unroll
    for (int kh = 0; kh < 2; kh++) {
      const int cofs = (kh * 32 + lq * 8) ^ swz;
      bf16x8 af[2], bfv[2];
#pragma unroll
      for (int i = 0; i < 2; i++)
        af[i] = *(const bf16x8*)&As[cur][(wr + i * 16 + lm) * 64 + cofs];
#pragma unroll
      for (int j = 0; j < 2; j++)
        bfv[j] = *(const bf16x8*)&Bs[cur][(wc + j * 16 + lm) * 64 + cofs];
#pragma unroll
      for (int i = 0; i < 2; i++)
#pragma unroll
        for (int j = 0; j < 2; j++)
          acc[i][j] = __builtin_amdgcn_mfma_f32_16x16x32_bf16(af[i], bfv[j], acc[i][j], 0, 0, 0);
    }
    __syncthreads();  // drains prefetch vmcnt + this tile's lgkm reads
    cur ^= 1;
  }

  const bool isbf = (*flag != 0);
#pragma unroll
  for (int i = 0; i < 2; i++) {
    const int rb = row0 + wr + i * 16 + lq * 4;
#pragma unroll
    for (int j = 0; j < 2; j++) {
      const int c = col0 + wc + j * 16 + lm;
      const float bv = (EPI != 5) ? (float)bias[c] : 0.f;
#pragma unroll
      for (int rg = 0; rg < 4; rg++) {
        const size_t idx = (size_t)(rb + rg) * ldc + c;
        float v = acc[i][j][rg] + bv;
        if (EPI == 1)
          v += isbf ? (float)((const bf16*)resid)[idx] : ((const float*)resid)[idx];
        if (EPI == 2) v = gelu_f(v);
        if (EPI == 4) v += (float)((const bf16*)resid)[idx];
        if (EPI == 5)
          v += isbf ? (float)((bf16*)Cout)[idx] : ((float*)Cout)[idx];
        if (EPI == 4 || EPI == 5) {
          if (isbf) ((bf16*)Cout)[idx] = (bf16)v;
          else      ((float*)Cout)[idx] = v;
        } else {
          ((bf16*)Cout)[idx] = (bf16)v;
        }
      }
    }
  }
}

// ------- fused q/k/v projection, z=2 computes V^T directly (bias per row) ------
struct QkvArgs {
  const bf16* A[3];
  const bf16* Bt[3];
  const bf16* bias[3];
  bf16* C[3];
  int K[3], ldc[3], gx[3], gy[3], brow[3];
};
__global__ __launch_bounds__(256) void gemm64db_qkv(QkvArgs a) {
  const int z = blockIdx.z;
  if ((int)blockIdx.x >= a.gx[z] || (int)blockIdx.y >= a.gy[z]) return;
  const bf16* A = a.A[z];
  const bf16* Bt = a.Bt[z];
  const int K = a.K[z];
  __shared__ __align__(16) bf16 As[2][64 * 64];
  __shared__ __align__(16) bf16 Bs[2][64 * 64];
  const int tid = threadIdx.x;
  const int lane = tid & 63, wv = tid >> 6;
  const int lq = lane >> 4, lm = lane & 15;
  const int row0 = blockIdx.y * 64, col0 = blockIdx.x * 64;
  const int wr = (wv >> 1) * 32, wc = (wv & 1) * 32;

  const int sr = lane >> 3;
  const int sc = ((lane & 7) ^ sr) * 8;
  const int swz = (lm & 7) << 3;

  f32x4 acc[2][2] = {};

  const bf16* Abase = A + (size_t)(row0 + wv * 16 + sr) * K + sc;
  const bf16* Bbase = Bt + (size_t)(col0 + wv * 16 + sr) * K + sc;

  const int nt = K >> 6;
#pragma unroll
  for (int b = 0; b < 2; b++) {
    async16(Abase + (size_t)(b * 8) * K, &As[0][wv * 1024 + b * 512]);
    async16(Bbase + (size_t)(b * 8) * K, &Bs[0][wv * 1024 + b * 512]);
  }
  __syncthreads();

  int cur = 0;
  for (int t = 0; t < nt; ++t) {
    if (t + 1 < nt) {
      const int k1 = (t + 1) << 6;
#pragma unroll
      for (int b = 0; b < 2; b++) {
        async16(Abase + (size_t)(b * 8) * K + k1, &As[cur ^ 1][wv * 1024 + b * 512]);
        async16(Bbase + (size_t)(b * 8) * K + k1, &Bs[cur ^ 1][wv * 1024 + b * 512]);
      }
    }
#pragma unroll
    for (int kh = 0; kh < 2; kh++) {
      const int cofs = (kh * 32 + lq * 8) ^ swz;
      bf16x8 af[2], bfv[2];
#pragma unroll
      for (int i = 0; i < 2; i++)
        af[i] = *(const bf16x8*)&As[cur][(wr + i * 16 + lm) * 64 + cofs];
#pragma unroll
      for (int j = 0; j < 2; j++)
        bfv[j] = *(const bf16x8*)&Bs[cur][(wc + j * 16 + lm) * 64 + cofs];
#pragma unroll
      for (int i = 0; i < 2; i++)
#pragma unroll
        for (int j = 0; j < 2; j++)
          acc[i][j] = __builtin_amdgcn_mfma_f32_16x16x32_bf16(af[i], bfv[j], acc[i][j], 0, 0, 0);
    }
    __syncthreads();
    cur ^= 1;
  }

  const bf16* bias = a.bias[z];
  bf16* C = a.C[z];
  const int ldc = a.ldc[z];
  const bool brow = a.brow[z] != 0;
#pragma unroll
  for (int i = 0; i < 2; i++) {
    const int rb = row0 + wr + i * 16 + lq * 4;
#pragma unroll
    for (int j = 0; j < 2; j++) {
      const int c = col0 + wc + j * 16 + lm;
      const float bcol = brow ? 0.f : (float)bias[c];
#pragma unroll
      for (int rg = 0; rg < 4; rg++) {
        const float bv = brow ? (float)bias[rb + rg] : bcol;
        C[(size_t)(rb + rg) * ldc + c] = (bf16)(acc[i][j][rg] + bv);
      }
    }
  }
}

// ---------------- Flash attention v9: T14 async-stage + XCD head grouping -----
// Next K/V tile loaded to REGISTERS during current tile's QK+softmax+PV
// (~1500cyc cover for ~900cyc HBM latency); ds_write after the loop-top
// barrier. Intra-loop barriers are lgkmcnt(0)+raw s_barrier so the prefetch
// vmcnt is NOT drained (every ds_read is consumed by an MFMA pre-barrier;
// ds_write visibility only needs lgkmcnt). Bijective block swizzle groups
// 4 heads per XCD (K/V slice 2MB fits 4MB per-XCD L2).
__global__ __launch_bounds__(256) void attn_kernel(
    const bf16* __restrict__ q, const bf16* __restrict__ k,
    const bf16* __restrict__ vT, bf16* __restrict__ pO0, bf16* __restrict__ pO1,
    float* __restrict__ l0, float* __restrict__ l1) {
  __shared__ __align__(16) bf16 KPs[128 * 64];  // Ks [128][64]; then P^T [64][128]
  __shared__ __align__(16) bf16 Vs[64 * 128];   // [d 64][m 128]
  const int tid = threadIdx.x, lane = tid & 63, wv = tid >> 6;
  const int lq = lane >> 4, lm = lane & 15;
  // XCD-aware bijective swizzle over the 1024-block grid (1024 = 8*128):
  // XCD j (= fid%8) gets swz ids [128j,128j+128) -> 4 heads per XCD.
  const int fid = blockIdx.x + 32 * (blockIdx.y + 16 * blockIdx.z);
  const int sid = (fid & 7) * 128 + (fid >> 3);
  const int n0 = (sid & 31) * 64;
  const int h = (sid >> 5) & 15;
  const int half = sid >> 9;
  const int mbeg = half * (M_TOK / 2), mend = mbeg + M_TOK / 2;
  bf16* pO = half ? pO1 : pO0;
  float* lb = half ? l1 : l0;

  bf16x8 qf[2];
#pragma unroll
  for (int f = 0; f < 2; f++)
    qf[f] = *(const bf16x8*)&q[(size_t)(n0 + wv * 16 + lm) * DIM + h * 64 + f * 32 + lq * 8];

  f32x4 oacc[4] = {};  // O^T tiles: rows d, cols n
  float lsum = 0.f;
  const float sc = 0.125f * 1.4426950408889634f;  // (1/sqrt(64)) * log2(e)

  // prologue: first K/V tile -> registers
  bf16x8 kreg[4], vreg[4];
#pragma unroll
  for (int it = 0; it < 4; it++) {
    const int e = tid * 8 + it * 2048;
    kreg[it] = *(const bf16x8*)&k[(size_t)(mbeg + (e >> 6)) * DIM + h * 64 + (e & 63)];
    vreg[it] = *(const bf16x8*)&vT[(size_t)(h * 64 + (e >> 7)) * M_TOK + mbeg + (e & 127)];
  }

  for (int m0 = mbeg; m0 < mend; m0 += 128) {
    // all waves done reading prev-tile LDS (reads consumed by MFMAs already)
    asm volatile("s_waitcnt lgkmcnt(0)" ::: "memory");
    __builtin_amdgcn_s_barrier();
#pragma unroll
    for (int it = 0; it < 4; it++) {  // regs -> LDS, swizzled
      const int e = tid * 8 + it * 2048;
      const int kr = e >> 6, kc = e & 63;
      *(bf16x8*)&KPs[kr * 64 + (kc ^ ((kr & 7) << 3))] = kreg[it];
      const int vr = e >> 7, vc = e & 127;
      *(bf16x8*)&Vs[vr * 128 + (vc ^ ((vr & 7) << 3))] = vreg[it];
    }
    if (m0 + 128 < mend) {  // issue next tile's loads; they fly under compute
      const int m1 = m0 + 128;
#pragma unroll
      for (int it = 0; it < 4; it++) {
        const int e = tid * 8 + it * 2048;
        kreg[it] = *(const bf16x8*)&k[(size_t)(m1 + (e >> 6)) * DIM + h * 64 + (e & 63)];
        vreg[it] = *(const bf16x8*)&vT[(size_t)(h * 64 + (e >> 7)) * M_TOK + m1 + (e & 127)];
      }
    }
    // LDS writes visible (lgkm only -- does NOT drain the vmcnt prefetch)
    asm volatile("s_waitcnt lgkmcnt(0)" ::: "memory");
    __builtin_amdgcn_s_barrier();

    // S^T into regs: tile j rows m = j*16+lq*4+rg, col n = wv*16 + (lane&15)
    f32x4 s[8];
#pragma unroll
    for (int j = 0; j < 8; j++) {
      const int kswz = (lm & 7) << 3;  // row = j*16+lm -> row&7 = lm&7
      bf16x8 kf0 = *(const bf16x8*)&KPs[(j * 16 + lm) * 64 + ((lq * 8) ^ kswz)];
      bf16x8 kf1 = *(const bf16x8*)&KPs[(j * 16 + lm) * 64 + ((32 + lq * 8) ^ kswz)];
      f32x4 z = {};
      z = __builtin_amdgcn_mfma_f32_16x16x32_bf16(kf0, qf[0], z, 0, 0, 0);
      s[j] = __builtin_amdgcn_mfma_f32_16x16x32_bf16(kf1, qf[1], z, 0, 0, 0);
    }
    // every wave done reading Ks; region becomes P^T [64][128]
    asm volatile("s_waitcnt lgkmcnt(0)" ::: "memory");
    __builtin_amdgcn_s_barrier();

#pragma unroll
    for (int j = 0; j < 8; j++) {
      bf16x4 pw;
#pragma unroll
      for (int rg = 0; rg < 4; rg++) {
        const float pv = exp2f(s[j][rg] * sc);
        lsum += pv;
        pw[rg] = (bf16)pv;
      }
      // P^T row = wv*16+lm (row&7 = lm&7), col = j*16+lq*4; swizzled b64 write
      *(bf16x4*)&KPs[(wv * 16 + lm) * 128 + ((j * 16 + lq * 4) ^ ((lm & 7) << 3))] = pw;
    }

    // O^T += V^T P^T (pf rows are this wave's own -> same-wave RAW, lgkmcnt)
#pragma unroll
    for (int kk = 0; kk < 4; kk++) {
      bf16x8 pf = *(const bf16x8*)&KPs[(wv * 16 + lm) * 128 +
                                       ((kk * 32 + lq * 8) ^ ((lm & 7) << 3))];
#pragma unroll
      for (int dt = 0; dt < 4; dt++) {
        bf16x8 vf = *(const bf16x8*)&Vs[(dt * 16 + lm) * 128 +
                                        ((kk * 32 + lq * 8) ^ ((lm & 7) << 3))];
        oacc[dt] = __builtin_amdgcn_mfma_f32_16x16x32_bf16(vf, pf, oacc[dt], 0, 0, 0);
      }
    }
  }

  // partial row-sum: reduce over the 4 lanes sharing this n (lane bits 4..5)
  lsum += __shfl_xor(lsum, 16, 64);
  lsum += __shfl_xor(lsum, 32, 64);
  if (lane < 16) lb[h * N_TOK + n0 + wv * 16 + lane] = lsum;

  const int rn = n0 + wv * 16 + lm;
#pragma unroll
  for (int dt = 0; dt < 4; dt++) {
    bf16x4 ow;
#pragma unroll
    for (int rg = 0; rg < 4; rg++) ow[rg] = (bf16)oacc[dt][rg];
    *(bf16x4*)&pO[(size_t)rn * DIM + h * 64 + dt * 16 + lq * 4] = ow;
  }
}

// ---------------- combine: om = (pO0 + pO1) / (l0 + l1) ----------------
__global__ __launch_bounds__(256) void attn_combine(
    const bf16* __restrict__ pO0, const bf16* __restrict__ pO1,
    const float* __restrict__ l0, const float* __restrict__ l1,
    bf16* __restrict__ om) {
  const int i4 = (blockIdx.x * 256 + threadIdx.x) * 4;  // over N*DIM = 2M elems
  const int n = i4 >> 10;
  const int h = (i4 & 1023) >> 6;
  const float rinv = 1.f / (l0[h * N_TOK + n] + l1[h * N_TOK + n]);
  bf16x4 a = *(const bf16x4*)&pO0[i4];
  bf16x4 b = *(const bf16x4*)&pO1[i4];
  bf16x4 o;
#pragma unroll
  for (int r = 0; r < 4; r++) o[r] = (bf16)(((float)a[r] + (float)b[r]) * rinv);
  *(bf16x4*)&om[i4] = o;
}

extern "C" void kernel_launch(void* const* d_in, const int* in_sizes, int n_in,
                              void* d_out, int out_size, void* d_ws, size_t ws_size,
                              hipStream_t stream) {
  const void* x_r     = d_in[0];
  const void* ctx_r   = d_in[1];
  const void* wq_r    = d_in[2];
  const void* bq_r    = d_in[3];
  const void* wk_r    = d_in[4];
  const void* bk_r    = d_in[5];
  const void* wv_r    = d_in[6];
  const void* bv_r    = d_in[7];
  const void* wo_r    = d_in[8];
  const void* bo_r    = d_in[9];
  const void* w1_r    = d_in[10];
  const void* b1_r    = d_in[11];
  const void* w2_r    = d_in[12];
  const void* b2_r    = d_in[13];
  const void* qnw_r   = d_in[14];
  const void* qnb_r   = d_in[15];
  const void* kvnw_r  = d_in[16];
  const void* kvnb_r  = d_in[17];
  const void* pnw_r   = d_in[18];
  const void* pnb_r   = d_in[19];

  // ---- workspace carve: 14M bf16 elems + smalls (~28.0 MB, known-good) ----
  bf16* p = (bf16*)d_ws;
  const size_t MEG = 1024 * 1024;
  bf16* qm  = p;             bf16* hln = qm;
  bf16* km  = p + 2 * MEG;   bf16* xat = km;
  bf16* wC  = p + 4 * MEG;
  bf16* xq  = p + 8 * MEG;   bf16* pO0 = xq;   bf16* om = xq;
  bf16* vTb = p + 10 * MEG;
  bf16* kvn = p + 12 * MEG;  bf16* pO1 = kvn;
  bf16* h1h = p + 10 * MEG;  // MLP h1 half spans [10M,14M)
  bf16* SM  = p + 14 * MEG;
  int* flag = (int*)(p + 14 * MEG + 16384);

  bf16* wqT = wC;
  bf16* wkT = wC + 1 * MEG;
  bf16* wvT = wC + 1 * MEG + 786432;
  bf16* woT = wC + 2 * MEG + 524288;
  bf16* w1Th = wC;
  bf16* w2Th = wC + 2 * MEG;
  float* l0 = (float*)wC;        // parks in dead wqT region after qkv (128 KB)
  float* l1 = l0 + N_TOK * 16;   // 32768 floats each

  bf16* bqc = SM, *bkc = SM + 1024, *bvc = SM + 2048, *boc = SM + 3072;
  bf16* b1c = SM + 4096, *b2c = SM + 8192;
  bf16* qnw = SM + 9216, *qnb = SM + 10240;
  bf16* kvnw = SM + 11264, *kvnb = SM + 12032;
  bf16* pnw = SM + 12800, *pnb = SM + 13824;

  // 0) batched small-vector conversion + dtype-flag publish (detect folded in)
  ConvArgs ca;
  ca.src[0] = bq_r;   ca.dst[0] = bqc;  ca.n[0] = DIM;
  ca.src[1] = bk_r;   ca.dst[1] = bkc;  ca.n[1] = DIM;
  ca.src[2] = bv_r;   ca.dst[2] = bvc;  ca.n[2] = DIM;
  ca.src[3] = bo_r;   ca.dst[3] = boc;  ca.n[3] = DIM;
  ca.src[4] = b1_r;   ca.dst[4] = b1c;  ca.n[4] = DFF;
  ca.src[5] = b2_r;   ca.dst[5] = b2c;  ca.n[5] = DIM;
  ca.src[6] = qnw_r;  ca.dst[6] = qnw;  ca.n[6] = DIM;
  ca.src[7] = qnb_r;  ca.dst[7] = qnb;  ca.n[7] = DIM;
  ca.src[8] = kvnw_r; ca.dst[8] = kvnw; ca.n[8] = CDIM;
  ca.src[9] = kvnb_r; ca.dst[9] = kvnb; ca.n[9] = CDIM;
  ca.src[10] = pnw_r; ca.dst[10] = pnw; ca.n[10] = DIM;
  ca.src[11] = pnb_r; ca.dst[11] = pnb; ca.n[11] = DIM;
  ca.xprobe = x_r;
  conv_small_kernel<<<12, 256, 0, stream>>>(ca, flag);

  // 1) both input layernorms in one launch
  ln_pair_kernel<<<dim3(2048, 2), 256, 0, stream>>>(x_r, qnw, qnb, xq,
                                                    ctx_r, kvnw, kvnb, kvn, flag);

  // 2) all four attention weight transposes in one launch
  {
    TmArgs ta;
    ta.force_bf = 0;
    ta.src[0] = wq_r; ta.dst[0] = wqT; ta.r0[0] = 0; ta.Rcnt[0] = DIM;
    ta.c0[0] = 0; ta.Cfull[0] = DIM; ta.gx[0] = 32; ta.gy[0] = 32;
    ta.src[1] = wk_r; ta.dst[1] = wkT; ta.r0[1] = 0; ta.Rcnt[1] = CDIM;
    ta.c0[1] = 0; ta.Cfull[1] = DIM; ta.gx[1] = 32; ta.gy[1] = 24;
    ta.src[2] = wv_r; ta.dst[2] = wvT; ta.r0[2] = 0; ta.Rcnt[2] = CDIM;
    ta.c0[2] = 0; ta.Cfull[2] = DIM; ta.gx[2] = 32; ta.gy[2] = 24;
    ta.src[3] = wo_r; ta.dst[3] = woT; ta.r0[3] = 0; ta.Rcnt[3] = DIM;
    ta.c0[3] = 0; ta.Cfull[3] = DIM; ta.gx[3] = 32; ta.gy[3] = 32;
    tmulti_kernel<<<dim3(32, 32, 4), 256, 0, stream>>>(ta, flag);
  }

  // 3) fused q/k/v; z=2 emits V^T directly (A=wvT rows d, Bt=kvn rows m)
  {
    QkvArgs qa;
    qa.A[0] = xq;  qa.Bt[0] = wqT; qa.bias[0] = bqc; qa.C[0] = qm;
    qa.K[0] = DIM;  qa.ldc[0] = DIM;   qa.gx[0] = 16; qa.gy[0] = 32; qa.brow[0] = 0;
    qa.A[1] = kvn; qa.Bt[1] = wkT; qa.bias[1] = bkc; qa.C[1] = km;
    qa.K[1] = CDIM; qa.ldc[1] = DIM;   qa.gx[1] = 16; qa.gy[1] = 32; qa.brow[1] = 0;
    qa.A[2] = wvT; qa.Bt[2] = kvn; qa.bias[2] = bvc; qa.C[2] = vTb;
    qa.K[2] = CDIM; qa.ldc[2] = M_TOK; qa.gx[2] = 32; qa.gy[2] = 16; qa.brow[2] = 1;
    gemm64db_qkv<<<dim3(32, 32, 3), 256, 0, stream>>>(qa);
  }

  // 4) attention split-M (1024 blocks) + combine
  attn_kernel<<<dim3(32, 16, 2), 256, 0, stream>>>(qm, km, vTb, pO0, pO1, l0, l1);
  attn_combine<<<2048, 256, 0, stream>>>(pO0, pO1, l0, l1, om);

  // 5) o-projection + raw-dtype residual(x)
  gemm64db<1><<<dim3(16, 32), 256, 0, stream>>>(om, woT, boc, x_r, xat, DIM, DIM, flag);

  // 6) post-norm
  ln_kernel<<<N_TOK, 256, 0, stream>>>(xat, pnw, pnb, hln, DIM);

  // 7) MLP split over DFF halves; final writes d_out in raw dtype
  for (int hh = 0; hh < 2; hh++) {
    TmArgs ta;
    ta.force_bf = 0;
    ta.src[0] = w1_r; ta.dst[0] = w1Th; ta.r0[0] = 0; ta.Rcnt[0] = DIM;
    ta.c0[0] = hh * 2048; ta.Cfull[0] = DFF; ta.gx[0] = 64; ta.gy[0] = 32;
    ta.src[1] = w2_r; ta.dst[1] = w2Th; ta.r0[1] = hh * 2048; ta.Rcnt[1] = 2048;
    ta.c0[1] = 0; ta.Cfull[1] = DIM; ta.gx[1] = 32; ta.gy[1] = 64;
    ta.src[2] = ta.src[0]; ta.dst[2] = ta.dst[0]; ta.r0[2] = 0; ta.Rcnt[2] = 32;
    ta.c0[2] = 0; ta.Cfull[2] = DIM; ta.gx[2] = 0; ta.gy[2] = 0;
    ta.src[3] = ta.src[0]; ta.dst[3] = ta.dst[0]; ta.r0[3] = 0; ta.Rcnt[3] = 32;
    ta.c0[3] = 0; ta.Cfull[3] = DIM; ta.gx[3] = 0; ta.gy[3] = 0;
    tmulti_kernel<<<dim3(64, 64, 2), 256, 0, stream>>>(ta, flag);

    // MLP1 half: [2048]x[2048], 1024 blocks of 64x64
    gemm64db<2><<<dim3(32, 32), 256, 0, stream>>>(hln, w1Th, b1c + hh * 2048, nullptr,
                                                  h1h, DIM, 2048, flag);
    // MLP2 half: [2048]x[1024], 512 blocks of 64x64
    if (hh == 0)
      gemm64db<4><<<dim3(16, 32), 256, 0, stream>>>(h1h, w2Th, b2c, xat, d_out,
                                                    2048, DIM, flag);
    else
      gemm64db<5><<<dim3(16, 32), 256, 0, stream>>>(h1h, w2Th, b2c, nullptr, d_out,
                                                    2048, DIM, flag);
  }
}

// Round 6
// 347.130 us; speedup vs baseline: 1.2684x; 1.0162x over previous
//
#include <hip/hip_runtime.h>

typedef __bf16 bf16;
typedef __bf16 bf16x4 __attribute__((ext_vector_type(4)));
typedef __bf16 bf16x8 __attribute__((ext_vector_type(8)));
typedef float f32x4 __attribute__((ext_vector_type(4)));

#define N_TOK 2048
#define M_TOK 2048
#define DIM 1024
#define CDIM 768
#define DFF 4096

// async global->LDS, 16B per lane; LDS dest = wave-uniform base + lane*16
static __device__ __forceinline__ void async16(const void* g, void* l) {
  __builtin_amdgcn_global_load_lds((const __attribute__((address_space(1))) void*)g,
                                   (__attribute__((address_space(3))) void*)l, 16, 0, 0);
}

// ---------- shared device helpers ----------
// local dtype detect: low-16 halves of first 512 words plausible as bf16?
// uses sbuf[0] as an int counter; leaves sbuf free after return.
__device__ __forceinline__ bool detect_bf(const void* xprobe, float* sbuf) {
  int* cnt = (int*)sbuf;
  if (threadIdx.x == 0) *cnt = 0;
  __syncthreads();
  const unsigned* w = (const unsigned*)xprobe;
  int ok = 0;
  for (int i = threadIdx.x; i < 512; i += 256) {
    unsigned lo = w[i] & 0xFFFFu;
    float f = __uint_as_float(lo << 16);
    if (lo == 0u || (fabsf(f) > 1e-3f && fabsf(f) < 1e3f)) ok++;
  }
  atomicAdd(cnt, ok);
  __syncthreads();
  return *cnt >= 256;
}

// 32x32 transpose tile (block = 256 thr); t is bf16[32*33] carved from shared
__device__ __forceinline__ void t32(const void* in, bf16* out, int r0, int Rcnt,
                                    int c0, int Cfull, bool isbf, bf16* t) {
  const int cb = blockIdx.x * 32, rb = blockIdx.y * 32;
  const int tx = threadIdx.x & 31, ty = threadIdx.x >> 5;
#pragma unroll
  for (int i = 0; i < 4; i++) {
    const size_t r = (size_t)(r0 + rb + ty + i * 8);
    const size_t c = (size_t)(c0 + cb + tx);
    float v = isbf ? (float)((const bf16*)in)[r * Cfull + c]
                   : ((const float*)in)[r * Cfull + c];
    t[(ty + i * 8) * 33 + tx] = (bf16)v;
  }
  __syncthreads();
#pragma unroll
  for (int i = 0; i < 4; i++)
    out[(size_t)(cb + ty + i * 8) * Rcnt + rb + tx] = t[tx * 33 + ty + i * 8];
}

// LayerNorm one row, single global read (row staged in LDS floats).
// in_bf: input dtype; w_bf: weight/bias dtype. xrow = cols floats; sh = 8 floats.
__device__ __forceinline__ void ln_row(const void* x, const void* wr, const void* br,
                                       bf16* outp, int cols, int row,
                                       bool in_bf, bool w_bf,
                                       float* xrow, float* sh) {
  const bf16* xr_b = (const bf16*)x + (size_t)row * cols;
  const float* xr_f = (const float*)x + (size_t)row * cols;
  bf16* orow = outp + (size_t)row * cols;
  float s = 0.f, ss = 0.f;
  for (int c = threadIdx.x; c < cols; c += 256) {
    float v = in_bf ? (float)xr_b[c] : xr_f[c];
    xrow[c] = v;
    s += v; ss += v * v;
  }
  for (int d = 1; d < 64; d <<= 1) { s += __shfl_xor(s, d, 64); ss += __shfl_xor(ss, d, 64); }
  const int wv = threadIdx.x >> 6, lane = threadIdx.x & 63;
  if (lane == 0) { sh[wv] = s; sh[4 + wv] = ss; }
  __syncthreads();
  s = sh[0] + sh[1] + sh[2] + sh[3];
  ss = sh[4] + sh[5] + sh[6] + sh[7];
  const float mean = s / cols;
  float var = ss / cols - mean * mean;
  var = fmaxf(var, 0.f);
  const float r = rsqrtf(var + 1e-12f);
  for (int c = threadIdx.x; c < cols; c += 256) {
    const float wv2 = w_bf ? (float)((const bf16*)wr)[c] : ((const float*)wr)[c];
    const float bv2 = w_bf ? (float)((const bf16*)br)[c] : ((const float*)br)[c];
    orow[c] = (bf16)((xrow[c] - mean) * r * wv2 + bv2);
  }
}

// ---------------- prep: z0-3 attn-weight transposes, z4-7 input LNs, z8 conv --
// Single launch replacing conv_small + ln_pair + tmulti(attn weights).
// Every block does a LOCAL dtype detect (no intra-launch flag dependency);
// z8/block0 publishes the flag for later launches.
struct PrepArgs {
  const void* tsrc[4]; bf16* tdst[4]; int tRcnt[4], tCfull[4], tgy[4];
  const void* x; const void* qnw; const void* qnb; bf16* xq;
  const void* ctx; const void* kvnw; const void* kvnb; bf16* kvn;
  const void* csrc[12]; bf16* cdst[12]; int cn[12];
  const void* xprobe;
};
__global__ __launch_bounds__(256) void prep_kernel(PrepArgs a, int* flag) {
  __shared__ __align__(16) float sbuf[1040];  // union: bf16 t[32*33] | xrow+sh
  const int z = blockIdx.z;
  const bool isbf = detect_bf(a.xprobe, sbuf);
  if (z < 4) {
    if ((int)blockIdx.y >= a.tgy[z]) return;
    t32(a.tsrc[z], a.tdst[z], 0, a.tRcnt[z], 0, a.tCfull[z], isbf, (bf16*)sbuf);
  } else if (z < 8) {
    const int row = blockIdx.x + 32 * blockIdx.y + (z & 1) * 1024;
    if (z < 6) ln_row(a.x,   a.qnw,  a.qnb,  a.xq,  DIM,  row, isbf, isbf, sbuf, sbuf + 1024);
    else       ln_row(a.ctx, a.kvnw, a.kvnb, a.kvn, CDIM, row, isbf, isbf, sbuf, sbuf + 1024);
  } else {
    const int b = blockIdx.x + 32 * blockIdx.y;
    if (b == 0 && threadIdx.x == 0) *flag = isbf ? 1 : 0;
    if (b >= 12) return;
    const void* in = a.csrc[b];
    bf16* out = a.cdst[b];
    const int n = a.cn[b];
    for (int i = threadIdx.x; i < n; i += 256)
      out[i] = isbf ? ((const bf16*)in)[i] : (bf16)((const float*)in)[i];
  }
}

// ---------------- post: z0-1 MLP-h0 w1/w2 transposes, z2 post-norm LN ---------
struct PostArgs {
  const void* w1; bf16* w1T;
  const void* w2; bf16* w2T;
  const bf16* xat; const void* pnw; const void* pnb; bf16* hln;
};
__global__ __launch_bounds__(256) void post_kernel(PostArgs a, const int* flag) {
  __shared__ __align__(16) float sbuf[1040];
  const int z = blockIdx.z;
  const bool isbf = (*flag != 0);
  if (z == 0) {  // w1[:, 0:2048] -> w1T [2048][1024]; gx=64, gy=32
    if (blockIdx.y >= 32) return;
    t32(a.w1, a.w1T, 0, DIM, 0, DFF, isbf, (bf16*)sbuf);
  } else if (z == 1) {  // w2[0:2048, :] -> w2T [1024][2048]; gx=32, gy=64
    if (blockIdx.x >= 32) return;
    t32(a.w2, a.w2T, 0, 2048, 0, DIM, isbf, (bf16*)sbuf);
  } else {  // post-norm LN over 2048 rows (input bf16, weights raw)
    const int row = blockIdx.x + 64 * blockIdx.y;
    if (row >= N_TOK) return;
    ln_row(a.xat, a.pnw, a.pnb, a.hln, DIM, row, true, isbf, sbuf, sbuf + 1024);
  }
}

// ---------- batched transpose+convert (MLP h1 slices) ----------
struct TmArgs {
  const void* src[4];
  bf16* dst[4];
  int r0[4], Rcnt[4], c0[4], Cfull[4], gx[4], gy[4];
  int force_bf;
};
__global__ __launch_bounds__(256) void tmulti_kernel(TmArgs a, const int* flag) {
  const int z = blockIdx.z;
  if ((int)blockIdx.x >= a.gx[z] || (int)blockIdx.y >= a.gy[z]) return;
  __shared__ bf16 t[32 * 33];
  const bool isbf = a.force_bf || (*flag != 0);
  t32(a.src[z], a.dst[z], a.r0[z], a.Rcnt[z], a.c0[z], a.Cfull[z], isbf, t);
}

__device__ __forceinline__ float gelu_f(float x) {
  float u = 0.7978845608028654f * (x + 0.044715f * x * x * x);
  return 0.5f * x * (1.f + tanhf(u));
}

// -------- gemm64db: 64x64 tile, BK=64, 256 thr (4 waves 2x2, 32x32/wave) -------
// (unchanged from round 4/5 - harness-verified)
template <int EPI>
__global__ __launch_bounds__(256) void gemm64db(
    const bf16* __restrict__ A, const bf16* __restrict__ Bt,
    const bf16* __restrict__ bias, const void* __restrict__ resid,
    void* __restrict__ Cout, int K, int ldc, const int* flag) {
  __shared__ __align__(16) bf16 As[2][64 * 64];
  __shared__ __align__(16) bf16 Bs[2][64 * 64];
  const int tid = threadIdx.x;
  const int lane = tid & 63, wv = tid >> 6;
  const int lq = lane >> 4, lm = lane & 15;
  const int row0 = blockIdx.y * 64, col0 = blockIdx.x * 64;
  const int wr = (wv >> 1) * 32, wc = (wv & 1) * 32;

  const int sr = lane >> 3;              // staging row within 8-row group
  const int sc = ((lane & 7) ^ sr) * 8;  // pre-swizzled source col (elems)
  const int swz = (lm & 7) << 3;         // read-side XOR (elems)

  f32x4 acc[2][2] = {};

  const bf16* Abase = A + (size_t)(row0 + wv * 16 + sr) * K + sc;
  const bf16* Bbase = Bt + (size_t)(col0 + wv * 16 + sr) * K + sc;

  const int nt = K >> 6;
#pragma unroll
  for (int b = 0; b < 2; b++) {
    async16(Abase + (size_t)(b * 8) * K, &As[0][wv * 1024 + b * 512]);
    async16(Bbase + (size_t)(b * 8) * K, &Bs[0][wv * 1024 + b * 512]);
  }
  __syncthreads();

  int cur = 0;
  for (int t = 0; t < nt; ++t) {
    if (t + 1 < nt) {  // prefetch next tile; loads fly under the MFMA phase
      const int k1 = (t + 1) << 6;
#pragma unroll
      for (int b = 0; b < 2; b++) {
        async16(Abase + (size_t)(b * 8) * K + k1, &As[cur ^ 1][wv * 1024 + b * 512]);
        async16(Bbase + (size_t)(b * 8) * K + k1, &Bs[cur ^ 1][wv * 1024 + b * 512]);
      }
    }
#pragma unroll
    for (int kh = 0; kh < 2; kh++) {
      const int cofs = (kh * 32 + lq * 8) ^ swz;
      bf16x8 af[2], bfv[2];
#pragma unroll
      for (int i = 0; i < 2; i++)
        af[i] = *(const bf16x8*)&As[cur][(wr + i * 16 + lm) * 64 + cofs];
#pragma unroll
      for (int j = 0; j < 2; j++)
        bfv[j] = *(const bf16x8*)&Bs[cur][(wc + j * 16 + lm) * 64 + cofs];
#pragma unroll
      for (int i = 0; i < 2; i++)
#pragma unroll
        for (int j = 0; j < 2; j++)
          acc[i][j] = __builtin_amdgcn_mfma_f32_16x16x32_bf16(af[i], bfv[j], acc[i][j], 0, 0, 0);
    }
    __syncthreads();  // drains prefetch vmcnt + this tile's lgkm reads
    cur ^= 1;
  }

  const bool isbf = (*flag != 0);
#pragma unroll
  for (int i = 0; i < 2; i++) {
    const int rb = row0 + wr + i * 16 + lq * 4;
#pragma unroll
    for (int j = 0; j < 2; j++) {
      const int c = col0 + wc + j * 16 + lm;
      const float bv = (EPI != 5) ? (float)bias[c] : 0.f;
#pragma unroll
      for (int rg = 0; rg < 4; rg++) {
        const size_t idx = (size_t)(rb + rg) * ldc + c;
        float v = acc[i][j][rg] + bv;
        if (EPI == 1)
          v += isbf ? (float)((const bf16*)resid)[idx] : ((const float*)resid)[idx];
        if (EPI == 2) v = gelu_f(v);
        if (EPI == 4) v += (float)((const bf16*)resid)[idx];
        if (EPI == 5)
          v += isbf ? (float)((bf16*)Cout)[idx] : ((float*)Cout)[idx];
        if (EPI == 4 || EPI == 5) {
          if (isbf) ((bf16*)Cout)[idx] = (bf16)v;
          else      ((float*)Cout)[idx] = v;
        } else {
          ((bf16*)Cout)[idx] = (bf16)v;
        }
      }
    }
  }
}

// ------- fused q/k/v projection, z=2 computes V^T directly (bias per row) ------
// Exact grid dim3(32,16,3): z<2 swap x/y (16 cols x 32 rows); z=2 direct.
struct QkvArgs {
  const bf16* A[3];
  const bf16* Bt[3];
  const bf16* bias[3];
  bf16* C[3];
  int K[3], ldc[3], brow[3];
};
__global__ __launch_bounds__(256) void gemm64db_qkv(QkvArgs a) {
  const int z = blockIdx.z;
  int bx, by;
  if (z < 2) { bx = blockIdx.y; by = blockIdx.x; }   // 16 col-blocks, 32 row-blocks
  else       { bx = blockIdx.x; by = blockIdx.y; }   // 32 col-blocks, 16 row-blocks
  const bf16* A = a.A[z];
  const bf16* Bt = a.Bt[z];
  const int K = a.K[z];
  __shared__ __align__(16) bf16 As[2][64 * 64];
  __shared__ __align__(16) bf16 Bs[2][64 * 64];
  const int tid = threadIdx.x;
  const int lane = tid & 63, wv = tid >> 6;
  const int lq = lane >> 4, lm = lane & 15;
  const int row0 = by * 64, col0 = bx * 64;
  const int wr = (wv >> 1) * 32, wc = (wv & 1) * 32;

  const int sr = lane >> 3;
  const int sc = ((lane & 7) ^ sr) * 8;
  const int swz = (lm & 7) << 3;

  f32x4 acc[2][2] = {};

  const bf16* Abase = A + (size_t)(row0 + wv * 16 + sr) * K + sc;
  const bf16* Bbase = Bt + (size_t)(col0 + wv * 16 + sr) * K + sc;

  const int nt = K >> 6;
#pragma unroll
  for (int b = 0; b < 2; b++) {
    async16(Abase + (size_t)(b * 8) * K, &As[0][wv * 1024 + b * 512]);
    async16(Bbase + (size_t)(b * 8) * K, &Bs[0][wv * 1024 + b * 512]);
  }
  __syncthreads();

  int cur = 0;
  for (int t = 0; t < nt; ++t) {
    if (t + 1 < nt) {
      const int k1 = (t + 1) << 6;
#pragma unroll
      for (int b = 0; b < 2; b++) {
        async16(Abase + (size_t)(b * 8) * K + k1, &As[cur ^ 1][wv * 1024 + b * 512]);
        async16(Bbase + (size_t)(b * 8) * K + k1, &Bs[cur ^ 1][wv * 1024 + b * 512]);
      }
    }
#pragma unroll
    for (int kh = 0; kh < 2; kh++) {
      const int cofs = (kh * 32 + lq * 8) ^ swz;
      bf16x8 af[2], bfv[2];
#pragma unroll
      for (int i = 0; i < 2; i++)
        af[i] = *(const bf16x8*)&As[cur][(wr + i * 16 + lm) * 64 + cofs];
#pragma unroll
      for (int j = 0; j < 2; j++)
        bfv[j] = *(const bf16x8*)&Bs[cur][(wc + j * 16 + lm) * 64 + cofs];
#pragma unroll
      for (int i = 0; i < 2; i++)
#pragma unroll
        for (int j = 0; j < 2; j++)
          acc[i][j] = __builtin_amdgcn_mfma_f32_16x16x32_bf16(af[i], bfv[j], acc[i][j], 0, 0, 0);
    }
    __syncthreads();
    cur ^= 1;
  }

  const bf16* bias = a.bias[z];
  bf16* C = a.C[z];
  const int ldc = a.ldc[z];
  const bool brow = a.brow[z] != 0;
#pragma unroll
  for (int i = 0; i < 2; i++) {
    const int rb = row0 + wr + i * 16 + lq * 4;
#pragma unroll
    for (int j = 0; j < 2; j++) {
      const int c = col0 + wc + j * 16 + lm;
      const float bcol = brow ? 0.f : (float)bias[c];
#pragma unroll
      for (int rg = 0; rg < 4; rg++) {
        const float bv = brow ? (float)bias[rb + rg] : bcol;
        C[(size_t)(rb + rg) * ldc + c] = (bf16)(acc[i][j][rg] + bv);
      }
    }
  }
}

// ---------------- Flash attention v10: v9 + s_setprio on MFMA clusters --------
__global__ __launch_bounds__(256) void attn_kernel(
    const bf16* __restrict__ q, const bf16* __restrict__ k,
    const bf16* __restrict__ vT, bf16* __restrict__ pO0, bf16* __restrict__ pO1,
    float* __restrict__ l0, float* __restrict__ l1) {
  __shared__ __align__(16) bf16 KPs[128 * 64];  // Ks [128][64]; then P^T [64][128]
  __shared__ __align__(16) bf16 Vs[64 * 128];   // [d 64][m 128]
  const int tid = threadIdx.x, lane = tid & 63, wv = tid >> 6;
  const int lq = lane >> 4, lm = lane & 15;
  // XCD-aware bijective swizzle (1024 = 8*128): XCD j gets 4 whole heads.
  const int fid = blockIdx.x + 32 * (blockIdx.y + 16 * blockIdx.z);
  const int sid = (fid & 7) * 128 + (fid >> 3);
  const int n0 = (sid & 31) * 64;
  const int h = (sid >> 5) & 15;
  const int half = sid >> 9;
  const int mbeg = half * (M_TOK / 2), mend = mbeg + M_TOK / 2;
  bf16* pO = half ? pO1 : pO0;
  float* lb = half ? l1 : l0;

  bf16x8 qf[2];
#pragma unroll
  for (int f = 0; f < 2; f++)
    qf[f] = *(const bf16x8*)&q[(size_t)(n0 + wv * 16 + lm) * DIM + h * 64 + f * 32 + lq * 8];

  f32x4 oacc[4] = {};  // O^T tiles: rows d, cols n
  float lsum = 0.f;
  const float sc = 0.125f * 1.4426950408889634f;  // (1/sqrt(64)) * log2(e)

  // prologue: first K/V tile -> registers
  bf16x8 kreg[4], vreg[4];
#pragma unroll
  for (int it = 0; it < 4; it++) {
    const int e = tid * 8 + it * 2048;
    kreg[it] = *(const bf16x8*)&k[(size_t)(mbeg + (e >> 6)) * DIM + h * 64 + (e & 63)];
    vreg[it] = *(const bf16x8*)&vT[(size_t)(h * 64 + (e >> 7)) * M_TOK + mbeg + (e & 127)];
  }

  for (int m0 = mbeg; m0 < mend; m0 += 128) {
    asm volatile("s_waitcnt lgkmcnt(0)" ::: "memory");
    __builtin_amdgcn_s_barrier();
#pragma unroll
    for (int it = 0; it < 4; it++) {  // regs -> LDS, swizzled
      const int e = tid * 8 + it * 2048;
      const int kr = e >> 6, kc = e & 63;
      *(bf16x8*)&KPs[kr * 64 + (kc ^ ((kr & 7) << 3))] = kreg[it];
      const int vr = e >> 7, vc = e & 127;
      *(bf16x8*)&Vs[vr * 128 + (vc ^ ((vr & 7) << 3))] = vreg[it];
    }
    if (m0 + 128 < mend) {  // issue next tile's loads; they fly under compute
      const int m1 = m0 + 128;
#pragma unroll
      for (int it = 0; it < 4; it++) {
        const int e = tid * 8 + it * 2048;
        kreg[it] = *(const bf16x8*)&k[(size_t)(m1 + (e >> 6)) * DIM + h * 64 + (e & 63)];
        vreg[it] = *(const bf16x8*)&vT[(size_t)(h * 64 + (e >> 7)) * M_TOK + m1 + (e & 127)];
      }
    }
    asm volatile("s_waitcnt lgkmcnt(0)" ::: "memory");
    __builtin_amdgcn_s_barrier();

    // S^T into regs: tile j rows m = j*16+lq*4+rg, col n = wv*16 + (lane&15)
    f32x4 s[8];
    __builtin_amdgcn_s_setprio(1);
#pragma unroll
    for (int j = 0; j < 8; j++) {
      const int kswz = (lm & 7) << 3;  // row = j*16+lm -> row&7 = lm&7
      bf16x8 kf0 = *(const bf16x8*)&KPs[(j * 16 + lm) * 64 + ((lq * 8) ^ kswz)];
      bf16x8 kf1 = *(const bf16x8*)&KPs[(j * 16 + lm) * 64 + ((32 + lq * 8) ^ kswz)];
      f32x4 z = {};
      z = __builtin_amdgcn_mfma_f32_16x16x32_bf16(kf0, qf[0], z, 0, 0, 0);
      s[j] = __builtin_amdgcn_mfma_f32_16x16x32_bf16(kf1, qf[1], z, 0, 0, 0);
    }
    __builtin_amdgcn_s_setprio(0);
    asm volatile("s_waitcnt lgkmcnt(0)" ::: "memory");
    __builtin_amdgcn_s_barrier();

#pragma unroll
    for (int j = 0; j < 8; j++) {
      bf16x4 pw;
#pragma unroll
      for (int rg = 0; rg < 4; rg++) {
        const float pv = exp2f(s[j][rg] * sc);
        lsum += pv;
        pw[rg] = (bf16)pv;
      }
      *(bf16x4*)&KPs[(wv * 16 + lm) * 128 + ((j * 16 + lq * 4) ^ ((lm & 7) << 3))] = pw;
    }

    // O^T += V^T P^T (pf rows are this wave's own -> same-wave RAW, lgkmcnt)
    __builtin_amdgcn_s_setprio(1);
#pragma unroll
    for (int kk = 0; kk < 4; kk++) {
      bf16x8 pf = *(const bf16x8*)&KPs[(wv * 16 + lm) * 128 +
                                       ((kk * 32 + lq * 8) ^ ((lm & 7) << 3))];
#pragma unroll
      for (int dt = 0; dt < 4; dt++) {
        bf16x8 vf = *(const bf16x8*)&Vs[(dt * 16 + lm) * 128 +
                                        ((kk * 32 + lq * 8) ^ ((lm & 7) << 3))];
        oacc[dt] = __builtin_amdgcn_mfma_f32_16x16x32_bf16(vf, pf, oacc[dt], 0, 0, 0);
      }
    }
    __builtin_amdgcn_s_setprio(0);
  }

  // partial row-sum: reduce over the 4 lanes sharing this n (lane bits 4..5)
  lsum += __shfl_xor(lsum, 16, 64);
  lsum += __shfl_xor(lsum, 32, 64);
  if (lane < 16) lb[h * N_TOK + n0 + wv * 16 + lane] = lsum;

  const int rn = n0 + wv * 16 + lm;
#pragma unroll
  for (int dt = 0; dt < 4; dt++) {
    bf16x4 ow;
#pragma unroll
    for (int rg = 0; rg < 4; rg++) ow[rg] = (bf16)oacc[dt][rg];
    *(bf16x4*)&pO[(size_t)rn * DIM + h * 64 + dt * 16 + lq * 4] = ow;
  }
}

// ---------------- combine: om = (pO0 + pO1) / (l0 + l1) ----------------
__global__ __launch_bounds__(256) void attn_combine(
    const bf16* __restrict__ pO0, const bf16* __restrict__ pO1,
    const float* __restrict__ l0, const float* __restrict__ l1,
    bf16* __restrict__ om) {
  const int i4 = (blockIdx.x * 256 + threadIdx.x) * 4;  // over N*DIM = 2M elems
  const int n = i4 >> 10;
  const int h = (i4 & 1023) >> 6;
  const float rinv = 1.f / (l0[h * N_TOK + n] + l1[h * N_TOK + n]);
  bf16x4 a = *(const bf16x4*)&pO0[i4];
  bf16x4 b = *(const bf16x4*)&pO1[i4];
  bf16x4 o;
#pragma unroll
  for (int r = 0; r < 4; r++) o[r] = (bf16)(((float)a[r] + (float)b[r]) * rinv);
  *(bf16x4*)&om[i4] = o;
}

extern "C" void kernel_launch(void* const* d_in, const int* in_sizes, int n_in,
                              void* d_out, int out_size, void* d_ws, size_t ws_size,
                              hipStream_t stream) {
  const void* x_r     = d_in[0];
  const void* ctx_r   = d_in[1];
  const void* wq_r    = d_in[2];
  const void* bq_r    = d_in[3];
  const void* wk_r    = d_in[4];
  const void* bk_r    = d_in[5];
  const void* wv_r    = d_in[6];
  const void* bv_r    = d_in[7];
  const void* wo_r    = d_in[8];
  const void* bo_r    = d_in[9];
  const void* w1_r    = d_in[10];
  const void* b1_r    = d_in[11];
  const void* w2_r    = d_in[12];
  const void* b2_r    = d_in[13];
  const void* qnw_r   = d_in[14];
  const void* qnb_r   = d_in[15];
  const void* kvnw_r  = d_in[16];
  const void* kvnb_r  = d_in[17];
  const void* pnw_r   = d_in[18];
  const void* pnb_r   = d_in[19];

  // ---- workspace carve: 14M bf16 elems + smalls (~28.0 MB, known-good) ----
  bf16* p = (bf16*)d_ws;
  const size_t MEG = 1024 * 1024;
  bf16* qm  = p;             bf16* hln = qm;
  bf16* km  = p + 2 * MEG;   bf16* xat = km;
  bf16* wC  = p + 4 * MEG;
  bf16* xq  = p + 8 * MEG;   bf16* pO0 = xq;   bf16* om = xq;
  bf16* vTb = p + 10 * MEG;
  bf16* kvn = p + 12 * MEG;  bf16* pO1 = kvn;
  bf16* h1h = p + 10 * MEG;  // MLP h1 half spans [10M,14M)
  bf16* SM  = p + 14 * MEG;
  int* flag = (int*)(p + 14 * MEG + 16384);

  bf16* wqT = wC;
  bf16* wkT = wC + 1 * MEG;
  bf16* wvT = wC + 1 * MEG + 786432;
  bf16* woT = wC + 2 * MEG + 524288;
  bf16* w1Th = wC;
  bf16* w2Th = wC + 2 * MEG;
  float* l0 = (float*)wC;        // parks in dead wqT region after qkv (128 KB)
  float* l1 = l0 + N_TOK * 16;   // 32768 floats each

  bf16* bqc = SM, *bkc = SM + 1024, *bvc = SM + 2048, *boc = SM + 3072;
  bf16* b1c = SM + 4096, *b2c = SM + 8192;
  bf16* qnw = SM + 9216, *qnb = SM + 10240;
  bf16* kvnw = SM + 11264, *kvnb = SM + 12032;
  bf16* pnw = SM + 12800, *pnb = SM + 13824;

  // 0) prep: conv + both input LNs + all 4 attention weight transposes
  {
    PrepArgs pa;
    pa.tsrc[0] = wq_r; pa.tdst[0] = wqT; pa.tRcnt[0] = DIM;  pa.tCfull[0] = DIM; pa.tgy[0] = 32;
    pa.tsrc[1] = wk_r; pa.tdst[1] = wkT; pa.tRcnt[1] = CDIM; pa.tCfull[1] = DIM; pa.tgy[1] = 24;
    pa.tsrc[2] = wv_r; pa.tdst[2] = wvT; pa.tRcnt[2] = CDIM; pa.tCfull[2] = DIM; pa.tgy[2] = 24;
    pa.tsrc[3] = wo_r; pa.tdst[3] = woT; pa.tRcnt[3] = DIM;  pa.tCfull[3] = DIM; pa.tgy[3] = 32;
    pa.x = x_r;   pa.qnw = qnw_r;   pa.qnb = qnb_r;   pa.xq = xq;
    pa.ctx = ctx_r; pa.kvnw = kvnw_r; pa.kvnb = kvnb_r; pa.kvn = kvn;
    pa.csrc[0] = bq_r;   pa.cdst[0] = bqc;  pa.cn[0] = DIM;
    pa.csrc[1] = bk_r;   pa.cdst[1] = bkc;  pa.cn[1] = DIM;
    pa.csrc[2] = bv_r;   pa.cdst[2] = bvc;  pa.cn[2] = DIM;
    pa.csrc[3] = bo_r;   pa.cdst[3] = boc;  pa.cn[3] = DIM;
    pa.csrc[4] = b1_r;   pa.cdst[4] = b1c;  pa.cn[4] = DFF;
    pa.csrc[5] = b2_r;   pa.cdst[5] = b2c;  pa.cn[5] = DIM;
    pa.csrc[6] = qnw_r;  pa.cdst[6] = qnw;  pa.cn[6] = DIM;
    pa.csrc[7] = qnb_r;  pa.cdst[7] = qnb;  pa.cn[7] = DIM;
    pa.csrc[8] = kvnw_r; pa.cdst[8] = kvnw; pa.cn[8] = CDIM;
    pa.csrc[9] = kvnb_r; pa.cdst[9] = kvnb; pa.cn[9] = CDIM;
    pa.csrc[10] = pnw_r; pa.cdst[10] = pnw; pa.cn[10] = DIM;
    pa.csrc[11] = pnb_r; pa.cdst[11] = pnb; pa.cn[11] = DIM;
    pa.xprobe = x_r;
    prep_kernel<<<dim3(32, 32, 9), 256, 0, stream>>>(pa, flag);
  }

  // 1) fused q/k/v; z=2 emits V^T directly (A=wvT rows d, Bt=kvn rows m)
  {
    QkvArgs qa;
    qa.A[0] = xq;  qa.Bt[0] = wqT; qa.bias[0] = bqc; qa.C[0] = qm;
    qa.K[0] = DIM;  qa.ldc[0] = DIM;   qa.brow[0] = 0;
    qa.A[1] = kvn; qa.Bt[1] = wkT; qa.bias[1] = bkc; qa.C[1] = km;
    qa.K[1] = CDIM; qa.ldc[1] = DIM;   qa.brow[1] = 0;
    qa.A[2] = wvT; qa.Bt[2] = kvn; qa.bias[2] = bvc; qa.C[2] = vTb;
    qa.K[2] = CDIM; qa.ldc[2] = M_TOK; qa.brow[2] = 1;
    gemm64db_qkv<<<dim3(32, 16, 3), 256, 0, stream>>>(qa);
  }

  // 2) attention split-M (1024 blocks) + combine
  attn_kernel<<<dim3(32, 16, 2), 256, 0, stream>>>(qm, km, vTb, pO0, pO1, l0, l1);
  attn_combine<<<2048, 256, 0, stream>>>(pO0, pO1, l0, l1, om);

  // 3) o-projection + raw-dtype residual(x)
  gemm64db<1><<<dim3(16, 32), 256, 0, stream>>>(om, woT, boc, x_r, xat, DIM, DIM, flag);

  // 4) post: post-norm LN + MLP-h0 w1/w2 transposes in one launch
  {
    PostArgs po;
    po.w1 = w1_r; po.w1T = w1Th;
    po.w2 = w2_r; po.w2T = w2Th;
    po.xat = xat; po.pnw = pnw_r; po.pnb = pnb_r; po.hln = hln;
    post_kernel<<<dim3(64, 64, 3), 256, 0, stream>>>(po, flag);
  }

  // 5) MLP half 0
  gemm64db<2><<<dim3(32, 32), 256, 0, stream>>>(hln, w1Th, b1c, nullptr,
                                                h1h, DIM, 2048, flag);
  gemm64db<4><<<dim3(16, 32), 256, 0, stream>>>(h1h, w2Th, b2c, xat, d_out,
                                                2048, DIM, flag);

  // 6) MLP half 1 (transposes reuse the same buffers -> must follow h0 gemms)
  {
    TmArgs ta;
    ta.force_bf = 0;
    ta.src[0] = w1_r; ta.dst[0] = w1Th; ta.r0[0] = 0; ta.Rcnt[0] = DIM;
    ta.c0[0] = 2048; ta.Cfull[0] = DFF; ta.gx[0] = 64; ta.gy[0] = 32;
    ta.src[1] = w2_r; ta.dst[1] = w2Th; ta.r0[1] = 2048; ta.Rcnt[1] = 2048;
    ta.c0[1] = 0; ta.Cfull[1] = DIM; ta.gx[1] = 32; ta.gy[1] = 64;
    ta.src[2] = ta.src[0]; ta.dst[2] = ta.dst[0]; ta.r0[2] = 0; ta.Rcnt[2] = 32;
    ta.c0[2] = 0; ta.Cfull[2] = DIM; ta.gx[2] = 0; ta.gy[2] = 0;
    ta.src[3] = ta.src[0]; ta.dst[3] = ta.dst[0]; ta.r0[3] = 0; ta.Rcnt[3] = 32;
    ta.c0[3] = 0; ta.Cfull[3] = DIM; ta.gx[3] = 0; ta.gy[3] = 0;
    tmulti_kernel<<<dim3(64, 64, 2), 256, 0, stream>>>(ta, flag);
  }
  gemm64db<2><<<dim3(32, 32), 256, 0, stream>>>(hln, w1Th, b1c + 2048, nullptr,
                                                h1h, DIM, 2048, flag);
  gemm64db<5><<<dim3(16, 32), 256, 0, stream>>>(h1h, w2Th, b2c, nullptr, d_out,
                                                2048, DIM, flag);
}

// Round 7
// 334.663 us; speedup vs baseline: 1.3156x; 1.0373x over previous
//
#include <hip/hip_runtime.h>

typedef __bf16 bf16;
typedef __bf16 bf16x4 __attribute__((ext_vector_type(4)));
typedef __bf16 bf16x8 __attribute__((ext_vector_type(8)));
typedef float f32x4 __attribute__((ext_vector_type(4)));

#define N_TOK 2048
#define M_TOK 2048
#define DIM 1024
#define CDIM 768
#define DFF 4096

// async global->LDS, 16B per lane; LDS dest = wave-uniform base + lane*16
static __device__ __forceinline__ void async16(const void* g, void* l) {
  __builtin_amdgcn_global_load_lds((const __attribute__((address_space(1))) void*)g,
                                   (__attribute__((address_space(3))) void*)l, 16, 0, 0);
}

// ---------- shared device helpers ----------
// local dtype detect: low-16 halves of first 512 words plausible as bf16?
__device__ __forceinline__ bool detect_bf(const void* xprobe, float* sbuf) {
  int* cnt = (int*)sbuf;
  if (threadIdx.x == 0) *cnt = 0;
  __syncthreads();
  const unsigned* w = (const unsigned*)xprobe;
  int ok = 0;
  for (int i = threadIdx.x; i < 512; i += 256) {
    unsigned lo = w[i] & 0xFFFFu;
    float f = __uint_as_float(lo << 16);
    if (lo == 0u || (fabsf(f) > 1e-3f && fabsf(f) < 1e3f)) ok++;
  }
  atomicAdd(cnt, ok);
  __syncthreads();
  return *cnt >= 256;
}

// 32x32 transpose tile (block = 256 thr); explicit block coords (bx, by)
__device__ __forceinline__ void t32(int bx, int by, const void* in, bf16* out,
                                    int r0, int Rcnt, int c0, int Cfull,
                                    bool isbf, bf16* t) {
  const int cb = bx * 32, rb = by * 32;
  const int tx = threadIdx.x & 31, ty = threadIdx.x >> 5;
#pragma unroll
  for (int i = 0; i < 4; i++) {
    const size_t r = (size_t)(r0 + rb + ty + i * 8);
    const size_t c = (size_t)(c0 + cb + tx);
    float v = isbf ? (float)((const bf16*)in)[r * Cfull + c]
                   : ((const float*)in)[r * Cfull + c];
    t[(ty + i * 8) * 33 + tx] = (bf16)v;
  }
  __syncthreads();
#pragma unroll
  for (int i = 0; i < 4; i++)
    out[(size_t)(cb + ty + i * 8) * Rcnt + rb + tx] = t[tx * 33 + ty + i * 8];
}

// LayerNorm one row, single global read (row staged in LDS floats).
__device__ __forceinline__ void ln_row(const void* x, const void* wr, const void* br,
                                       bf16* outp, int cols, int row,
                                       bool in_bf, bool w_bf,
                                       float* xrow, float* sh) {
  const bf16* xr_b = (const bf16*)x + (size_t)row * cols;
  const float* xr_f = (const float*)x + (size_t)row * cols;
  bf16* orow = outp + (size_t)row * cols;
  float s = 0.f, ss = 0.f;
  for (int c = threadIdx.x; c < cols; c += 256) {
    float v = in_bf ? (float)xr_b[c] : xr_f[c];
    xrow[c] = v;
    s += v; ss += v * v;
  }
  for (int d = 1; d < 64; d <<= 1) { s += __shfl_xor(s, d, 64); ss += __shfl_xor(ss, d, 64); }
  const int wv = threadIdx.x >> 6, lane = threadIdx.x & 63;
  if (lane == 0) { sh[wv] = s; sh[4 + wv] = ss; }
  __syncthreads();
  s = sh[0] + sh[1] + sh[2] + sh[3];
  ss = sh[4] + sh[5] + sh[6] + sh[7];
  const float mean = s / cols;
  float var = ss / cols - mean * mean;
  var = fmaxf(var, 0.f);
  const float r = rsqrtf(var + 1e-12f);
  for (int c = threadIdx.x; c < cols; c += 256) {
    const float wv2 = w_bf ? (float)((const bf16*)wr)[c] : ((const float*)wr)[c];
    const float bv2 = w_bf ? (float)((const bf16*)br)[c] : ((const float*)br)[c];
    orow[c] = (bf16)((xrow[c] - mean) * r * wv2 + bv2);
  }
}

// ---------------- prep: z0-3 attn-weight transposes, z4-7 input LNs, z8 conv --
struct PrepArgs {
  const void* tsrc[4]; bf16* tdst[4]; int tRcnt[4], tCfull[4], tgy[4];
  const void* x; const void* qnw; const void* qnb; bf16* xq;
  const void* ctx; const void* kvnw; const void* kvnb; bf16* kvn;
  const void* csrc[12]; bf16* cdst[12]; int cn[12];
  const void* xprobe;
};
__global__ __launch_bounds__(256) void prep_kernel(PrepArgs a, int* flag) {
  __shared__ __align__(16) float sbuf[1040];  // union: bf16 t[32*33] | xrow+sh
  const int z = blockIdx.z;
  const bool isbf = detect_bf(a.xprobe, sbuf);
  if (z < 4) {
    if ((int)blockIdx.y >= a.tgy[z]) return;
    t32(blockIdx.x, blockIdx.y, a.tsrc[z], a.tdst[z], 0, a.tRcnt[z], 0, a.tCfull[z],
        isbf, (bf16*)sbuf);
  } else if (z < 8) {
    const int row = blockIdx.x + 32 * blockIdx.y + (z & 1) * 1024;
    if (z < 6) ln_row(a.x,   a.qnw,  a.qnb,  a.xq,  DIM,  row, isbf, isbf, sbuf, sbuf + 1024);
    else       ln_row(a.ctx, a.kvnw, a.kvnb, a.kvn, CDIM, row, isbf, isbf, sbuf, sbuf + 1024);
  } else {
    const int b = blockIdx.x + 32 * blockIdx.y;
    if (b == 0 && threadIdx.x == 0) *flag = isbf ? 1 : 0;
    if (b >= 12) return;
    const void* in = a.csrc[b];
    bf16* out = a.cdst[b];
    const int n = a.cn[b];
    for (int i = threadIdx.x; i < n; i += 256)
      out[i] = isbf ? ((const bf16*)in)[i] : (bf16)((const float*)in)[i];
  }
}

// ---------------- post: z0 w1-h0 T, z1 w2-h0 T (remapped), z2 post-norm LN ----
// grid (64,32,3)
struct PostArgs {
  const void* w1; bf16* w1T;
  const void* w2; bf16* w2T;
  const bf16* xat; const void* pnw; const void* pnb; bf16* hln;
};
__global__ __launch_bounds__(256) void post_kernel(PostArgs a, const int* flag) {
  __shared__ __align__(16) float sbuf[1040];
  const int z = blockIdx.z;
  const bool isbf = (*flag != 0);
  if (z == 0) {  // w1[:, 0:2048] -> w1T [2048][1024]; 64 x 32
    t32(blockIdx.x, blockIdx.y, a.w1, a.w1T, 0, DIM, 0, DFF, isbf, (bf16*)sbuf);
  } else if (z == 1) {  // w2[0:2048, :] -> w2T [1024][2048]; 32 x 64 via remap
    const int tbx = blockIdx.x & 31, tby = blockIdx.y + 32 * (blockIdx.x >> 5);
    t32(tbx, tby, a.w2, a.w2T, 0, 2048, 0, DIM, isbf, (bf16*)sbuf);
  } else {  // post-norm LN over 2048 rows (input bf16, weights raw)
    const int row = blockIdx.x + 64 * blockIdx.y;
    ln_row(a.xat, a.pnw, a.pnb, a.hln, DIM, row, true, isbf, sbuf, sbuf + 1024);
  }
}

__device__ __forceinline__ float gelu_f(float x) {
  float u = 0.7978845608028654f * (x + 0.044715f * x * x * x);
  return 0.5f * x * (1.f + tanhf(u));
}

// -------- gemm_body: 64x64 tile, BK=64, 256 thr (4 waves 2x2, 32x32/wave) ------
// Harness-verified structure (rounds 4-6): 2-phase double-buffer + both-sides
// XOR swizzle. EPI: 1 bias+raw resid->bf16 | 2 bias+gelu->bf16 |
// 4 bias+bf16 resid->raw | 5 accumulate raw->raw (no bias)
template <int EPI>
__device__ __forceinline__ void gemm_body(
    int bx, int by,
    const bf16* __restrict__ A, const bf16* __restrict__ Bt,
    const bf16* __restrict__ bias, const void* __restrict__ resid,
    void* __restrict__ Cout, int K, int ldc, const int* flag) {
  __shared__ __align__(16) bf16 As[2][64 * 64];
  __shared__ __align__(16) bf16 Bs[2][64 * 64];
  const int tid = threadIdx.x;
  const int lane = tid & 63, wv = tid >> 6;
  const int lq = lane >> 4, lm = lane & 15;
  const int row0 = by * 64, col0 = bx * 64;
  const int wr = (wv >> 1) * 32, wc = (wv & 1) * 32;

  const int sr = lane >> 3;              // staging row within 8-row group
  const int sc = ((lane & 7) ^ sr) * 8;  // pre-swizzled source col (elems)
  const int swz = (lm & 7) << 3;         // read-side XOR (elems)

  f32x4 acc[2][2] = {};

  const bf16* Abase = A + (size_t)(row0 + wv * 16 + sr) * K + sc;
  const bf16* Bbase = Bt + (size_t)(col0 + wv * 16 + sr) * K + sc;

  const int nt = K >> 6;
#pragma unroll
  for (int b = 0; b < 2; b++) {
    async16(Abase + (size_t)(b * 8) * K, &As[0][wv * 1024 + b * 512]);
    async16(Bbase + (size_t)(b * 8) * K, &Bs[0][wv * 1024 + b * 512]);
  }
  __syncthreads();

  int cur = 0;
  for (int t = 0; t < nt; ++t) {
    if (t + 1 < nt) {  // prefetch next tile; loads fly under the MFMA phase
      const int k1 = (t + 1) << 6;
#pragma unroll
      for (int b = 0; b < 2; b++) {
        async16(Abase + (size_t)(b * 8) * K + k1, &As[cur ^ 1][wv * 1024 + b * 512]);
        async16(Bbase + (size_t)(b * 8) * K + k1, &Bs[cur ^ 1][wv * 1024 + b * 512]);
      }
    }
#pragma unroll
    for (int kh = 0; kh < 2; kh++) {
      const int cofs = (kh * 32 + lq * 8) ^ swz;
      bf16x8 af[2], bfv[2];
#pragma unroll
      for (int i = 0; i < 2; i++)
        af[i] = *(const bf16x8*)&As[cur][(wr + i * 16 + lm) * 64 + cofs];
#pragma unroll
      for (int j = 0; j < 2; j++)
        bfv[j] = *(const bf16x8*)&Bs[cur][(wc + j * 16 + lm) * 64 + cofs];
#pragma unroll
      for (int i = 0; i < 2; i++)
#pragma unroll
        for (int j = 0; j < 2; j++)
          acc[i][j] = __builtin_amdgcn_mfma_f32_16x16x32_bf16(af[i], bfv[j], acc[i][j], 0, 0, 0);
    }
    __syncthreads();  // drains prefetch vmcnt + this tile's lgkm reads
    cur ^= 1;
  }

  const bool isbf = (*flag != 0);
#pragma unroll
  for (int i = 0; i < 2; i++) {
    const int rb = row0 + wr + i * 16 + lq * 4;
#pragma unroll
    for (int j = 0; j < 2; j++) {
      const int c = col0 + wc + j * 16 + lm;
      const float bv = (EPI != 5) ? (float)bias[c] : 0.f;
#pragma unroll
      for (int rg = 0; rg < 4; rg++) {
        const size_t idx = (size_t)(rb + rg) * ldc + c;
        float v = acc[i][j][rg] + bv;
        if (EPI == 1)
          v += isbf ? (float)((const bf16*)resid)[idx] : ((const float*)resid)[idx];
        if (EPI == 2) v = gelu_f(v);
        if (EPI == 4) v += (float)((const bf16*)resid)[idx];
        if (EPI == 5)
          v += isbf ? (float)((bf16*)Cout)[idx] : ((float*)Cout)[idx];
        if (EPI == 4 || EPI == 5) {
          if (isbf) ((bf16*)Cout)[idx] = (bf16)v;
          else      ((float*)Cout)[idx] = v;
        } else {
          ((bf16*)Cout)[idx] = (bf16)v;
        }
      }
    }
  }
}

template <int EPI>
__global__ __launch_bounds__(256) void gemm64db(
    const bf16* __restrict__ A, const bf16* __restrict__ Bt,
    const bf16* __restrict__ bias, const void* __restrict__ resid,
    void* __restrict__ Cout, int K, int ldc, const int* flag) {
  gemm_body<EPI>(blockIdx.x, blockIdx.y, A, Bt, bias, resid, Cout, K, ldc, flag);
}

// ---- fused MLP2-h0 gemm + MLP-h1 weight transposes (grid 64x32x3) ----
// z0: gemm<4> (bx<16, by<32). z1: w1[:,2048:4096]->w1T (w1T free: its reader
// MLP1-h0 already done). z2: w2[2048:,:]->w2Ts SHADOW (avoids racing z0's
// w2T reads), 32x64 via remap.
struct Mlp2Args {
  const bf16* h1; const bf16* w2T; const bf16* b2; const bf16* xat; void* out;
  const void* w1raw; bf16* w1Tdst;
  const void* w2raw; bf16* w2Tdst;
};
__global__ __launch_bounds__(256) void mlp2h0_fused(Mlp2Args a, const int* flag) {
  const int z = blockIdx.z;
  if (z == 0) {
    if ((int)blockIdx.x >= 16) return;
    gemm_body<4>(blockIdx.x, blockIdx.y, a.h1, a.w2T, a.b2, a.xat, a.out,
                 2048, DIM, flag);
  } else {
    __shared__ __align__(16) bf16 t[32 * 33];
    const bool isbf = (*flag != 0);
    if (z == 1) {
      t32(blockIdx.x, blockIdx.y, a.w1raw, a.w1Tdst, 0, DIM, 2048, DFF, isbf, t);
    } else {
      const int tbx = blockIdx.x & 31, tby = blockIdx.y + 32 * (blockIdx.x >> 5);
      t32(tbx, tby, a.w2raw, a.w2Tdst, 2048, 2048, 0, DIM, isbf, t);
    }
  }
}

// ------- fused q/k/v projection, z=2 computes V^T directly (bias per row) ------
struct QkvArgs {
  const bf16* A[3];
  const bf16* Bt[3];
  const bf16* bias[3];
  bf16* C[3];
  int K[3], ldc[3], brow[3];
};
__global__ __launch_bounds__(256) void gemm64db_qkv(QkvArgs a) {
  const int z = blockIdx.z;
  int bx, by;
  if (z < 2) { bx = blockIdx.y; by = blockIdx.x; }   // 16 col-blocks, 32 row-blocks
  else       { bx = blockIdx.x; by = blockIdx.y; }   // 32 col-blocks, 16 row-blocks
  const bf16* A = a.A[z];
  const bf16* Bt = a.Bt[z];
  const int K = a.K[z];
  __shared__ __align__(16) bf16 As[2][64 * 64];
  __shared__ __align__(16) bf16 Bs[2][64 * 64];
  const int tid = threadIdx.x;
  const int lane = tid & 63, wv = tid >> 6;
  const int lq = lane >> 4, lm = lane & 15;
  const int row0 = by * 64, col0 = bx * 64;
  const int wr = (wv >> 1) * 32, wc = (wv & 1) * 32;

  const int sr = lane >> 3;
  const int sc = ((lane & 7) ^ sr) * 8;
  const int swz = (lm & 7) << 3;

  f32x4 acc[2][2] = {};

  const bf16* Abase = A + (size_t)(row0 + wv * 16 + sr) * K + sc;
  const bf16* Bbase = Bt + (size_t)(col0 + wv * 16 + sr) * K + sc;

  const int nt = K >> 6;
#pragma unroll
  for (int b = 0; b < 2; b++) {
    async16(Abase + (size_t)(b * 8) * K, &As[0][wv * 1024 + b * 512]);
    async16(Bbase + (size_t)(b * 8) * K, &Bs[0][wv * 1024 + b * 512]);
  }
  __syncthreads();

  int cur = 0;
  for (int t = 0; t < nt; ++t) {
    if (t + 1 < nt) {
      const int k1 = (t + 1) << 6;
#pragma unroll
      for (int b = 0; b < 2; b++) {
        async16(Abase + (size_t)(b * 8) * K + k1, &As[cur ^ 1][wv * 1024 + b * 512]);
        async16(Bbase + (size_t)(b * 8) * K + k1, &Bs[cur ^ 1][wv * 1024 + b * 512]);
      }
    }
#pragma unroll
    for (int kh = 0; kh < 2; kh++) {
      const int cofs = (kh * 32 + lq * 8) ^ swz;
      bf16x8 af[2], bfv[2];
#pragma unroll
      for (int i = 0; i < 2; i++)
        af[i] = *(const bf16x8*)&As[cur][(wr + i * 16 + lm) * 64 + cofs];
#pragma unroll
      for (int j = 0; j < 2; j++)
        bfv[j] = *(const bf16x8*)&Bs[cur][(wc + j * 16 + lm) * 64 + cofs];
#pragma unroll
      for (int i = 0; i < 2; i++)
#pragma unroll
        for (int j = 0; j < 2; j++)
          acc[i][j] = __builtin_amdgcn_mfma_f32_16x16x32_bf16(af[i], bfv[j], acc[i][j], 0, 0, 0);
    }
    __syncthreads();
    cur ^= 1;
  }

  const bf16* bias = a.bias[z];
  bf16* C = a.C[z];
  const int ldc = a.ldc[z];
  const bool brow = a.brow[z] != 0;
#pragma unroll
  for (int i = 0; i < 2; i++) {
    const int rb = row0 + wr + i * 16 + lq * 4;
#pragma unroll
    for (int j = 0; j < 2; j++) {
      const int c = col0 + wc + j * 16 + lm;
      const float bcol = brow ? 0.f : (float)bias[c];
#pragma unroll
      for (int rg = 0; rg < 4; rg++) {
        const float bv = brow ? (float)bias[rb + rg] : bcol;
        C[(size_t)(rb + rg) * ldc + c] = (bf16)(acc[i][j][rg] + bv);
      }
    }
  }
}

// ---------------- Flash attention v11: QBLK=128, 8 waves (512 thr) ------------
// Staging work per thread HALVES vs QBLK=64 (each K/V tile serves 128 q-rows);
// per-wave MFMA work unchanged. T14 async reg-stage + XCD head grouping +
// setprio kept. LDS: KPs 32KB (Ks uses first 16KB; P^T [128n][128m] uses all)
// + Vs 16KB = 48KB; grid 512 blocks -> 2 blocks/CU, 4 waves/SIMD.
__global__ __launch_bounds__(512) void attn_kernel(
    const bf16* __restrict__ q, const bf16* __restrict__ k,
    const bf16* __restrict__ vT, bf16* __restrict__ pO0, bf16* __restrict__ pO1,
    float* __restrict__ l0, float* __restrict__ l1) {
  __shared__ __align__(16) bf16 KPs[128 * 128];  // Ks [128][64]; then P^T [128][128]
  __shared__ __align__(16) bf16 Vs[64 * 128];    // [d 64][m 128]
  const int tid = threadIdx.x, lane = tid & 63, wv = tid >> 6;
  const int lq = lane >> 4, lm = lane & 15;
  // XCD-aware bijective swizzle (512 = 8*64): XCD j gets 4 whole heads (1 half).
  const int fid = blockIdx.x + 16 * (blockIdx.y + 16 * blockIdx.z);
  const int sid = (fid & 7) * 64 + (fid >> 3);
  const int n0 = (sid & 15) * 128;
  const int h = (sid >> 4) & 15;
  const int half = sid >> 8;
  const int mbeg = half * (M_TOK / 2), mend = mbeg + M_TOK / 2;
  bf16* pO = half ? pO1 : pO0;
  float* lb = half ? l1 : l0;

  bf16x8 qf[2];
#pragma unroll
  for (int f = 0; f < 2; f++)
    qf[f] = *(const bf16x8*)&q[(size_t)(n0 + wv * 16 + lm) * DIM + h * 64 + f * 32 + lq * 8];

  f32x4 oacc[4] = {};  // O^T tiles: rows d, cols n (n-col = wv*16+lm)
  float lsum = 0.f;
  const float sc = 0.125f * 1.4426950408889634f;  // (1/sqrt(64)) * log2(e)

  // prologue: first K/V tile -> registers (512 thr -> 2 chunks each)
  bf16x8 kreg[2], vreg[2];
#pragma unroll
  for (int it = 0; it < 2; it++) {
    const int e = tid * 8 + it * 4096;
    kreg[it] = *(const bf16x8*)&k[(size_t)(mbeg + (e >> 6)) * DIM + h * 64 + (e & 63)];
    vreg[it] = *(const bf16x8*)&vT[(size_t)(h * 64 + (e >> 7)) * M_TOK + mbeg + (e & 127)];
  }

  for (int m0 = mbeg; m0 < mend; m0 += 128) {
    asm volatile("s_waitcnt lgkmcnt(0)" ::: "memory");
    __builtin_amdgcn_s_barrier();
#pragma unroll
    for (int it = 0; it < 2; it++) {  // regs -> LDS, swizzled
      const int e = tid * 8 + it * 4096;
      const int kr = e >> 6, kc = e & 63;
      *(bf16x8*)&KPs[kr * 64 + (kc ^ ((kr & 7) << 3))] = kreg[it];
      const int vr = e >> 7, vc = e & 127;
      *(bf16x8*)&Vs[vr * 128 + (vc ^ ((vr & 7) << 3))] = vreg[it];
    }
    if (m0 + 128 < mend) {  // issue next tile's loads; they fly under compute
      const int m1 = m0 + 128;
#pragma unroll
      for (int it = 0; it < 2; it++) {
        const int e = tid * 8 + it * 4096;
        kreg[it] = *(const bf16x8*)&k[(size_t)(m1 + (e >> 6)) * DIM + h * 64 + (e & 63)];
        vreg[it] = *(const bf16x8*)&vT[(size_t)(h * 64 + (e >> 7)) * M_TOK + m1 + (e & 127)];
      }
    }
    asm volatile("s_waitcnt lgkmcnt(0)" ::: "memory");
    __builtin_amdgcn_s_barrier();

    // S^T into regs: tile j rows m = j*16+lq*4+rg, col n = wv*16 + lm
    f32x4 s[8];
    __builtin_amdgcn_s_setprio(1);
#pragma unroll
    for (int j = 0; j < 8; j++) {
      const int kswz = (lm & 7) << 3;  // row = j*16+lm -> row&7 = lm&7
      bf16x8 kf0 = *(const bf16x8*)&KPs[(j * 16 + lm) * 64 + ((lq * 8) ^ kswz)];
      bf16x8 kf1 = *(const bf16x8*)&KPs[(j * 16 + lm) * 64 + ((32 + lq * 8) ^ kswz)];
      f32x4 z = {};
      z = __builtin_amdgcn_mfma_f32_16x16x32_bf16(kf0, qf[0], z, 0, 0, 0);
      s[j] = __builtin_amdgcn_mfma_f32_16x16x32_bf16(kf1, qf[1], z, 0, 0, 0);
    }
    __builtin_amdgcn_s_setprio(0);
    asm volatile("s_waitcnt lgkmcnt(0)" ::: "memory");
    __builtin_amdgcn_s_barrier();  // Ks region free -> becomes P^T [128][128]

#pragma unroll
    for (int j = 0; j < 8; j++) {
      bf16x4 pw;
#pragma unroll
      for (int rg = 0; rg < 4; rg++) {
        const float pv = exp2f(s[j][rg] * sc);
        lsum += pv;
        pw[rg] = (bf16)pv;
      }
      // P^T row n = wv*16+lm (row&7 = lm&7), col m = j*16+lq*4; swizzled write
      *(bf16x4*)&KPs[(wv * 16 + lm) * 128 + ((j * 16 + lq * 4) ^ ((lm & 7) << 3))] = pw;
    }

    // O^T += V^T P^T (pf rows are this wave's own -> same-wave RAW, lgkmcnt)
    __builtin_amdgcn_s_setprio(1);
#pragma unroll
    for (int kk = 0; kk < 4; kk++) {
      bf16x8 pf = *(const bf16x8*)&KPs[(wv * 16 + lm) * 128 +
                                       ((kk * 32 + lq * 8) ^ ((lm & 7) << 3))];
#pragma unroll
      for (int dt = 0; dt < 4; dt++) {
        bf16x8 vf = *(const bf16x8*)&Vs[(dt * 16 + lm) * 128 +
                                        ((kk * 32 + lq * 8) ^ ((lm & 7) << 3))];
        oacc[dt] = __builtin_amdgcn_mfma_f32_16x16x32_bf16(vf, pf, oacc[dt], 0, 0, 0);
      }
    }
    __builtin_amdgcn_s_setprio(0);
  }

  // partial row-sum: reduce over the 4 lanes sharing this n (lane bits 4..5)
  lsum += __shfl_xor(lsum, 16, 64);
  lsum += __shfl_xor(lsum, 32, 64);
  if (lane < 16) lb[h * N_TOK + n0 + wv * 16 + lane] = lsum;

  const int rn = n0 + wv * 16 + lm;
#pragma unroll
  for (int dt = 0; dt < 4; dt++) {
    bf16x4 ow;
#pragma unroll
    for (int rg = 0; rg < 4; rg++) ow[rg] = (bf16)oacc[dt][rg];
    *(bf16x4*)&pO[(size_t)rn * DIM + h * 64 + dt * 16 + lq * 4] = ow;
  }
}

// ---------------- combine: om = (pO0 + pO1) / (l0 + l1) ----------------
__global__ __launch_bounds__(256) void attn_combine(
    const bf16* __restrict__ pO0, const bf16* __restrict__ pO1,
    const float* __restrict__ l0, const float* __restrict__ l1,
    bf16* __restrict__ om) {
  const int i4 = (blockIdx.x * 256 + threadIdx.x) * 4;  // over N*DIM = 2M elems
  const int n = i4 >> 10;
  const int h = (i4 & 1023) >> 6;
  const float rinv = 1.f / (l0[h * N_TOK + n] + l1[h * N_TOK + n]);
  bf16x4 a = *(const bf16x4*)&pO0[i4];
  bf16x4 b = *(const bf16x4*)&pO1[i4];
  bf16x4 o;
#pragma unroll
  for (int r = 0; r < 4; r++) o[r] = (bf16)(((float)a[r] + (float)b[r]) * rinv);
  *(bf16x4*)&om[i4] = o;
}

extern "C" void kernel_launch(void* const* d_in, const int* in_sizes, int n_in,
                              void* d_out, int out_size, void* d_ws, size_t ws_size,
                              hipStream_t stream) {
  const void* x_r     = d_in[0];
  const void* ctx_r   = d_in[1];
  const void* wq_r    = d_in[2];
  const void* bq_r    = d_in[3];
  const void* wk_r    = d_in[4];
  const void* bk_r    = d_in[5];
  const void* wv_r    = d_in[6];
  const void* bv_r    = d_in[7];
  const void* wo_r    = d_in[8];
  const void* bo_r    = d_in[9];
  const void* w1_r    = d_in[10];
  const void* b1_r    = d_in[11];
  const void* w2_r    = d_in[12];
  const void* b2_r    = d_in[13];
  const void* qnw_r   = d_in[14];
  const void* qnb_r   = d_in[15];
  const void* kvnw_r  = d_in[16];
  const void* kvnb_r  = d_in[17];
  const void* pnw_r   = d_in[18];
  const void* pnb_r   = d_in[19];

  // ---- workspace carve: 14M bf16 elems + smalls (~28.0 MB, known-good) ----
  bf16* p = (bf16*)d_ws;
  const size_t MEG = 1024 * 1024;
  bf16* qm  = p;             bf16* hln = qm;
  bf16* km  = p + 2 * MEG;   bf16* xat = km;
  bf16* wC  = p + 4 * MEG;
  bf16* xq  = p + 8 * MEG;   bf16* pO0 = xq;   bf16* om = xq;
  bf16* vTb = p + 10 * MEG;
  bf16* kvn = p + 12 * MEG;  bf16* pO1 = kvn;
  bf16* h1h = p + 10 * MEG;  // MLP h1 half spans [10M,14M)
  bf16* SM  = p + 14 * MEG;
  int* flag = (int*)(p + 14 * MEG + 16384);

  bf16* wqT = wC;
  bf16* wkT = wC + 1 * MEG;
  bf16* wvT = wC + 1 * MEG + 786432;
  bf16* woT = wC + 2 * MEG + 524288;
  bf16* w1Th = wC;
  bf16* w2Th = wC + 2 * MEG;
  bf16* w2Ts = p + 8 * MEG;      // shadow w2T-h1 in dead om region (2M elems)
  float* l0 = (float*)wC;        // parks in dead wqT region after qkv (128 KB)
  float* l1 = l0 + N_TOK * 16;   // 32768 floats each

  bf16* bqc = SM, *bkc = SM + 1024, *bvc = SM + 2048, *boc = SM + 3072;
  bf16* b1c = SM + 4096, *b2c = SM + 8192;
  bf16* qnw = SM + 9216, *qnb = SM + 10240;
  bf16* kvnw = SM + 11264, *kvnb = SM + 12032;
  bf16* pnw = SM + 12800, *pnb = SM + 13824;

  // 0) prep: conv + both input LNs + all 4 attention weight transposes
  {
    PrepArgs pa;
    pa.tsrc[0] = wq_r; pa.tdst[0] = wqT; pa.tRcnt[0] = DIM;  pa.tCfull[0] = DIM; pa.tgy[0] = 32;
    pa.tsrc[1] = wk_r; pa.tdst[1] = wkT; pa.tRcnt[1] = CDIM; pa.tCfull[1] = DIM; pa.tgy[1] = 24;
    pa.tsrc[2] = wv_r; pa.tdst[2] = wvT; pa.tRcnt[2] = CDIM; pa.tCfull[2] = DIM; pa.tgy[2] = 24;
    pa.tsrc[3] = wo_r; pa.tdst[3] = woT; pa.tRcnt[3] = DIM;  pa.tCfull[3] = DIM; pa.tgy[3] = 32;
    pa.x = x_r;   pa.qnw = qnw_r;   pa.qnb = qnb_r;   pa.xq = xq;
    pa.ctx = ctx_r; pa.kvnw = kvnw_r; pa.kvnb = kvnb_r; pa.kvn = kvn;
    pa.csrc[0] = bq_r;   pa.cdst[0] = bqc;  pa.cn[0] = DIM;
    pa.csrc[1] = bk_r;   pa.cdst[1] = bkc;  pa.cn[1] = DIM;
    pa.csrc[2] = bv_r;   pa.cdst[2] = bvc;  pa.cn[2] = DIM;
    pa.csrc[3] = bo_r;   pa.cdst[3] = boc;  pa.cn[3] = DIM;
    pa.csrc[4] = b1_r;   pa.cdst[4] = b1c;  pa.cn[4] = DFF;
    pa.csrc[5] = b2_r;   pa.cdst[5] = b2c;  pa.cn[5] = DIM;
    pa.csrc[6] = qnw_r;  pa.cdst[6] = qnw;  pa.cn[6] = DIM;
    pa.csrc[7] = qnb_r;  pa.cdst[7] = qnb;  pa.cn[7] = DIM;
    pa.csrc[8] = kvnw_r; pa.cdst[8] = kvnw; pa.cn[8] = CDIM;
    pa.csrc[9] = kvnb_r; pa.cdst[9] = kvnb; pa.cn[9] = CDIM;
    pa.csrc[10] = pnw_r; pa.cdst[10] = pnw; pa.cn[10] = DIM;
    pa.csrc[11] = pnb_r; pa.cdst[11] = pnb; pa.cn[11] = DIM;
    pa.xprobe = x_r;
    prep_kernel<<<dim3(32, 32, 9), 256, 0, stream>>>(pa, flag);
  }

  // 1) fused q/k/v; z=2 emits V^T directly (A=wvT rows d, Bt=kvn rows m)
  {
    QkvArgs qa;
    qa.A[0] = xq;  qa.Bt[0] = wqT; qa.bias[0] = bqc; qa.C[0] = qm;
    qa.K[0] = DIM;  qa.ldc[0] = DIM;   qa.brow[0] = 0;
    qa.A[1] = kvn; qa.Bt[1] = wkT; qa.bias[1] = bkc; qa.C[1] = km;
    qa.K[1] = CDIM; qa.ldc[1] = DIM;   qa.brow[1] = 0;
    qa.A[2] = wvT; qa.Bt[2] = kvn; qa.bias[2] = bvc; qa.C[2] = vTb;
    qa.K[2] = CDIM; qa.ldc[2] = M_TOK; qa.brow[2] = 1;
    gemm64db_qkv<<<dim3(32, 16, 3), 256, 0, stream>>>(qa);
  }

  // 2) attention split-M (512 blocks x 512 thr) + combine
  attn_kernel<<<dim3(16, 16, 2), 512, 0, stream>>>(qm, km, vTb, pO0, pO1, l0, l1);
  attn_combine<<<2048, 256, 0, stream>>>(pO0, pO1, l0, l1, om);

  // 3) o-projection + raw-dtype residual(x)
  gemm64db<1><<<dim3(16, 32), 256, 0, stream>>>(om, woT, boc, x_r, xat, DIM, DIM, flag);

  // 4) post: post-norm LN + MLP-h0 w1/w2 transposes in one launch
  {
    PostArgs po;
    po.w1 = w1_r; po.w1T = w1Th;
    po.w2 = w2_r; po.w2T = w2Th;
    po.xat = xat; po.pnw = pnw_r; po.pnb = pnb_r; po.hln = hln;
    post_kernel<<<dim3(64, 32, 3), 256, 0, stream>>>(po, flag);
  }

  // 5) MLP1 half 0
  gemm64db<2><<<dim3(32, 32), 256, 0, stream>>>(hln, w1Th, b1c, nullptr,
                                                h1h, DIM, 2048, flag);

  // 6) MLP2 half 0 fused with MLP-h1 weight transposes (w2-h1 -> shadow w2Ts)
  {
    Mlp2Args ma;
    ma.h1 = h1h; ma.w2T = w2Th; ma.b2 = b2c; ma.xat = xat; ma.out = d_out;
    ma.w1raw = w1_r; ma.w1Tdst = w1Th;
    ma.w2raw = w2_r; ma.w2Tdst = w2Ts;
    mlp2h0_fused<<<dim3(64, 32, 3), 256, 0, stream>>>(ma, flag);
  }

  // 7) MLP half 1
  gemm64db<2><<<dim3(32, 32), 256, 0, stream>>>(hln, w1Th, b1c + 2048, nullptr,
                                                h1h, DIM, 2048, flag);
  gemm64db<5><<<dim3(16, 32), 256, 0, stream>>>(h1h, w2Ts, b2c, nullptr, d_out,
                                                2048, DIM, flag);
}

// Round 8
// 333.791 us; speedup vs baseline: 1.3191x; 1.0026x over previous
//
#include <hip/hip_runtime.h>

typedef __bf16 bf16;
typedef __bf16 bf16x4 __attribute__((ext_vector_type(4)));
typedef __bf16 bf16x8 __attribute__((ext_vector_type(8)));
typedef float f32x4 __attribute__((ext_vector_type(4)));

#define N_TOK 2048
#define M_TOK 2048
#define DIM 1024
#define CDIM 768
#define DFF 4096

// async global->LDS, 16B per lane; LDS dest = wave-uniform base + lane*16
static __device__ __forceinline__ void async16(const void* g, void* l) {
  __builtin_amdgcn_global_load_lds((const __attribute__((address_space(1))) void*)g,
                                   (__attribute__((address_space(3))) void*)l, 16, 0, 0);
}

// ---------- shared device helpers ----------
// local dtype detect: low-16 halves of first 512 words plausible as bf16?
__device__ __forceinline__ bool detect_bf(const void* xprobe, float* sbuf) {
  int* cnt = (int*)sbuf;
  if (threadIdx.x == 0) *cnt = 0;
  __syncthreads();
  const unsigned* w = (const unsigned*)xprobe;
  int ok = 0;
  for (int i = threadIdx.x; i < 512; i += 256) {
    unsigned lo = w[i] & 0xFFFFu;
    float f = __uint_as_float(lo << 16);
    if (lo == 0u || (fabsf(f) > 1e-3f && fabsf(f) < 1e3f)) ok++;
  }
  atomicAdd(cnt, ok);
  __syncthreads();
  return *cnt >= 256;
}

// 32x32 transpose tile (256 active thr); explicit block coords (bx, by)
__device__ __forceinline__ void t32(int bx, int by, const void* in, bf16* out,
                                    int r0, int Rcnt, int c0, int Cfull,
                                    bool isbf, bf16* t) {
  const int cb = bx * 32, rb = by * 32;
  const int tx = threadIdx.x & 31, ty = threadIdx.x >> 5;
#pragma unroll
  for (int i = 0; i < 4; i++) {
    const size_t r = (size_t)(r0 + rb + ty + i * 8);
    const size_t c = (size_t)(c0 + cb + tx);
    float v = isbf ? (float)((const bf16*)in)[r * Cfull + c]
                   : ((const float*)in)[r * Cfull + c];
    t[(ty + i * 8) * 33 + tx] = (bf16)v;
  }
  __syncthreads();
#pragma unroll
  for (int i = 0; i < 4; i++)
    out[(size_t)(cb + ty + i * 8) * Rcnt + rb + tx] = t[tx * 33 + ty + i * 8];
}

// LayerNorm one row, single global read (row staged in LDS floats).
__device__ __forceinline__ void ln_row(const void* x, const void* wr, const void* br,
                                       bf16* outp, int cols, int row,
                                       bool in_bf, bool w_bf,
                                       float* xrow, float* sh) {
  const bf16* xr_b = (const bf16*)x + (size_t)row * cols;
  const float* xr_f = (const float*)x + (size_t)row * cols;
  bf16* orow = outp + (size_t)row * cols;
  float s = 0.f, ss = 0.f;
  for (int c = threadIdx.x; c < cols; c += 256) {
    float v = in_bf ? (float)xr_b[c] : xr_f[c];
    xrow[c] = v;
    s += v; ss += v * v;
  }
  for (int d = 1; d < 64; d <<= 1) { s += __shfl_xor(s, d, 64); ss += __shfl_xor(ss, d, 64); }
  const int wv = threadIdx.x >> 6, lane = threadIdx.x & 63;
  if (lane == 0) { sh[wv] = s; sh[4 + wv] = ss; }
  __syncthreads();
  s = sh[0] + sh[1] + sh[2] + sh[3];
  ss = sh[4] + sh[5] + sh[6] + sh[7];
  const float mean = s / cols;
  float var = ss / cols - mean * mean;
  var = fmaxf(var, 0.f);
  const float r = rsqrtf(var + 1e-12f);
  for (int c = threadIdx.x; c < cols; c += 256) {
    const float wv2 = w_bf ? (float)((const bf16*)wr)[c] : ((const float*)wr)[c];
    const float bv2 = w_bf ? (float)((const bf16*)br)[c] : ((const float*)br)[c];
    orow[c] = (bf16)((xrow[c] - mean) * r * wv2 + bv2);
  }
}

// ---------------- prep: z0-3 attn-weight transposes, z4-7 input LNs, z8 conv --
struct PrepArgs {
  const void* tsrc[4]; bf16* tdst[4]; int tRcnt[4], tCfull[4], tgy[4];
  const void* x; const void* qnw; const void* qnb; bf16* xq;
  const void* ctx; const void* kvnw; const void* kvnb; bf16* kvn;
  const void* csrc[12]; bf16* cdst[12]; int cn[12];
  const void* xprobe;
};
__global__ __launch_bounds__(256) void prep_kernel(PrepArgs a, int* flag) {
  __shared__ __align__(16) float sbuf[1040];  // union: bf16 t[32*33] | xrow+sh
  const int z = blockIdx.z;
  const bool isbf = detect_bf(a.xprobe, sbuf);
  if (z < 4) {
    if ((int)blockIdx.y >= a.tgy[z]) return;
    t32(blockIdx.x, blockIdx.y, a.tsrc[z], a.tdst[z], 0, a.tRcnt[z], 0, a.tCfull[z],
        isbf, (bf16*)sbuf);
  } else if (z < 8) {
    const int row = blockIdx.x + 32 * blockIdx.y + (z & 1) * 1024;
    if (z < 6) ln_row(a.x,   a.qnw,  a.qnb,  a.xq,  DIM,  row, isbf, isbf, sbuf, sbuf + 1024);
    else       ln_row(a.ctx, a.kvnw, a.kvnb, a.kvn, CDIM, row, isbf, isbf, sbuf, sbuf + 1024);
  } else {
    const int b = blockIdx.x + 32 * blockIdx.y;
    if (b == 0 && threadIdx.x == 0) *flag = isbf ? 1 : 0;
    if (b >= 12) return;
    const void* in = a.csrc[b];
    bf16* out = a.cdst[b];
    const int n = a.cn[b];
    for (int i = threadIdx.x; i < n; i += 256)
      out[i] = isbf ? ((const bf16*)in)[i] : (bf16)((const float*)in)[i];
  }
}

// ---------------- post: z0 w2-h0 T (remapped 32x64), z1 post-norm LN ----------
// grid (64,32,2). (w1-h0 T moved into the attn launch.)
struct PostArgs {
  const void* w2; bf16* w2T;
  const bf16* xat; const void* pnw; const void* pnb; bf16* hln;
};
__global__ __launch_bounds__(256) void post_kernel(PostArgs a, const int* flag) {
  __shared__ __align__(16) float sbuf[1040];
  const bool isbf = (*flag != 0);
  if (blockIdx.z == 0) {  // w2[0:2048, :] -> w2T [1024][2048]; 32 x 64 via remap
    const int tbx = blockIdx.x & 31, tby = blockIdx.y + 32 * (blockIdx.x >> 5);
    t32(tbx, tby, a.w2, a.w2T, 0, 2048, 0, DIM, isbf, (bf16*)sbuf);
  } else {  // post-norm LN over 2048 rows (input bf16, weights raw)
    const int row = blockIdx.x + 64 * blockIdx.y;
    ln_row(a.xat, a.pnw, a.pnb, a.hln, DIM, row, true, isbf, sbuf, sbuf + 1024);
  }
}

__device__ __forceinline__ float gelu_f(float x) {
  float u = 0.7978845608028654f * (x + 0.044715f * x * x * x);
  return 0.5f * x * (1.f + tanhf(u));
}

// -------- gemm_body: 64x64 tile, BK=64, 256 thr (4 waves 2x2, 32x32/wave) ------
// Harness-verified (rounds 4-7): 2-phase double-buffer + both-sides XOR swizzle.
template <int EPI>
__device__ __forceinline__ void gemm_body(
    int bx, int by,
    const bf16* __restrict__ A, const bf16* __restrict__ Bt,
    const bf16* __restrict__ bias, const void* __restrict__ resid,
    void* __restrict__ Cout, int K, int ldc, const int* flag) {
  __shared__ __align__(16) bf16 As[2][64 * 64];
  __shared__ __align__(16) bf16 Bs[2][64 * 64];
  const int tid = threadIdx.x;
  const int lane = tid & 63, wv = tid >> 6;
  const int lq = lane >> 4, lm = lane & 15;
  const int row0 = by * 64, col0 = bx * 64;
  const int wr = (wv >> 1) * 32, wc = (wv & 1) * 32;

  const int sr = lane >> 3;              // staging row within 8-row group
  const int sc = ((lane & 7) ^ sr) * 8;  // pre-swizzled source col (elems)
  const int swz = (lm & 7) << 3;         // read-side XOR (elems)

  f32x4 acc[2][2] = {};

  const bf16* Abase = A + (size_t)(row0 + wv * 16 + sr) * K + sc;
  const bf16* Bbase = Bt + (size_t)(col0 + wv * 16 + sr) * K + sc;

  const int nt = K >> 6;
#pragma unroll
  for (int b = 0; b < 2; b++) {
    async16(Abase + (size_t)(b * 8) * K, &As[0][wv * 1024 + b * 512]);
    async16(Bbase + (size_t)(b * 8) * K, &Bs[0][wv * 1024 + b * 512]);
  }
  __syncthreads();

  int cur = 0;
  for (int t = 0; t < nt; ++t) {
    if (t + 1 < nt) {  // prefetch next tile; loads fly under the MFMA phase
      const int k1 = (t + 1) << 6;
#pragma unroll
      for (int b = 0; b < 2; b++) {
        async16(Abase + (size_t)(b * 8) * K + k1, &As[cur ^ 1][wv * 1024 + b * 512]);
        async16(Bbase + (size_t)(b * 8) * K + k1, &Bs[cur ^ 1][wv * 1024 + b * 512]);
      }
    }
#pragma unroll
    for (int kh = 0; kh < 2; kh++) {
      const int cofs = (kh * 32 + lq * 8) ^ swz;
      bf16x8 af[2], bfv[2];
#pragma unroll
      for (int i = 0; i < 2; i++)
        af[i] = *(const bf16x8*)&As[cur][(wr + i * 16 + lm) * 64 + cofs];
#pragma unroll
      for (int j = 0; j < 2; j++)
        bfv[j] = *(const bf16x8*)&Bs[cur][(wc + j * 16 + lm) * 64 + cofs];
#pragma unroll
      for (int i = 0; i < 2; i++)
#pragma unroll
        for (int j = 0; j < 2; j++)
          acc[i][j] = __builtin_amdgcn_mfma_f32_16x16x32_bf16(af[i], bfv[j], acc[i][j], 0, 0, 0);
    }
    __syncthreads();  // drains prefetch vmcnt + this tile's lgkm reads
    cur ^= 1;
  }

  const bool isbf = (*flag != 0);
#pragma unroll
  for (int i = 0; i < 2; i++) {
    const int rb = row0 + wr + i * 16 + lq * 4;
#pragma unroll
    for (int j = 0; j < 2; j++) {
      const int c = col0 + wc + j * 16 + lm;
      const float bv = (EPI != 5) ? (float)bias[c] : 0.f;
#pragma unroll
      for (int rg = 0; rg < 4; rg++) {
        const size_t idx = (size_t)(rb + rg) * ldc + c;
        float v = acc[i][j][rg] + bv;
        if (EPI == 1)
          v += isbf ? (float)((const bf16*)resid)[idx] : ((const float*)resid)[idx];
        if (EPI == 2) v = gelu_f(v);
        if (EPI == 4) v += (float)((const bf16*)resid)[idx];
        if (EPI == 5)
          v += isbf ? (float)((bf16*)Cout)[idx] : ((float*)Cout)[idx];
        if (EPI == 4 || EPI == 5) {
          if (isbf) ((bf16*)Cout)[idx] = (bf16)v;
          else      ((float*)Cout)[idx] = v;
        } else {
          ((bf16*)Cout)[idx] = (bf16)v;
        }
      }
    }
  }
}

// T1 XCD swizzle: contiguous grid chunks per XCD (all grids have nwg % 8 == 0)
template <int EPI>
__global__ __launch_bounds__(256) void gemm64db(
    const bf16* __restrict__ A, const bf16* __restrict__ Bt,
    const bf16* __restrict__ bias, const void* __restrict__ resid,
    void* __restrict__ Cout, int K, int ldc, const int* flag) {
  const int gx = gridDim.x;
  const int nwg = gx * gridDim.y;
  const int fid = blockIdx.x + gx * blockIdx.y;
  const int sid = (fid & 7) * (nwg >> 3) + (fid >> 3);
  gemm_body<EPI>(sid % gx, sid / gx, A, Bt, bias, resid, Cout, K, ldc, flag);
}

// ---- fused MLP2-h0 gemm + MLP-h1 weight transposes (grid 64x32x3) ----
// z0: gemm<4> (bx<16, XCD-swizzled). z1: w1[:,2048:4096]->w1T (w1T free: its
// reader MLP1-h0 already done). z2: w2[2048:,:]->w2Ts SHADOW, 32x64 via remap.
struct Mlp2Args {
  const bf16* h1; const bf16* w2T; const bf16* b2; const bf16* xat; void* out;
  const void* w1raw; bf16* w1Tdst;
  const void* w2raw; bf16* w2Tdst;
};
__global__ __launch_bounds__(256) void mlp2h0_fused(Mlp2Args a, const int* flag) {
  const int z = blockIdx.z;
  if (z == 0) {
    if ((int)blockIdx.x >= 16) return;
    const int fid = blockIdx.x + 16 * blockIdx.y;  // 512 blocks
    const int sid = (fid & 7) * 64 + (fid >> 3);
    gemm_body<4>(sid & 15, sid >> 4, a.h1, a.w2T, a.b2, a.xat, a.out,
                 2048, DIM, flag);
  } else {
    __shared__ __align__(16) bf16 t[32 * 33];
    const bool isbf = (*flag != 0);
    if (z == 1) {
      t32(blockIdx.x, blockIdx.y, a.w1raw, a.w1Tdst, 0, DIM, 2048, DFF, isbf, t);
    } else {
      const int tbx = blockIdx.x & 31, tby = blockIdx.y + 32 * (blockIdx.x >> 5);
      t32(tbx, tby, a.w2raw, a.w2Tdst, 2048, 2048, 0, DIM, isbf, t);
    }
  }
}

// ------- fused q/k/v projection, z=2 computes V^T directly (bias per row) ------
struct QkvArgs {
  const bf16* A[3];
  const bf16* Bt[3];
  const bf16* bias[3];
  bf16* C[3];
  int K[3], ldc[3], brow[3];
};
__global__ __launch_bounds__(256) void gemm64db_qkv(QkvArgs a) {
  const int z = blockIdx.z;
  int gx, bx0, by0;
  if (z < 2) { gx = 16; bx0 = blockIdx.y; by0 = blockIdx.x; }   // 16c x 32r
  else       { gx = 32; bx0 = blockIdx.x; by0 = blockIdx.y; }   // 32c x 16r
  const int fid = bx0 + gx * by0;                                // 512 blocks
  const int sid = (fid & 7) * 64 + (fid >> 3);
  const int bx = sid % gx, by = sid / gx;
  const bf16* A = a.A[z];
  const bf16* Bt = a.Bt[z];
  const int K = a.K[z];
  __shared__ __align__(16) bf16 As[2][64 * 64];
  __shared__ __align__(16) bf16 Bs[2][64 * 64];
  const int tid = threadIdx.x;
  const int lane = tid & 63, wv = tid >> 6;
  const int lq = lane >> 4, lm = lane & 15;
  const int row0 = by * 64, col0 = bx * 64;
  const int wr = (wv >> 1) * 32, wc = (wv & 1) * 32;

  const int sr = lane >> 3;
  const int sc = ((lane & 7) ^ sr) * 8;
  const int swz = (lm & 7) << 3;

  f32x4 acc[2][2] = {};

  const bf16* Abase = A + (size_t)(row0 + wv * 16 + sr) * K + sc;
  const bf16* Bbase = Bt + (size_t)(col0 + wv * 16 + sr) * K + sc;

  const int nt = K >> 6;
#pragma unroll
  for (int b = 0; b < 2; b++) {
    async16(Abase + (size_t)(b * 8) * K, &As[0][wv * 1024 + b * 512]);
    async16(Bbase + (size_t)(b * 8) * K, &Bs[0][wv * 1024 + b * 512]);
  }
  __syncthreads();

  int cur = 0;
  for (int t = 0; t < nt; ++t) {
    if (t + 1 < nt) {
      const int k1 = (t + 1) << 6;
#pragma unroll
      for (int b = 0; b < 2; b++) {
        async16(Abase + (size_t)(b * 8) * K + k1, &As[cur ^ 1][wv * 1024 + b * 512]);
        async16(Bbase + (size_t)(b * 8) * K + k1, &Bs[cur ^ 1][wv * 1024 + b * 512]);
      }
    }
#pragma unroll
    for (int kh = 0; kh < 2; kh++) {
      const int cofs = (kh * 32 + lq * 8) ^ swz;
      bf16x8 af[2], bfv[2];
#pragma unroll
      for (int i = 0; i < 2; i++)
        af[i] = *(const bf16x8*)&As[cur][(wr + i * 16 + lm) * 64 + cofs];
#pragma unroll
      for (int j = 0; j < 2; j++)
        bfv[j] = *(const bf16x8*)&Bs[cur][(wc + j * 16 + lm) * 64 + cofs];
#pragma unroll
      for (int i = 0; i < 2; i++)
#pragma unroll
        for (int j = 0; j < 2; j++)
          acc[i][j] = __builtin_amdgcn_mfma_f32_16x16x32_bf16(af[i], bfv[j], acc[i][j], 0, 0, 0);
    }
    __syncthreads();
    cur ^= 1;
  }

  const bf16* bias = a.bias[z];
  bf16* C = a.C[z];
  const int ldc = a.ldc[z];
  const bool brow = a.brow[z] != 0;
#pragma unroll
  for (int i = 0; i < 2; i++) {
    const int rb = row0 + wr + i * 16 + lq * 4;
#pragma unroll
    for (int j = 0; j < 2; j++) {
      const int c = col0 + wc + j * 16 + lm;
      const float bcol = brow ? 0.f : (float)bias[c];
#pragma unroll
      for (int rg = 0; rg < 4; rg++) {
        const float bv = brow ? (float)bias[rb + rg] : bcol;
        C[(size_t)(rb + rg) * ldc + c] = (bf16)(acc[i][j][rg] + bv);
      }
    }
  }
}

// ---------------- Flash attention v12: v11 + absorbed w1-h0 transpose ---------
// z0,z1: attention halves (512 thr). z2..9: w1[:,0:2048]->w1T transpose blocks
// (256 active thr, waves 4-7 exit; t32 buffer aliases KPs). Transposes' ~20MB
// of traffic hides under attn's latency-bound window (attn is 4.8% HBM).
__global__ __launch_bounds__(512) void attn_kernel(
    const bf16* __restrict__ q, const bf16* __restrict__ k,
    const bf16* __restrict__ vT, bf16* __restrict__ pO0, bf16* __restrict__ pO1,
    float* __restrict__ l0, float* __restrict__ l1,
    const void* __restrict__ w1raw, bf16* __restrict__ w1Tdst,
    const int* __restrict__ flag) {
  __shared__ __align__(16) bf16 KPs[128 * 128];  // Ks [128][64]; then P^T [128][128]
  __shared__ __align__(16) bf16 Vs[64 * 128];    // [d 64][m 128]
  const int z = blockIdx.z;
  if (z >= 2) {  // w1-h0 transpose: 2048 blocks over z=2..9
    if (threadIdx.x >= 256) return;  // waves 4-7 exit (wave-aligned)
    const int id = blockIdx.x + 16 * blockIdx.y + 256 * (z - 2);
    const bool isbf = (*flag != 0);
    t32(id & 63, id >> 6, w1raw, w1Tdst, 0, DIM, 0, DFF, isbf, (bf16*)KPs);
    return;
  }
  const int tid = threadIdx.x, lane = tid & 63, wv = tid >> 6;
  const int lq = lane >> 4, lm = lane & 15;
  // XCD-aware bijective swizzle (512 = 8*64): XCD j gets 4 whole heads (1 half).
  const int fid = blockIdx.x + 16 * (blockIdx.y + 16 * z);
  const int sid = (fid & 7) * 64 + (fid >> 3);
  const int n0 = (sid & 15) * 128;
  const int h = (sid >> 4) & 15;
  const int half = sid >> 8;
  const int mbeg = half * (M_TOK / 2), mend = mbeg + M_TOK / 2;
  bf16* pO = half ? pO1 : pO0;
  float* lb = half ? l1 : l0;

  bf16x8 qf[2];
#pragma unroll
  for (int f = 0; f < 2; f++)
    qf[f] = *(const bf16x8*)&q[(size_t)(n0 + wv * 16 + lm) * DIM + h * 64 + f * 32 + lq * 8];

  f32x4 oacc[4] = {};  // O^T tiles: rows d, cols n (n-col = wv*16+lm)
  float lsum = 0.f;
  const float sc = 0.125f * 1.4426950408889634f;  // (1/sqrt(64)) * log2(e)

  // prologue: first K/V tile -> registers (512 thr -> 2 chunks each)
  bf16x8 kreg[2], vreg[2];
#pragma unroll
  for (int it = 0; it < 2; it++) {
    const int e = tid * 8 + it * 4096;
    kreg[it] = *(const bf16x8*)&k[(size_t)(mbeg + (e >> 6)) * DIM + h * 64 + (e & 63)];
    vreg[it] = *(const bf16x8*)&vT[(size_t)(h * 64 + (e >> 7)) * M_TOK + mbeg + (e & 127)];
  }

  for (int m0 = mbeg; m0 < mend; m0 += 128) {
    asm volatile("s_waitcnt lgkmcnt(0)" ::: "memory");
    __builtin_amdgcn_s_barrier();
#pragma unroll
    for (int it = 0; it < 2; it++) {  // regs -> LDS, swizzled
      const int e = tid * 8 + it * 4096;
      const int kr = e >> 6, kc = e & 63;
      *(bf16x8*)&KPs[kr * 64 + (kc ^ ((kr & 7) << 3))] = kreg[it];
      const int vr = e >> 7, vc = e & 127;
      *(bf16x8*)&Vs[vr * 128 + (vc ^ ((vr & 7) << 3))] = vreg[it];
    }
    if (m0 + 128 < mend) {  // issue next tile's loads; they fly under compute
      const int m1 = m0 + 128;
#pragma unroll
      for (int it = 0; it < 2; it++) {
        const int e = tid * 8 + it * 4096;
        kreg[it] = *(const bf16x8*)&k[(size_t)(m1 + (e >> 6)) * DIM + h * 64 + (e & 63)];
        vreg[it] = *(const bf16x8*)&vT[(size_t)(h * 64 + (e >> 7)) * M_TOK + m1 + (e & 127)];
      }
    }
    asm volatile("s_waitcnt lgkmcnt(0)" ::: "memory");
    __builtin_amdgcn_s_barrier();

    // S^T into regs: tile j rows m = j*16+lq*4+rg, col n = wv*16 + lm
    f32x4 s[8];
    __builtin_amdgcn_s_setprio(1);
#pragma unroll
    for (int j = 0; j < 8; j++) {
      const int kswz = (lm & 7) << 3;  // row = j*16+lm -> row&7 = lm&7
      bf16x8 kf0 = *(const bf16x8*)&KPs[(j * 16 + lm) * 64 + ((lq * 8) ^ kswz)];
      bf16x8 kf1 = *(const bf16x8*)&KPs[(j * 16 + lm) * 64 + ((32 + lq * 8) ^ kswz)];
      f32x4 zz = {};
      zz = __builtin_amdgcn_mfma_f32_16x16x32_bf16(kf0, qf[0], zz, 0, 0, 0);
      s[j] = __builtin_amdgcn_mfma_f32_16x16x32_bf16(kf1, qf[1], zz, 0, 0, 0);
    }
    __builtin_amdgcn_s_setprio(0);
    asm volatile("s_waitcnt lgkmcnt(0)" ::: "memory");
    __builtin_amdgcn_s_barrier();  // Ks region free -> becomes P^T [128][128]

#pragma unroll
    for (int j = 0; j < 8; j++) {
      bf16x4 pw;
#pragma unroll
      for (int rg = 0; rg < 4; rg++) {
        const float pv = exp2f(s[j][rg] * sc);
        lsum += pv;
        pw[rg] = (bf16)pv;
      }
      // P^T row n = wv*16+lm (row&7 = lm&7), col m = j*16+lq*4; swizzled write
      *(bf16x4*)&KPs[(wv * 16 + lm) * 128 + ((j * 16 + lq * 4) ^ ((lm & 7) << 3))] = pw;
    }

    // O^T += V^T P^T (pf rows are this wave's own -> same-wave RAW, lgkmcnt)
    __builtin_amdgcn_s_setprio(1);
#pragma unroll
    for (int kk = 0; kk < 4; kk++) {
      bf16x8 pf = *(const bf16x8*)&KPs[(wv * 16 + lm) * 128 +
                                       ((kk * 32 + lq * 8) ^ ((lm & 7) << 3))];
#pragma unroll
      for (int dt = 0; dt < 4; dt++) {
        bf16x8 vf = *(const bf16x8*)&Vs[(dt * 16 + lm) * 128 +
                                        ((kk * 32 + lq * 8) ^ ((lm & 7) << 3))];
        oacc[dt] = __builtin_amdgcn_mfma_f32_16x16x32_bf16(vf, pf, oacc[dt], 0, 0, 0);
      }
    }
    __builtin_amdgcn_s_setprio(0);
  }

  // partial row-sum: reduce over the 4 lanes sharing this n (lane bits 4..5)
  lsum += __shfl_xor(lsum, 16, 64);
  lsum += __shfl_xor(lsum, 32, 64);
  if (lane < 16) lb[h * N_TOK + n0 + wv * 16 + lane] = lsum;

  const int rn = n0 + wv * 16 + lm;
#pragma unroll
  for (int dt = 0; dt < 4; dt++) {
    bf16x4 ow;
#pragma unroll
    for (int rg = 0; rg < 4; rg++) ow[rg] = (bf16)oacc[dt][rg];
    *(bf16x4*)&pO[(size_t)rn * DIM + h * 64 + dt * 16 + lq * 4] = ow;
  }
}

// ---------------- combine: om = (pO0 + pO1) / (l0 + l1) ----------------
__global__ __launch_bounds__(256) void attn_combine(
    const bf16* __restrict__ pO0, const bf16* __restrict__ pO1,
    const float* __restrict__ l0, const float* __restrict__ l1,
    bf16* __restrict__ om) {
  const int i4 = (blockIdx.x * 256 + threadIdx.x) * 4;  // over N*DIM = 2M elems
  const int n = i4 >> 10;
  const int h = (i4 & 1023) >> 6;
  const float rinv = 1.f / (l0[h * N_TOK + n] + l1[h * N_TOK + n]);
  bf16x4 a = *(const bf16x4*)&pO0[i4];
  bf16x4 b = *(const bf16x4*)&pO1[i4];
  bf16x4 o;
#pragma unroll
  for (int r = 0; r < 4; r++) o[r] = (bf16)(((float)a[r] + (float)b[r]) * rinv);
  *(bf16x4*)&om[i4] = o;
}

extern "C" void kernel_launch(void* const* d_in, const int* in_sizes, int n_in,
                              void* d_out, int out_size, void* d_ws, size_t ws_size,
                              hipStream_t stream) {
  const void* x_r     = d_in[0];
  const void* ctx_r   = d_in[1];
  const void* wq_r    = d_in[2];
  const void* bq_r    = d_in[3];
  const void* wk_r    = d_in[4];
  const void* bk_r    = d_in[5];
  const void* wv_r    = d_in[6];
  const void* bv_r    = d_in[7];
  const void* wo_r    = d_in[8];
  const void* bo_r    = d_in[9];
  const void* w1_r    = d_in[10];
  const void* b1_r    = d_in[11];
  const void* w2_r    = d_in[12];
  const void* b2_r    = d_in[13];
  const void* qnw_r   = d_in[14];
  const void* qnb_r   = d_in[15];
  const void* kvnw_r  = d_in[16];
  const void* kvnb_r  = d_in[17];
  const void* pnw_r   = d_in[18];
  const void* pnb_r   = d_in[19];

  // ---- workspace carve: 14M bf16 elems + smalls (~28.0 MB, known-good) ----
  bf16* p = (bf16*)d_ws;
  const size_t MEG = 1024 * 1024;
  bf16* qm  = p;             bf16* hln = qm;
  bf16* km  = p + 2 * MEG;   bf16* xat = km;
  bf16* wC  = p + 4 * MEG;
  bf16* xq  = p + 8 * MEG;   bf16* pO0 = xq;   bf16* om = xq;
  bf16* vTb = p + 10 * MEG;
  bf16* kvn = p + 12 * MEG;  bf16* pO1 = kvn;
  bf16* h1h = p + 10 * MEG;  // MLP h1 half spans [10M,14M)
  bf16* SM  = p + 14 * MEG;
  int* flag = (int*)(p + 14 * MEG + 16384);

  bf16* wqT = wC;
  bf16* wkT = wC + 1 * MEG;
  bf16* wvT = wC + 1 * MEG + 786432;
  bf16* woT = wC + 2 * MEG + 524288;
  bf16* w1Th = wC;
  bf16* w2Th = wC + 2 * MEG;
  bf16* w2Ts = p + 8 * MEG;      // shadow w2T-h1 in dead om region (2M elems)
  // l0/l1 in wC tail [3.5M,3.75M): free after woT through combine (w1Th/w2Th
  // only overwrite wC after combine has consumed l0/l1).
  float* l0 = (float*)(wC + 3584 * 1024);
  float* l1 = l0 + N_TOK * 16;   // 32768 floats each

  bf16* bqc = SM, *bkc = SM + 1024, *bvc = SM + 2048, *boc = SM + 3072;
  bf16* b1c = SM + 4096, *b2c = SM + 8192;
  bf16* qnw = SM + 9216, *qnb = SM + 10240;
  bf16* kvnw = SM + 11264, *kvnb = SM + 12032;
  bf16* pnw = SM + 12800, *pnb = SM + 13824;

  // 0) prep: conv + both input LNs + all 4 attention weight transposes
  {
    PrepArgs pa;
    pa.tsrc[0] = wq_r; pa.tdst[0] = wqT; pa.tRcnt[0] = DIM;  pa.tCfull[0] = DIM; pa.tgy[0] = 32;
    pa.tsrc[1] = wk_r; pa.tdst[1] = wkT; pa.tRcnt[1] = CDIM; pa.tCfull[1] = DIM; pa.tgy[1] = 24;
    pa.tsrc[2] = wv_r; pa.tdst[2] = wvT; pa.tRcnt[2] = CDIM; pa.tCfull[2] = DIM; pa.tgy[2] = 24;
    pa.tsrc[3] = wo_r; pa.tdst[3] = woT; pa.tRcnt[3] = DIM;  pa.tCfull[3] = DIM; pa.tgy[3] = 32;
    pa.x = x_r;   pa.qnw = qnw_r;   pa.qnb = qnb_r;   pa.xq = xq;
    pa.ctx = ctx_r; pa.kvnw = kvnw_r; pa.kvnb = kvnb_r; pa.kvn = kvn;
    pa.csrc[0] = bq_r;   pa.cdst[0] = bqc;  pa.cn[0] = DIM;
    pa.csrc[1] = bk_r;   pa.cdst[1] = bkc;  pa.cn[1] = DIM;
    pa.csrc[2] = bv_r;   pa.cdst[2] = bvc;  pa.cn[2] = DIM;
    pa.csrc[3] = bo_r;   pa.cdst[3] = boc;  pa.cn[3] = DIM;
    pa.csrc[4] = b1_r;   pa.cdst[4] = b1c;  pa.cn[4] = DFF;
    pa.csrc[5] = b2_r;   pa.cdst[5] = b2c;  pa.cn[5] = DIM;
    pa.csrc[6] = qnw_r;  pa.cdst[6] = qnw;  pa.cn[6] = DIM;
    pa.csrc[7] = qnb_r;  pa.cdst[7] = qnb;  pa.cn[7] = DIM;
    pa.csrc[8] = kvnw_r; pa.cdst[8] = kvnw; pa.cn[8] = CDIM;
    pa.csrc[9] = kvnb_r; pa.cdst[9] = kvnb; pa.cn[9] = CDIM;
    pa.csrc[10] = pnw_r; pa.cdst[10] = pnw; pa.cn[10] = DIM;
    pa.csrc[11] = pnb_r; pa.cdst[11] = pnb; pa.cn[11] = DIM;
    pa.xprobe = x_r;
    prep_kernel<<<dim3(32, 32, 9), 256, 0, stream>>>(pa, flag);
  }

  // 1) fused q/k/v; z=2 emits V^T directly (A=wvT rows d, Bt=kvn rows m)
  {
    QkvArgs qa;
    qa.A[0] = xq;  qa.Bt[0] = wqT; qa.bias[0] = bqc; qa.C[0] = qm;
    qa.K[0] = DIM;  qa.ldc[0] = DIM;   qa.brow[0] = 0;
    qa.A[1] = kvn; qa.Bt[1] = wkT; qa.bias[1] = bkc; qa.C[1] = km;
    qa.K[1] = CDIM; qa.ldc[1] = DIM;   qa.brow[1] = 0;
    qa.A[2] = wvT; qa.Bt[2] = kvn; qa.bias[2] = bvc; qa.C[2] = vTb;
    qa.K[2] = CDIM; qa.ldc[2] = M_TOK; qa.brow[2] = 1;
    gemm64db_qkv<<<dim3(32, 16, 3), 256, 0, stream>>>(qa);
  }

  // 2) attention split-M (512 attn blocks) + w1-h0 transpose (z2..9) + combine
  attn_kernel<<<dim3(16, 16, 10), 512, 0, stream>>>(qm, km, vTb, pO0, pO1,
                                                    l0, l1, w1_r, w1Th, flag);
  attn_combine<<<2048, 256, 0, stream>>>(pO0, pO1, l0, l1, om);

  // 3) o-projection + raw-dtype residual(x)
  gemm64db<1><<<dim3(16, 32), 256, 0, stream>>>(om, woT, boc, x_r, xat, DIM, DIM, flag);

  // 4) post: post-norm LN + w2-h0 transpose in one launch
  {
    PostArgs po;
    po.w2 = w2_r; po.w2T = w2Th;
    po.xat = xat; po.pnw = pnw_r; po.pnb = pnb_r; po.hln = hln;
    post_kernel<<<dim3(64, 32, 2), 256, 0, stream>>>(po, flag);
  }

  // 5) MLP1 half 0
  gemm64db<2><<<dim3(32, 32), 256, 0, stream>>>(hln, w1Th, b1c, nullptr,
                                                h1h, DIM, 2048, flag);

  // 6) MLP2 half 0 fused with MLP-h1 weight transposes (w2-h1 -> shadow w2Ts)
  {
    Mlp2Args ma;
    ma.h1 = h1h; ma.w2T = w2Th; ma.b2 = b2c; ma.xat = xat; ma.out = d_out;
    ma.w1raw = w1_r; ma.w1Tdst = w1Th;
    ma.w2raw = w2_r; ma.w2Tdst = w2Ts;
    mlp2h0_fused<<<dim3(64, 32, 3), 256, 0, stream>>>(ma, flag);
  }

  // 7) MLP half 1
  gemm64db<2><<<dim3(32, 32), 256, 0, stream>>>(hln, w1Th, b1c + 2048, nullptr,
                                                h1h, DIM, 2048, flag);
  gemm64db<5><<<dim3(16, 32), 256, 0, stream>>>(h1h, w2Ts, b2c, nullptr, d_out,
                                                2048, DIM, flag);
}